// Round 1
// baseline (9537.044 us; speedup 1.0000x reference)
//
#include <hip/hip_runtime.h>
#include <math.h>

#define DI __device__ __forceinline__

namespace {
constexpr int B_ = 32;
constexpr int T_ = 512;
constexpr int N_ = 512;   // d_model
constexpr int H_ = 8;
constexpr int C_ = 32;    // c_out / conv_ch / skip_ch
constexpr int KH_ = 481;
constexpr int HOP_ = 48;
constexpr int WIN_ = 48;
constexpr int NFR_ = 11;
constexpr int NBIN_ = 257;
constexpr int TOKMAX = 22528;   // 64*352 >= max possible tokens (21760)
constexpr float EPS_ = 1e-5f;
constexpr float ALPHA_ = 0.05f;

constexpr size_t OFF_META = 0;                        // 64 ints
constexpr size_t OFF_FREQ = 1024;                     // 257 floats
constexpr size_t OFF_SW   = 4096;                     // 32*4 floats
constexpr size_t OFF_A32  = 8192;                     // 32*32 floats
constexpr size_t OFF_WD   = 16384;                    // 1024*512 floats = 2MB
constexpr size_t OFF_B1K  = OFF_WD + 1024ull*512*4;   // 1024 floats
constexpr size_t OFF_OSM  = OFF_B1K + 4096;           // 1024*512 floats = 2MB
constexpr size_t SZ_CUR   = (size_t)B_*T_*N_*4;       // 32MB
constexpr size_t OFF_CUR0 = OFF_OSM + 1024ull*512*4;
constexpr size_t OFF_CUR1 = OFF_CUR0 + SZ_CUR;
constexpr size_t OFF_ACC  = OFF_CUR1 + SZ_CUR;
constexpr size_t SZ_R     = (size_t)TOKMAX*N_*4;      // 44MB
constexpr size_t OFF_R0   = OFF_ACC + SZ_CUR;
constexpr size_t OFF_R1   = OFF_R0 + SZ_R;
constexpr size_t OFF_R2   = OFF_R1 + SZ_R;
constexpr size_t OFF_R3   = OFF_R2 + SZ_R;
constexpr size_t OFF_R4   = OFF_R3 + SZ_R;
} // namespace

DI float gelu_exact(float x) { return 0.5f * x * (1.0f + erff(x * 0.7071067811865475f)); }
DI unsigned short f2bf(float f) {
  unsigned u = __float_as_uint(f);
  u += 0x7FFFu + ((u >> 16) & 1u);
  return (unsigned short)(u >> 16);
}
DI float bf2f(unsigned short s) { return __uint_as_float(((unsigned)s) << 16); }

// ---------------- STFT: freq accumulation ----------------
// block = (b, frame). Twiddles (window-folded) cached in LDS with exact
// integer angle reduction: ang = ((k*(232+j)) mod 512) * 2pi/512.
__global__ __launch_bounds__(256) void k_stft_freq(const float* __restrict__ x,
                                                   float* __restrict__ freq) {
  int b = blockIdx.x / NFR_, f = blockIdx.x % NFR_;
  __shared__ float ct[NBIN_ * 49];
  __shared__ float st[NBIN_ * 49];
  __shared__ float xw[WIN_ * 8];
  int tid = threadIdx.x;
  for (int i = tid; i < NBIN_ * WIN_; i += 256) {
    int k = i / WIN_, j = i % WIN_;
    int r = (k * (232 + j)) & 511;
    float ang = (float)r * 0.012271846303085130f;   // 2pi/512
    float w = 0.5f - 0.5f * cosf((float)j * 0.13089969389957472f);  // 2pi/48
    ct[k * 49 + j] = w * cosf(ang);
    st[k * 49 + j] = w * sinf(ang);
  }
  float fa0 = 0.f, fa1 = 0.f;
  for (int n0 = 0; n0 < N_; n0 += 8) {
    __syncthreads();
    for (int i = tid; i < WIN_ * 8; i += 256) {
      int j = i >> 3, nn = i & 7;
      int gi = f * HOP_ + 232 + j - 256;
      if (gi < 0) gi = -gi;   // reflect pad (left only; right never reached)
      xw[i] = x[((size_t)b * T_ + gi) * N_ + n0 + nn];
    }
    __syncthreads();
    for (int kk = tid; kk < NBIN_; kk += 256) {
      const float* cp = &ct[kk * 49];
      const float* sp = &st[kk * 49];
      float re[8] = {0,0,0,0,0,0,0,0}, im[8] = {0,0,0,0,0,0,0,0};
      for (int j = 0; j < WIN_; ++j) {
        float cj = cp[j], sj = sp[j];
#pragma unroll
        for (int nn = 0; nn < 8; ++nn) {
          float xv = xw[j * 8 + nn];
          re[nn] += xv * cj;
          im[nn] += xv * sj;
        }
      }
      float a = 0.f;
#pragma unroll
      for (int nn = 0; nn < 8; ++nn) a += sqrtf(re[nn] * re[nn] + im[nn] * im[nn]);
      if (kk == tid) fa0 += a; else fa1 += a;
    }
  }
  atomicAdd(&freq[tid], fa0);
  if (tid == 0) atomicAdd(&freq[256], fa1);
}

// ---------------- top-k + meta ----------------
__global__ void k_topk(const float* __restrict__ freq, int* __restrict__ meta) {
  if (threadIdx.x == 0 && blockIdx.x == 0) {
    float bv[3] = {-1e30f, -1e30f, -1e30f};
    int bi[3] = {1, 1, 1};
    for (int k = 1; k < NBIN_; ++k) {
      float v = freq[k];
      if (v > bv[0]) { bv[2]=bv[1]; bi[2]=bi[1]; bv[1]=bv[0]; bi[1]=bi[0]; bv[0]=v; bi[0]=k; }
      else if (v > bv[1]) { bv[2]=bv[1]; bi[2]=bi[1]; bv[1]=v; bi[1]=k; }
      else if (v > bv[2]) { bv[2]=v; bi[2]=k; }
    }
    for (int i = 0; i < 3; ++i) {
      int top = bi[i];
      int p = T_ / top;
      int L = ((T_ + p - 1) / p) * p;
      meta[i] = top;
      meta[3 + i] = p;
      meta[6 + i] = L;
      meta[9 + i] = L / p;
      meta[15 + i] = B_ * L;   // tokens
    }
  }
}

// ---------------- per-batch branch weights sw ----------------
__global__ __launch_bounds__(256) void k_sw(const float* __restrict__ x,
                                            const int* __restrict__ meta,
                                            float* __restrict__ swb) {
  int b = blockIdx.x;
  __shared__ float ct[3][WIN_], st[3][WIN_];
  __shared__ float red[256];
  int tid = threadIdx.x;
  for (int i = tid; i < 3 * WIN_; i += 256) {
    int kk = i / WIN_, j = i % WIN_;
    int k = meta[kk];
    int r = (k * (232 + j)) & 511;
    float ang = (float)r * 0.012271846303085130f;
    float w = 0.5f - 0.5f * cosf((float)j * 0.13089969389957472f);
    ct[kk][j] = w * cosf(ang);
    st[kk][j] = w * sinf(ang);
  }
  __syncthreads();
  float acc[3] = {0.f, 0.f, 0.f};
  for (int it = tid; it < NFR_ * N_; it += 256) {
    int f = it / N_, n = it % N_;
    float xs[WIN_];
    for (int j = 0; j < WIN_; ++j) {
      int gi = f * HOP_ + 232 + j - 256;
      if (gi < 0) gi = -gi;
      xs[j] = x[((size_t)b * T_ + gi) * N_ + n];
    }
    for (int kk = 0; kk < 3; ++kk) {
      float re = 0.f, im = 0.f;
      for (int j = 0; j < WIN_; ++j) { re += xs[j] * ct[kk][j]; im += xs[j] * st[kk][j]; }
      acc[kk] += sqrtf(re * re + im * im);
    }
  }
  for (int kk = 0; kk < 3; ++kk) {
    red[tid] = acc[kk];
    __syncthreads();
    for (int off = 128; off > 0; off >>= 1) {
      if (tid < off) red[tid] += red[tid + off];
      __syncthreads();
    }
    if (tid == 0) swb[b * 4 + kk] = red[0];
    __syncthreads();
  }
  if (tid == 0) {
    float inv = 1.0f / (float)(NFR_ * N_);
    float m0 = swb[b*4+0]*inv, m1 = swb[b*4+1]*inv, m2 = swb[b*4+2]*inv;
    float mx = fmaxf(m0, fmaxf(m1, m2));
    float e0 = expf(m0-mx), e1 = expf(m1-mx), e2 = expf(m2-mx);
    float s = e0 + e1 + e2;
    swb[b*4+0] = e0/s; swb[b*4+1] = e1/s; swb[b*4+2] = e2/s;
  }
}

// ---------------- graph adjacency ----------------
__global__ void k_adj(const float* __restrict__ nv1, const float* __restrict__ nv2,
                      float* __restrict__ a32) {
  int v = threadIdx.x;
  if (v < C_) {
    float row[C_];
    for (int w = 0; w < C_; ++w) {
      float s = 0.f;
      for (int d = 0; d < 10; ++d) s += nv1[v * 10 + d] * nv2[d * C_ + w];
      row[w] = fmaxf(s, 0.f);
    }
    float mx = -1e30f;
    for (int w = 0; w < C_; ++w) mx = fmaxf(mx, row[w]);
    float sm = 0.f;
    for (int w = 0; w < C_; ++w) { row[w] = expf(row[w] - mx); sm += row[w]; }
    for (int w = 0; w < C_; ++w) row[w] /= sm;
    row[v] += 1.0f;
    float rs = 0.f;
    for (int w = 0; w < C_; ++w) rs += row[w];
    for (int w = 0; w < C_; ++w) a32[v * C_ + w] = row[w] / rs;
  }
}

// ---------------- dense conv weight build ----------------
__global__ void k_wd(const float* __restrict__ swi, const float* __restrict__ sbi,
                     float* __restrict__ Wd, float* __restrict__ b1k) {
  int idx = blockIdx.x * 256 + threadIdx.x;
  if (idx < 1024 * N_) {
    int row = idx / N_, j = idx % N_;
    int o = row >> 5, n = row & 31;
    int k = j - n;
    Wd[idx] = (k >= 0 && k < KH_) ? swi[o * KH_ + k] : 0.f;
    if (j == 0) b1k[row] = sbi[o];
  }
}

// ---------------- generic fp32 GEMM: C[M][N] = A[M][K] @ B[N][K]^T + bias ----------------
__global__ __launch_bounds__(256) void k_gemm(const float* __restrict__ A,
                                              const float* __restrict__ Bm,
                                              const float* __restrict__ bias,
                                              float* __restrict__ Cm,
                                              int M, int N, int K,
                                              const int* __restrict__ Mdyn, int dogelu) {
  if (Mdyn) M = *Mdyn;
  int bm = blockIdx.y * 64;
  if (bm >= M) return;
  int bn = blockIdx.x * 64;
  __shared__ float As[16][64];
  __shared__ float Bs[16][64];
  int tid = threadIdx.x;
  int lm = tid >> 2, lk = (tid & 3) * 4;
  int tx = tid & 15, ty = tid >> 4;
  float acc[4][4] = {};
  for (int k0 = 0; k0 < K; k0 += 16) {
    __syncthreads();
    {
      int row = bm + lm;
      float4 v4 = make_float4(0.f, 0.f, 0.f, 0.f);
      if (row < M) v4 = *(const float4*)&A[(size_t)row * K + k0 + lk];
      As[lk + 0][lm] = v4.x; As[lk + 1][lm] = v4.y; As[lk + 2][lm] = v4.z; As[lk + 3][lm] = v4.w;
      float4 w4 = *(const float4*)&Bm[(size_t)(bn + lm) * K + k0 + lk];
      Bs[lk + 0][lm] = w4.x; Bs[lk + 1][lm] = w4.y; Bs[lk + 2][lm] = w4.z; Bs[lk + 3][lm] = w4.w;
    }
    __syncthreads();
#pragma unroll
    for (int kk = 0; kk < 16; ++kk) {
      float4 a4 = *(const float4*)&As[kk][ty * 4];
      float4 b4 = *(const float4*)&Bs[kk][tx * 4];
      acc[0][0] += a4.x*b4.x; acc[0][1] += a4.x*b4.y; acc[0][2] += a4.x*b4.z; acc[0][3] += a4.x*b4.w;
      acc[1][0] += a4.y*b4.x; acc[1][1] += a4.y*b4.y; acc[1][2] += a4.y*b4.z; acc[1][3] += a4.y*b4.w;
      acc[2][0] += a4.z*b4.x; acc[2][1] += a4.z*b4.y; acc[2][2] += a4.z*b4.z; acc[2][3] += a4.z*b4.w;
      acc[3][0] += a4.w*b4.x; acc[3][1] += a4.w*b4.y; acc[3][2] += a4.w*b4.z; acc[3][3] += a4.w*b4.w;
    }
  }
  float4 bi4 = make_float4(0.f, 0.f, 0.f, 0.f);
  if (bias) bi4 = *(const float4*)&bias[bn + tx * 4];
#pragma unroll
  for (int i = 0; i < 4; ++i) {
    int row = bm + ty * 4 + i;
    if (row >= M) continue;
    float4 r;
    r.x = acc[i][0] + bi4.x; r.y = acc[i][1] + bi4.y;
    r.z = acc[i][2] + bi4.z; r.w = acc[i][3] + bi4.w;
    if (dogelu) { r.x = gelu_exact(r.x); r.y = gelu_exact(r.y); r.z = gelu_exact(r.z); r.w = gelu_exact(r.w); }
    *(float4*)&Cm[(size_t)row * N + bn + tx * 4] = r;
  }
}

// ---------------- GCN propagate + mix + gelu (per token) ----------------
__global__ __launch_bounds__(256) void k_gcnmix(const float* __restrict__ Hb,
                                                const float* __restrict__ a32,
                                                const float* __restrict__ mw,
                                                const float* __restrict__ mb,
                                                float* __restrict__ G) {
  __shared__ float X[3][C_][C_];
  __shared__ float am[C_ * 33];
  __shared__ float mwl[C_ * 96];
  __shared__ float mbl[C_];
  size_t tok = blockIdx.x;
  int tid = threadIdx.x;
  for (int i = tid; i < C_ * C_; i += 256) am[(i >> 5) * 33 + (i & 31)] = a32[i];
  for (int i = tid; i < C_ * 96; i += 256) mwl[i] = mw[i];
  if (tid < C_) mbl[tid] = mb[tid];
  for (int i = tid; i < 1024; i += 256) X[0][i >> 5][i & 31] = Hb[tok * 1024 + i];
  __syncthreads();
#pragma unroll
  for (int dep = 1; dep <= 2; ++dep) {
    for (int i = tid; i < 1024; i += 256) {
      int c = i >> 5, v = i & 31;
      float s = 0.f;
      for (int w = 0; w < C_; ++w) s += X[dep - 1][c][w] * am[v * 33 + w];
      X[dep][c][v] = ALPHA_ * X[0][c][v] + (1.0f - ALPHA_) * s;
    }
    __syncthreads();
  }
  for (int i = tid; i < 1024; i += 256) {
    int o = i >> 5, v = i & 31;
    float s = mbl[o];
    for (int cc = 0; cc < 96; ++cc) s += mwl[o * 96 + cc] * X[cc >> 5][cc & 31][v];
    G[tok * 1024 + i] = gelu_exact(s);
  }
}

// ---------------- repack G[(b,s),(c,n)] -> G2[(b,n),(c,s)] ----------------
__global__ __launch_bounds__(256) void k_repack(const float* __restrict__ G,
                                                float* __restrict__ G2) {
  int bid = blockIdx.x;
  int st = bid & 15, c = (bid >> 4) & 31, b = bid >> 9;
  __shared__ float tile[32][33];
  int tid = threadIdx.x;
  int n = tid & 31, s = tid >> 5;
  for (int q = 0; q < 4; ++q) {
    int ss = s + q * 8;
    tile[ss][n] = G[((size_t)b * T_ + st * 32 + ss) * 1024 + c * 32 + n];
  }
  __syncthreads();
  int s2 = tid & 31, n2 = tid >> 5;
  for (int q = 0; q < 4; ++q) {
    int nn = n2 + q * 8;
    G2[((size_t)b * 32 + nn) * 16384 + c * 512 + st * 32 + s2] = tile[s2][nn];
  }
}

// ---------------- lw projection + residual + LN (graph epilogue) ----------------
__global__ __launch_bounds__(256) void k_lwln(const float* __restrict__ osm,
                                              const float* __restrict__ lw,
                                              const float* __restrict__ lb,
                                              const float* __restrict__ curIn,
                                              const float* __restrict__ g,
                                              const float* __restrict__ bt,
                                              float* __restrict__ curOut) {
  int tok = blockIdx.x;
  int b = tok >> 9, t = tok & 511;
  __shared__ float os[C_];
  __shared__ float red[256];
  int tid = threadIdx.x;
  if (tid < C_) os[tid] = osm[((size_t)b * C_ + tid) * T_ + t];
  __syncthreads();
  float val[2];
#pragma unroll
  for (int q = 0; q < 2; ++q) {
    int m = tid + q * 256;
    float s = lb[m] + curIn[(size_t)tok * N_ + m];
    for (int n2 = 0; n2 < C_; ++n2) s += os[n2] * lw[n2 * N_ + m];
    val[q] = s;
  }
  red[tid] = val[0] + val[1];
  __syncthreads();
  for (int off = 128; off > 0; off >>= 1) { if (tid < off) red[tid] += red[tid + off]; __syncthreads(); }
  float mean = red[0] * (1.0f / N_);
  __syncthreads();
  float d0 = val[0] - mean, d1 = val[1] - mean;
  red[tid] = d0 * d0 + d1 * d1;
  __syncthreads();
  for (int off = 128; off > 0; off >>= 1) { if (tid < off) red[tid] += red[tid + off]; __syncthreads(); }
  float inv = rsqrtf(red[0] * (1.0f / N_) + EPS_);
  curOut[(size_t)tok * N_ + tid] = d0 * inv * g[tid] + bt[tid];
  curOut[(size_t)tok * N_ + tid + 256] = d1 * inv * g[tid + 256] + bt[tid + 256];
}

// ---------------- zero-pad tokens ----------------
__global__ void k_pad(const float* __restrict__ cur, float* __restrict__ xa,
                      const int* __restrict__ meta, int iter) {
  int L = meta[6 + iter];
  size_t total = (size_t)(B_ * L) * N_;
  for (size_t idx = (size_t)blockIdx.x * 256 + threadIdx.x; idx < total;
       idx += (size_t)gridDim.x * 256) {
    size_t tokd = idx >> 9;
    int d = (int)(idx & 511);
    int b = (int)(tokd / L), l = (int)(tokd % L);
    xa[idx] = (l < T_) ? cur[((size_t)b * T_ + l) * N_ + d] : 0.f;
  }
}

// ---------------- residual add + LN (attention) ----------------
__global__ __launch_bounds__(256) void k_lnadd(const float* __restrict__ r1,
                                               const float* __restrict__ r2,
                                               const float* __restrict__ g,
                                               const float* __restrict__ bt,
                                               float* __restrict__ dst,
                                               const int* __restrict__ meta, int iter) {
  int tokens = meta[15 + iter];
  int tok = blockIdx.x;
  if (tok >= tokens) return;
  __shared__ float red[256];
  int tid = threadIdx.x;
  float val[2];
#pragma unroll
  for (int q = 0; q < 2; ++q) {
    int m = tid + q * 256;
    val[q] = r1[(size_t)tok * N_ + m] + r2[(size_t)tok * N_ + m];
  }
  red[tid] = val[0] + val[1];
  __syncthreads();
  for (int off = 128; off > 0; off >>= 1) { if (tid < off) red[tid] += red[tid + off]; __syncthreads(); }
  float mean = red[0] * (1.0f / N_);
  __syncthreads();
  float d0 = val[0] - mean, d1 = val[1] - mean;
  red[tid] = d0 * d0 + d1 * d1;
  __syncthreads();
  for (int off = 128; off > 0; off >>= 1) { if (tid < off) red[tid] += red[tid + off]; __syncthreads(); }
  float inv = rsqrtf(red[0] * (1.0f / N_) + EPS_);
  dst[(size_t)tok * N_ + tid] = d0 * inv * g[tid] + bt[tid];
  dst[(size_t)tok * N_ + tid + 256] = d1 * inv * g[tid + 256] + bt[tid + 256];
}

// ---------------- fused attention (one block per (seq, head)) ----------------
template <int SMAX>
__global__ __launch_bounds__(256) void k_attn(const float* __restrict__ qb,
                                              const float* __restrict__ kb,
                                              const float* __restrict__ vb,
                                              float* __restrict__ ob,
                                              const int* __restrict__ meta, int iter) {
  int p = meta[3 + iter];
  if (SMAX == 128) { if (p > 128) return; } else { if (p <= 128) return; }
  int L = meta[6 + iter], nseq = meta[9 + iter];
  int M = B_ * nseq;
  int mh = blockIdx.x;
  int m = mh >> 3, h = mh & 7;
  if (m >= M) return;
  int S = p;
  int b = m / nseq, g2 = m % nseq;
  size_t tok0 = (size_t)b * L + (size_t)g2 * S;
  __shared__ unsigned short Ks[SMAX * 66];
  __shared__ unsigned short Vs[SMAX * 66];
  __shared__ float qrow[4][64];
  __shared__ float Pr[4][SMAX];
  int tid = threadIdx.x;
  for (int i = tid; i < S * 64; i += 256) {
    int t = i >> 6, d = i & 63;
    Ks[t * 66 + d] = f2bf(kb[(tok0 + t) * N_ + h * 64 + d]);
    Vs[t * 66 + d] = f2bf(vb[(tok0 + t) * N_ + h * 64 + d]);
  }
  __syncthreads();
  int wave = tid >> 6, lane = tid & 63;
  int rounds = (S + 3) >> 2;
  constexpr int TC = (SMAX + 63) / 64;
  for (int r = 0; r < rounds; ++r) {
    int s = r * 4 + wave;
    bool act = (s < S);
    if (act) qrow[wave][lane] = qb[(tok0 + s) * N_ + h * 64 + lane];
    __syncthreads();
    float sc[TC];
    float ssum = 0.f;
    if (act) {
      const float2* qp = (const float2*)&qrow[wave][0];
      float mx = -3.0e38f;
#pragma unroll
      for (int c2 = 0; c2 < TC; ++c2) {
        int t = lane + c2 * 64;
        float sv = -3.0e38f;
        if (t < S) {
          const unsigned int* kp = (const unsigned int*)&Ks[t * 66];
          float ad = 0.f;
#pragma unroll
          for (int j2 = 0; j2 < 32; ++j2) {
            float2 qq = qp[j2];
            unsigned int kw = kp[j2];
            ad += qq.x * bf2f((unsigned short)(kw & 0xffffu));
            ad += qq.y * bf2f((unsigned short)(kw >> 16));
          }
          sv = ad * 0.125f;
        }
        sc[c2] = sv;
        mx = fmaxf(mx, sv);
      }
      for (int off = 32; off > 0; off >>= 1) mx = fmaxf(mx, __shfl_xor(mx, off));
#pragma unroll
      for (int c2 = 0; c2 < TC; ++c2) {
        int t = lane + c2 * 64;
        float e = 0.f;
        if (t < S) { e = expf(sc[c2] - mx); Pr[wave][t] = e; }
        ssum += e;
      }
      for (int off = 32; off > 0; off >>= 1) ssum += __shfl_xor(ssum, off);
    }
    __syncthreads();
    if (act) {
      float inv = 1.0f / ssum;
      float ov = 0.f;
      for (int t = 0; t < S; ++t) ov += Pr[wave][t] * bf2f(Vs[t * 66 + lane]);
      ob[(tok0 + s) * N_ + h * 64 + lane] = ov * inv;
    }
    __syncthreads();
  }
}

// ---------------- final LN + gelu + weighted accumulate ----------------
__global__ __launch_bounds__(256) void k_fin(const float* __restrict__ y,
                                             const float* __restrict__ g,
                                             const float* __restrict__ bt,
                                             const float* __restrict__ swb,
                                             float* __restrict__ acc,
                                             const int* __restrict__ meta, int iter) {
  int L = meta[6 + iter];
  int tokens = B_ * L;
  int tok = blockIdx.x;
  if (tok >= tokens) return;
  int b = tok / L, l = tok % L;
  if (l >= T_) return;   // truncated away
  __shared__ float red[256];
  int tid = threadIdx.x;
  float val[2];
#pragma unroll
  for (int q = 0; q < 2; ++q) val[q] = y[(size_t)tok * N_ + tid + q * 256];
  red[tid] = val[0] + val[1];
  __syncthreads();
  for (int off = 128; off > 0; off >>= 1) { if (tid < off) red[tid] += red[tid + off]; __syncthreads(); }
  float mean = red[0] * (1.0f / N_);
  __syncthreads();
  float d0 = val[0] - mean, d1 = val[1] - mean;
  red[tid] = d0 * d0 + d1 * d1;
  __syncthreads();
  for (int off = 128; off > 0; off >>= 1) { if (tid < off) red[tid] += red[tid + off]; __syncthreads(); }
  float inv = rsqrtf(red[0] * (1.0f / N_) + EPS_);
  float s = swb[b * 4 + iter];
  float u0 = gelu_exact(d0 * inv * g[tid] + bt[tid]);
  float u1 = gelu_exact(d1 * inv * g[tid + 256] + bt[tid + 256]);
  size_t o = ((size_t)b * T_ + l) * N_;
  acc[o + tid] += s * u0;
  acc[o + tid + 256] += s * u1;
}

// ---------------- final output ----------------
__global__ void k_final(const float* __restrict__ acc, const float* __restrict__ cur,
                        float* __restrict__ out) {
  size_t idx = (size_t)blockIdx.x * 256 + threadIdx.x;
  out[idx] = acc[idx] + cur[idx];
}

extern "C" void kernel_launch(void* const* d_in, const int* in_sizes, int n_in,
                              void* d_out, int out_size, void* d_ws, size_t ws_size,
                              hipStream_t stream) {
  (void)in_sizes; (void)n_in; (void)out_size; (void)ws_size;
  const float* x       = (const float*)d_in[0];
  const float* nv1     = (const float*)d_in[1];
  const float* nv2     = (const float*)d_in[2];
  const float* start_w = (const float*)d_in[3];
  const float* start_b = (const float*)d_in[4];
  const float* mix_w   = (const float*)d_in[5];
  const float* mix_b   = (const float*)d_in[6];
  const float* end_w   = (const float*)d_in[7];
  const float* end_b   = (const float*)d_in[8];
  const float* glin_w  = (const float*)d_in[9];
  const float* glin_b  = (const float*)d_in[10];
  const float* gnorm_g = (const float*)d_in[11];
  const float* gnorm_b = (const float*)d_in[12];
  const float* wq = (const float*)d_in[13];
  const float* bq = (const float*)d_in[14];
  const float* wk = (const float*)d_in[15];
  const float* bk = (const float*)d_in[16];
  const float* wv = (const float*)d_in[17];
  const float* bv = (const float*)d_in[18];
  const float* wo = (const float*)d_in[19];
  const float* bo = (const float*)d_in[20];
  const float* ff1w = (const float*)d_in[21];
  const float* ff1b = (const float*)d_in[22];
  const float* ff2w = (const float*)d_in[23];
  const float* ff2b = (const float*)d_in[24];
  const float* an1g = (const float*)d_in[25];
  const float* an1b = (const float*)d_in[26];
  const float* an2g = (const float*)d_in[27];
  const float* an2b = (const float*)d_in[28];
  const float* nrmg = (const float*)d_in[29];
  const float* nrmb = (const float*)d_in[30];

  char* ws = (char*)d_ws;
  int*   meta = (int*)(ws + OFF_META);
  float* freq = (float*)(ws + OFF_FREQ);
  float* swb  = (float*)(ws + OFF_SW);
  float* a32  = (float*)(ws + OFF_A32);
  float* Wd   = (float*)(ws + OFF_WD);
  float* b1k  = (float*)(ws + OFF_B1K);
  float* osm  = (float*)(ws + OFF_OSM);
  float* cur0 = (float*)(ws + OFF_CUR0);
  float* cur1 = (float*)(ws + OFF_CUR1);
  float* accb = (float*)(ws + OFF_ACC);
  float* R0 = (float*)(ws + OFF_R0);
  float* R1 = (float*)(ws + OFF_R1);
  float* R2 = (float*)(ws + OFF_R2);
  float* R3 = (float*)(ws + OFF_R3);
  float* R4 = (float*)(ws + OFF_R4);

  hipMemsetAsync(freq, 0, NBIN_ * sizeof(float), stream);
  hipMemsetAsync(accb, 0, SZ_CUR, stream);

  k_stft_freq<<<B_ * NFR_, 256, 0, stream>>>(x, freq);
  k_topk<<<1, 64, 0, stream>>>(freq, meta);
  k_sw<<<B_, 256, 0, stream>>>(x, meta, swb);

  const float* curIn = x;
  float* curs[2] = {cur0, cur1};
  for (int i = 0; i < 3; ++i) {
    float* curOut = curs[i & 1];
    // ---- graph block ----
    k_adj<<<1, 64, 0, stream>>>(nv1 + i * C_ * 10, nv2 + i * 10 * C_, a32);
    k_wd<<<(1024 * N_ + 255) / 256, 256, 0, stream>>>(start_w + i * C_ * KH_, start_b + i * C_, Wd, b1k);
    k_gemm<<<dim3(1024 / 64, (B_ * T_) / 64), 256, 0, stream>>>(curIn, Wd, b1k, R0,
                                                                B_ * T_, 1024, N_, nullptr, 0);
    k_gcnmix<<<B_ * T_, 256, 0, stream>>>(R0, a32, mix_w + i * C_ * 96, mix_b + i * C_, R1);
    k_repack<<<B_ * C_ * 16, 256, 0, stream>>>(R1, R2);
    k_gemm<<<dim3(512 / 64, 1024 / 64), 256, 0, stream>>>(R2, end_w + (size_t)i * T_ * C_ * T_,
                                                          end_b + i * T_, osm, 1024, 512, 16384,
                                                          nullptr, 0);
    k_lwln<<<B_ * T_, 256, 0, stream>>>(osm, glin_w + i * C_ * N_, glin_b + i * N_, curIn,
                                        gnorm_g + i * N_, gnorm_b + i * N_, curOut);
    // ---- attention branch ----
    const int* Mdyn = meta + 15 + i;
    k_pad<<<4096, 256, 0, stream>>>(curOut, R0, meta, i);
    dim3 gT(512 / 64, TOKMAX / 64);
    k_gemm<<<gT, 256, 0, stream>>>(R0, wq, bq, R1, TOKMAX, 512, 512, Mdyn, 0);
    k_gemm<<<gT, 256, 0, stream>>>(R0, wk, bk, R2, TOKMAX, 512, 512, Mdyn, 0);
    k_gemm<<<gT, 256, 0, stream>>>(R0, wv, bv, R3, TOKMAX, 512, 512, Mdyn, 0);
    k_attn<128><<<65536, 256, 0, stream>>>(R1, R2, R3, R4, meta, i);
    k_attn<512><<<1024, 256, 0, stream>>>(R1, R2, R3, R4, meta, i);
    k_gemm<<<gT, 256, 0, stream>>>(R4, wo, bo, R1, TOKMAX, 512, 512, Mdyn, 0);
    k_lnadd<<<TOKMAX, 256, 0, stream>>>(R0, R1, an1g, an1b, R2, meta, i);
    k_gemm<<<gT, 256, 0, stream>>>(R2, ff1w, ff1b, R3, TOKMAX, 512, 512, Mdyn, 1);
    k_gemm<<<gT, 256, 0, stream>>>(R3, ff2w, ff2b, R1, TOKMAX, 512, 512, Mdyn, 0);
    k_lnadd<<<TOKMAX, 256, 0, stream>>>(R2, R1, an2g, an2b, R0, meta, i);
    k_fin<<<TOKMAX, 256, 0, stream>>>(R0, nrmg, nrmb, swb, accb, meta, i);
    curIn = curOut;
  }
  k_final<<<(B_ * T_ * N_) / 256, 256, 0, stream>>>(accb, curIn, (float*)d_out);
}

// Round 2
// 4232.840 us; speedup vs baseline: 2.2531x; 2.2531x over previous
//
#include <hip/hip_runtime.h>
#include <math.h>

#define DI __device__ __forceinline__

namespace {
constexpr int B_ = 32;
constexpr int T_ = 512;
constexpr int N_ = 512;   // d_model
constexpr int C_ = 32;    // c_out / conv_ch / skip_ch
constexpr int KH_ = 481;
constexpr int HOP_ = 48;
constexpr int WIN_ = 48;
constexpr int NFR_ = 11;
constexpr int NBIN_ = 257;
constexpr int TOKMAX = 22528;   // 176*128 >= max possible tokens (21760)
constexpr float EPS_ = 1e-5f;
constexpr float ALPHA_ = 0.05f;

constexpr size_t MBY = 1ull << 20;
constexpr size_t OFF_META = 0;
constexpr size_t OFF_FREQ = 4096;
constexpr size_t OFF_SW   = 8192;
constexpr size_t OFF_A32  = 12288;
constexpr size_t OFF_B1K  = 16384;
constexpr size_t OFF_OSM  = 1 * MBY;     // 2MB
constexpr size_t OFF_WB   = 4 * MBY;     // 12 planes x 512KB = 6MB
constexpr size_t OFF_WDH  = 10 * MBY;    // 1MB
constexpr size_t OFF_WDL  = 11 * MBY;    // 1MB
constexpr size_t OFF_EWH  = 12 * MBY;    // 16MB
constexpr size_t OFF_EWL  = 28 * MBY;    // 16MB
constexpr size_t OFF_CUR  = 44 * MBY;    // 32MB
constexpr size_t OFF_ACC  = 76 * MBY;    // 32MB
constexpr size_t TR       = 108 * MBY;   // transient union region
// graph phase
constexpr size_t OFF_R0G  = TR;            // 64MB [16384][1024]
constexpr size_t OFF_G    = TR + 64 * MBY; // 64MB
constexpr size_t OFF_G2   = TR + 128 * MBY;// 64MB [1024][16384]
constexpr size_t OFF_PART = TR + 192 * MBY;// 16MB [8][1024][512]
// attention phase (aliases graph region)
constexpr size_t OFF_A0 = TR;              // 44MB each
constexpr size_t OFF_A2 = TR + 44 * MBY;
constexpr size_t OFF_A3 = TR + 88 * MBY;
constexpr size_t OFF_A4 = TR + 132 * MBY;
constexpr size_t OFF_A5 = TR + 176 * MBY;  // ends 328MB
} // namespace

typedef __attribute__((ext_vector_type(4))) float f32x4;
typedef __attribute__((ext_vector_type(8))) short bf8;
typedef __attribute__((ext_vector_type(8))) unsigned short u16x8;

DI float gelu_exact(float x) { return 0.5f * x * (1.0f + erff(x * 0.7071067811865475f)); }
DI unsigned short f2bf(float f) {   // round-to-nearest-even
  unsigned u = __float_as_uint(f);
  u += 0x7FFFu + ((u >> 16) & 1u);
  return (unsigned short)(u >> 16);
}
DI float bf2f(unsigned short s) { return __uint_as_float(((unsigned)s) << 16); }

// ---------------- STFT: freq accumulation ----------------
__global__ __launch_bounds__(256) void k_stft_freq(const float* __restrict__ x,
                                                   float* __restrict__ freq) {
  int b = blockIdx.x / NFR_, f = blockIdx.x % NFR_;
  __shared__ float ct[NBIN_ * 49];
  __shared__ float st[NBIN_ * 49];
  __shared__ float xw[WIN_ * 8];
  int tid = threadIdx.x;
  for (int i = tid; i < NBIN_ * WIN_; i += 256) {
    int k = i / WIN_, j = i % WIN_;
    int r = (k * (232 + j)) & 511;
    float ang = (float)r * 0.012271846303085130f;   // 2pi/512
    float w = 0.5f - 0.5f * cosf((float)j * 0.13089969389957472f);  // 2pi/48
    ct[k * 49 + j] = w * cosf(ang);
    st[k * 49 + j] = w * sinf(ang);
  }
  float fa0 = 0.f, fa1 = 0.f;
  for (int n0 = 0; n0 < N_; n0 += 8) {
    __syncthreads();
    for (int i = tid; i < WIN_ * 8; i += 256) {
      int j = i >> 3, nn = i & 7;
      int gi = f * HOP_ + 232 + j - 256;
      if (gi < 0) gi = -gi;   // reflect pad
      xw[i] = x[((size_t)b * T_ + gi) * N_ + n0 + nn];
    }
    __syncthreads();
    for (int kk = tid; kk < NBIN_; kk += 256) {
      const float* cp = &ct[kk * 49];
      const float* sp = &st[kk * 49];
      float re[8] = {0,0,0,0,0,0,0,0}, im[8] = {0,0,0,0,0,0,0,0};
      for (int j = 0; j < WIN_; ++j) {
        float cj = cp[j], sj = sp[j];
#pragma unroll
        for (int nn = 0; nn < 8; ++nn) {
          float xv = xw[j * 8 + nn];
          re[nn] += xv * cj;
          im[nn] += xv * sj;
        }
      }
      float a = 0.f;
#pragma unroll
      for (int nn = 0; nn < 8; ++nn) a += sqrtf(re[nn] * re[nn] + im[nn] * im[nn]);
      if (kk == tid) fa0 += a; else fa1 += a;
    }
  }
  atomicAdd(&freq[tid], fa0);
  if (tid == 0) atomicAdd(&freq[256], fa1);
}

// ---------------- top-k + meta ----------------
__global__ void k_topk(const float* __restrict__ freq, int* __restrict__ meta) {
  if (threadIdx.x == 0 && blockIdx.x == 0) {
    float bv[3] = {-1e30f, -1e30f, -1e30f};
    int bi[3] = {1, 1, 1};
    for (int k = 1; k < NBIN_; ++k) {
      float v = freq[k];
      if (v > bv[0]) { bv[2]=bv[1]; bi[2]=bi[1]; bv[1]=bv[0]; bi[1]=bi[0]; bv[0]=v; bi[0]=k; }
      else if (v > bv[1]) { bv[2]=bv[1]; bi[2]=bi[1]; bv[1]=v; bi[1]=k; }
      else if (v > bv[2]) { bv[2]=v; bi[2]=k; }
    }
    for (int i = 0; i < 3; ++i) {
      int top = bi[i];
      int p = T_ / top;
      int L = ((T_ + p - 1) / p) * p;
      meta[i] = top;
      meta[3 + i] = p;
      meta[6 + i] = L;
      meta[9 + i] = L / p;
      meta[15 + i] = B_ * L;   // tokens
    }
  }
}

// ---------------- per-batch branch weights sw ----------------
__global__ __launch_bounds__(256) void k_sw(const float* __restrict__ x,
                                            const int* __restrict__ meta,
                                            float* __restrict__ swb) {
  int b = blockIdx.x;
  __shared__ float ct[3][WIN_], st[3][WIN_];
  __shared__ float red[256];
  int tid = threadIdx.x;
  for (int i = tid; i < 3 * WIN_; i += 256) {
    int kk = i / WIN_, j = i % WIN_;
    int k = meta[kk];
    int r = (k * (232 + j)) & 511;
    float ang = (float)r * 0.012271846303085130f;
    float w = 0.5f - 0.5f * cosf((float)j * 0.13089969389957472f);
    ct[kk][j] = w * cosf(ang);
    st[kk][j] = w * sinf(ang);
  }
  __syncthreads();
  float acc[3] = {0.f, 0.f, 0.f};
  for (int it = tid; it < NFR_ * N_; it += 256) {
    int f = it / N_, n = it % N_;
    float xs[WIN_];
    for (int j = 0; j < WIN_; ++j) {
      int gi = f * HOP_ + 232 + j - 256;
      if (gi < 0) gi = -gi;
      xs[j] = x[((size_t)b * T_ + gi) * N_ + n];
    }
    for (int kk = 0; kk < 3; ++kk) {
      float re = 0.f, im = 0.f;
      for (int j = 0; j < WIN_; ++j) { re += xs[j] * ct[kk][j]; im += xs[j] * st[kk][j]; }
      acc[kk] += sqrtf(re * re + im * im);
    }
  }
  for (int kk = 0; kk < 3; ++kk) {
    red[tid] = acc[kk];
    __syncthreads();
    for (int off = 128; off > 0; off >>= 1) {
      if (tid < off) red[tid] += red[tid + off];
      __syncthreads();
    }
    if (tid == 0) swb[b * 4 + kk] = red[0];
    __syncthreads();
  }
  if (tid == 0) {
    float inv = 1.0f / (float)(NFR_ * N_);
    float m0 = swb[b*4+0]*inv, m1 = swb[b*4+1]*inv, m2 = swb[b*4+2]*inv;
    float mx = fmaxf(m0, fmaxf(m1, m2));
    float e0 = expf(m0-mx), e1 = expf(m1-mx), e2 = expf(m2-mx);
    float s = e0 + e1 + e2;
    swb[b*4+0] = e0/s; swb[b*4+1] = e1/s; swb[b*4+2] = e2/s;
  }
}

// ---------------- graph adjacency ----------------
__global__ void k_adj(const float* __restrict__ nv1, const float* __restrict__ nv2,
                      float* __restrict__ a32) {
  int v = threadIdx.x;
  if (v < C_) {
    float row[C_];
    for (int w = 0; w < C_; ++w) {
      float s = 0.f;
      for (int d = 0; d < 10; ++d) s += nv1[v * 10 + d] * nv2[d * C_ + w];
      row[w] = fmaxf(s, 0.f);
    }
    float mx = -1e30f;
    for (int w = 0; w < C_; ++w) mx = fmaxf(mx, row[w]);
    float sm = 0.f;
    for (int w = 0; w < C_; ++w) { row[w] = expf(row[w] - mx); sm += row[w]; }
    for (int w = 0; w < C_; ++w) row[w] /= sm;
    row[v] += 1.0f;
    float rs = 0.f;
    for (int w = 0; w < C_; ++w) rs += row[w];
    for (int w = 0; w < C_; ++w) a32[v * C_ + w] = row[w] / rs;
  }
}

// ---------------- weight hi/lo split ----------------
__global__ void k_split(const float* __restrict__ src, unsigned short* __restrict__ Hi,
                        unsigned short* __restrict__ Lo, int n) {
  int i = blockIdx.x * 256 + threadIdx.x;
  if (i * 4 >= n) return;
  float4 v = *(const float4*)&src[i * 4];
  float vv[4] = {v.x, v.y, v.z, v.w};
  ushort4 h, l;
  unsigned short hs[4], ls[4];
#pragma unroll
  for (int j = 0; j < 4; ++j) {
    unsigned short hh = f2bf(vv[j]);
    hs[j] = hh;
    ls[j] = f2bf(vv[j] - bf2f(hh));
  }
  h.x = hs[0]; h.y = hs[1]; h.z = hs[2]; h.w = hs[3];
  l.x = ls[0]; l.y = ls[1]; l.z = ls[2]; l.w = ls[3];
  *(ushort4*)&Hi[i * 4] = h;
  *(ushort4*)&Lo[i * 4] = l;
}

// ---------------- dense conv weight build (split planes) ----------------
__global__ void k_wd(const float* __restrict__ swi, const float* __restrict__ sbi,
                     unsigned short* __restrict__ WdH, unsigned short* __restrict__ WdL,
                     float* __restrict__ b1k) {
  int idx = blockIdx.x * 256 + threadIdx.x;
  if (idx < 1024 * N_) {
    int row = idx >> 9, j = idx & 511;
    int o = row >> 5, n = row & 31;
    int k = j - n;
    float v = (k >= 0 && k < KH_) ? swi[o * KH_ + k] : 0.f;
    unsigned short h = f2bf(v);
    WdH[idx] = h;
    WdL[idx] = f2bf(v - bf2f(h));
    if (j == 0) b1k[row] = sbi[o];
  }
}

// ---------------- split-bf16 MFMA GEMM ----------------
// C[M][N] = A[M][lda](fp32) @ W[N][K]^T, W pre-split into Bh+Bl bf16 planes.
// a*b ~= ah*bh + al*bh + ah*bl (3 MFMAs). 128x128 tile, 4 waves (2x2 of 64x64),
// 16x16x32 MFMA. LDS tiles [128 rows][32 k] bf16 with 16B-slot XOR swizzle
// slot^((row>>1)&3) -> 2-way bank aliasing (free). Split-K via gridDim.z.
__global__ __launch_bounds__(256, 2) void k_mm(
    const float* __restrict__ A, const unsigned short* __restrict__ Bh,
    const unsigned short* __restrict__ Bl, const float* __restrict__ bias,
    float* __restrict__ C, float* __restrict__ Cpart,
    int M, int N, int K, int lda, const int* __restrict__ Mdyn, int dogelu) {
  if (Mdyn) M = *Mdyn;
  const int bm = blockIdx.y * 128;
  if (bm >= M) return;
  const int bn = blockIdx.x * 128;
  const int nz = gridDim.z, z = blockIdx.z;
  const int kpb = K / nz;
  const int kbeg = z * kpb, kend = kbeg + kpb;

  __shared__ unsigned short AhS[4096], AlS[4096], BhS[4096], BlS[4096];

  const int tid = threadIdx.x;
  const int wave = tid >> 6, lane = tid & 63;
  const int wr = wave >> 1, wc = wave & 1;
  const int fr = lane & 15, fs = lane >> 4;

  // staging: thread -> (row sr, 2 consecutive 16B k-slots ss, ss+1)
  const int sr = tid >> 1, ss = (tid & 1) * 2;
  const int sx = (sr >> 1) & 3;
  const int so0 = sr * 32 + 8 * (ss ^ sx);
  const int so1 = sr * 32 + 8 * ((ss + 1) ^ sx);

  int aoff[4], boff[4];
#pragma unroll
  for (int m = 0; m < 4; ++m) {
    int ra = wr * 64 + m * 16 + fr;
    aoff[m] = ra * 32 + 8 * (fs ^ ((ra >> 1) & 3));
    int rb = wc * 64 + m * 16 + fr;
    boff[m] = rb * 32 + 8 * (fs ^ ((rb >> 1) & 3));
  }

  const bool aok = (bm + sr) < M;
  const float* Arow = A + (size_t)(bm + sr) * lda + ss * 8;
  const unsigned short* BhRow = Bh + (size_t)(bn + sr) * K + ss * 8;
  const unsigned short* BlRow = Bl + (size_t)(bn + sr) * K + ss * 8;

  f32x4 acc[4][4];
#pragma unroll
  for (int m = 0; m < 4; ++m)
#pragma unroll
    for (int n = 0; n < 4; ++n) acc[m][n] = (f32x4){0.f, 0.f, 0.f, 0.f};

  for (int k0 = kbeg; k0 < kend; k0 += 32) {
    float4 a0, a1, a2, a3;
    if (aok) {
      const float4* p = (const float4*)(Arow + k0);
      a0 = p[0]; a1 = p[1]; a2 = p[2]; a3 = p[3];
    } else {
      a0 = a1 = a2 = a3 = make_float4(0.f, 0.f, 0.f, 0.f);
    }
    u16x8 gb0 = *(const u16x8*)(BhRow + k0);
    u16x8 gb1 = *(const u16x8*)(BhRow + k0 + 8);
    u16x8 gl0 = *(const u16x8*)(BlRow + k0);
    u16x8 gl1 = *(const u16x8*)(BlRow + k0 + 8);
    float av[16];
    av[0]=a0.x; av[1]=a0.y; av[2]=a0.z; av[3]=a0.w;
    av[4]=a1.x; av[5]=a1.y; av[6]=a1.z; av[7]=a1.w;
    av[8]=a2.x; av[9]=a2.y; av[10]=a2.z; av[11]=a2.w;
    av[12]=a3.x; av[13]=a3.y; av[14]=a3.z; av[15]=a3.w;
    u16x8 h0, h1, l0, l1;
#pragma unroll
    for (int j = 0; j < 8; ++j) {   // truncation split: err <= 2^-16 rel
      unsigned u = __float_as_uint(av[j]);
      h0[j] = (unsigned short)(u >> 16);
      float r2 = av[j] - __uint_as_float(u & 0xffff0000u);
      l0[j] = (unsigned short)(__float_as_uint(r2) >> 16);
      unsigned u2 = __float_as_uint(av[j + 8]);
      h1[j] = (unsigned short)(u2 >> 16);
      float r3 = av[j + 8] - __uint_as_float(u2 & 0xffff0000u);
      l1[j] = (unsigned short)(__float_as_uint(r3) >> 16);
    }
    __syncthreads();   // previous step's frag reads done
    *(u16x8*)&AhS[so0] = h0; *(u16x8*)&AhS[so1] = h1;
    *(u16x8*)&AlS[so0] = l0; *(u16x8*)&AlS[so1] = l1;
    *(u16x8*)&BhS[so0] = gb0; *(u16x8*)&BhS[so1] = gb1;
    *(u16x8*)&BlS[so0] = gl0; *(u16x8*)&BlS[so1] = gl1;
    __syncthreads();
    bf8 ah[4], al4[4], bh4[4], bl4[4];
#pragma unroll
    for (int m = 0; m < 4; ++m) {
      ah[m]  = *(const bf8*)&AhS[aoff[m]];
      al4[m] = *(const bf8*)&AlS[aoff[m]];
    }
#pragma unroll
    for (int n = 0; n < 4; ++n) {
      bh4[n] = *(const bf8*)&BhS[boff[n]];
      bl4[n] = *(const bf8*)&BlS[boff[n]];
    }
#pragma unroll
    for (int m = 0; m < 4; ++m)
#pragma unroll
      for (int n = 0; n < 4; ++n) {
        acc[m][n] = __builtin_amdgcn_mfma_f32_16x16x32_bf16(ah[m],  bh4[n], acc[m][n], 0, 0, 0);
        acc[m][n] = __builtin_amdgcn_mfma_f32_16x16x32_bf16(al4[m], bh4[n], acc[m][n], 0, 0, 0);
        acc[m][n] = __builtin_amdgcn_mfma_f32_16x16x32_bf16(ah[m],  bl4[n], acc[m][n], 0, 0, 0);
      }
  }

  if (nz > 1) {
    float* P = Cpart + (size_t)z * M * N;
#pragma unroll
    for (int m = 0; m < 4; ++m)
#pragma unroll
      for (int r = 0; r < 4; ++r) {
        int row = bm + wr * 64 + m * 16 + fs * 4 + r;
        if (row < M) {
#pragma unroll
          for (int n = 0; n < 4; ++n) {
            int col = bn + wc * 64 + n * 16 + fr;
            P[(size_t)row * N + col] = acc[m][n][r];
          }
        }
      }
  } else {
    float bcol[4];
#pragma unroll
    for (int n = 0; n < 4; ++n) bcol[n] = bias ? bias[bn + wc * 64 + n * 16 + fr] : 0.f;
#pragma unroll
    for (int m = 0; m < 4; ++m)
#pragma unroll
      for (int r = 0; r < 4; ++r) {
        int row = bm + wr * 64 + m * 16 + fs * 4 + r;
        if (row < M) {
#pragma unroll
          for (int n = 0; n < 4; ++n) {
            int col = bn + wc * 64 + n * 16 + fr;
            float v = acc[m][n][r] + bcol[n];
            if (dogelu) v = gelu_exact(v);
            C[(size_t)row * N + col] = v;
          }
        }
      }
  }
}

// ---------------- split-K reduce (+bias) for end GEMM ----------------
__global__ void k_red(const float* __restrict__ part, const float* __restrict__ eb,
                      float* __restrict__ osm) {
  int idx = blockIdx.x * 256 + threadIdx.x;   // 1024*512
  float s = eb[idx & 511];
#pragma unroll
  for (int zz = 0; zz < 8; ++zz) s += part[(size_t)zz * 524288 + idx];
  osm[idx] = s;
}

// ---------------- GCN propagate + mix + gelu (per token) ----------------
__global__ __launch_bounds__(256) void k_gcnmix(const float* __restrict__ Hb,
                                                const float* __restrict__ a32,
                                                const float* __restrict__ mw,
                                                const float* __restrict__ mb,
                                                float* __restrict__ G) {
  __shared__ float X[3][C_][C_];
  __shared__ float am[C_ * 33];
  __shared__ float mwl[C_ * 96];
  __shared__ float mbl[C_];
  size_t tok = blockIdx.x;
  int tid = threadIdx.x;
  for (int i = tid; i < C_ * C_; i += 256) am[(i >> 5) * 33 + (i & 31)] = a32[i];
  for (int i = tid; i < C_ * 96; i += 256) mwl[i] = mw[i];
  if (tid < C_) mbl[tid] = mb[tid];
  for (int i = tid; i < 1024; i += 256) X[0][i >> 5][i & 31] = Hb[tok * 1024 + i];
  __syncthreads();
#pragma unroll
  for (int dep = 1; dep <= 2; ++dep) {
    for (int i = tid; i < 1024; i += 256) {
      int c = i >> 5, v = i & 31;
      float s = 0.f;
      for (int w = 0; w < C_; ++w) s += X[dep - 1][c][w] * am[v * 33 + w];
      X[dep][c][v] = ALPHA_ * X[0][c][v] + (1.0f - ALPHA_) * s;
    }
    __syncthreads();
  }
  for (int i = tid; i < 1024; i += 256) {
    int o = i >> 5, v = i & 31;
    float s = mbl[o];
    for (int cc = 0; cc < 96; ++cc) s += mwl[o * 96 + cc] * X[cc >> 5][cc & 31][v];
    G[tok * 1024 + i] = gelu_exact(s);
  }
}

// ---------------- repack G[(b,s),(c,n)] -> G2[(b,n),(c,s)] ----------------
__global__ __launch_bounds__(256) void k_repack(const float* __restrict__ G,
                                                float* __restrict__ G2) {
  int bid = blockIdx.x;
  int st = bid & 15, c = (bid >> 4) & 31, b = bid >> 9;
  __shared__ float tile[32][33];
  int tid = threadIdx.x;
  int n = tid & 31, s = tid >> 5;
  for (int q = 0; q < 4; ++q) {
    int ss = s + q * 8;
    tile[ss][n] = G[((size_t)b * T_ + st * 32 + ss) * 1024 + c * 32 + n];
  }
  __syncthreads();
  int s2 = tid & 31, n2 = tid >> 5;
  for (int q = 0; q < 4; ++q) {
    int nn = n2 + q * 8;
    G2[((size_t)b * 32 + nn) * 16384 + c * 512 + st * 32 + s2] = tile[s2][nn];
  }
}

// ---------------- lw projection + residual + LN (graph epilogue) ----------------
__global__ __launch_bounds__(256) void k_lwln(const float* __restrict__ osm,
                                              const float* __restrict__ lw,
                                              const float* __restrict__ lb,
                                              const float* __restrict__ curIn,
                                              const float* __restrict__ g,
                                              const float* __restrict__ bt,
                                              float* __restrict__ curOut) {
  int tok = blockIdx.x;
  int b = tok >> 9, t = tok & 511;
  __shared__ float os[C_];
  __shared__ float red[256];
  int tid = threadIdx.x;
  if (tid < C_) os[tid] = osm[((size_t)b * C_ + tid) * T_ + t];
  __syncthreads();
  float val[2];
#pragma unroll
  for (int q = 0; q < 2; ++q) {
    int m = tid + q * 256;
    float s = lb[m] + curIn[(size_t)tok * N_ + m];
    for (int n2 = 0; n2 < C_; ++n2) s += os[n2] * lw[n2 * N_ + m];
    val[q] = s;
  }
  red[tid] = val[0] + val[1];
  __syncthreads();
  for (int off = 128; off > 0; off >>= 1) { if (tid < off) red[tid] += red[tid + off]; __syncthreads(); }
  float mean = red[0] * (1.0f / N_);
  __syncthreads();
  float d0 = val[0] - mean, d1 = val[1] - mean;
  red[tid] = d0 * d0 + d1 * d1;
  __syncthreads();
  for (int off = 128; off > 0; off >>= 1) { if (tid < off) red[tid] += red[tid + off]; __syncthreads(); }
  float inv = rsqrtf(red[0] * (1.0f / N_) + EPS_);
  curOut[(size_t)tok * N_ + tid] = d0 * inv * g[tid] + bt[tid];
  curOut[(size_t)tok * N_ + tid + 256] = d1 * inv * g[tid + 256] + bt[tid + 256];
}

// ---------------- zero-pad tokens ----------------
__global__ void k_pad(const float* __restrict__ cur, float* __restrict__ xa,
                      const int* __restrict__ meta, int iter) {
  int L = meta[6 + iter];
  size_t total = (size_t)(B_ * L) * N_;
  for (size_t idx = (size_t)blockIdx.x * 256 + threadIdx.x; idx < total;
       idx += (size_t)gridDim.x * 256) {
    size_t tokd = idx >> 9;
    int d = (int)(idx & 511);
    int b = (int)(tokd / L), l = (int)(tokd % L);
    xa[idx] = (l < T_) ? cur[((size_t)b * T_ + l) * N_ + d] : 0.f;
  }
}

// ---------------- residual add + LN (attention) ----------------
__global__ __launch_bounds__(256) void k_lnadd(const float* __restrict__ r1,
                                               const float* __restrict__ r2,
                                               const float* __restrict__ g,
                                               const float* __restrict__ bt,
                                               float* __restrict__ dst,
                                               const int* __restrict__ meta, int iter) {
  int tokens = meta[15 + iter];
  int tok = blockIdx.x;
  if (tok >= tokens) return;
  __shared__ float red[256];
  int tid = threadIdx.x;
  float val[2];
#pragma unroll
  for (int q = 0; q < 2; ++q) {
    int m = tid + q * 256;
    val[q] = r1[(size_t)tok * N_ + m] + r2[(size_t)tok * N_ + m];
  }
  red[tid] = val[0] + val[1];
  __syncthreads();
  for (int off = 128; off > 0; off >>= 1) { if (tid < off) red[tid] += red[tid + off]; __syncthreads(); }
  float mean = red[0] * (1.0f / N_);
  __syncthreads();
  float d0 = val[0] - mean, d1 = val[1] - mean;
  red[tid] = d0 * d0 + d1 * d1;
  __syncthreads();
  for (int off = 128; off > 0; off >>= 1) { if (tid < off) red[tid] += red[tid + off]; __syncthreads(); }
  float inv = rsqrtf(red[0] * (1.0f / N_) + EPS_);
  dst[(size_t)tok * N_ + tid] = d0 * inv * g[tid] + bt[tid];
  dst[(size_t)tok * N_ + tid + 256] = d1 * inv * g[tid + 256] + bt[tid + 256];
}

// ---------------- fused attention, S<=128, fp32 K/V in LDS ----------------
// K stored transposed Ks[64][129] (conflict-free per-lane-t reads); V row-major.
__global__ __launch_bounds__(256) void k_attn_small(const float* __restrict__ qb,
                                                    const float* __restrict__ kb,
                                                    const float* __restrict__ vb,
                                                    float* __restrict__ ob,
                                                    const int* __restrict__ meta, int iter) {
  int p = meta[3 + iter];
  if (p > 128) return;
  int L = meta[6 + iter], nseq = meta[9 + iter];
  int M = B_ * nseq;
  int mh = blockIdx.x;
  int m = mh >> 3, h = mh & 7;
  if (m >= M) return;
  int S = p;
  int b = m / nseq, g2 = m % nseq;
  size_t tok0 = (size_t)b * L + (size_t)g2 * S;
  __shared__ float Ks[64 * 129];
  __shared__ float Vs[128 * 65];
  __shared__ float qrow[4][64];
  __shared__ float Pr[4][128];
  int tid = threadIdx.x;
  for (int i = tid; i < S * 64; i += 256) {
    int t = i >> 6, d = i & 63;
    float kv = kb[(tok0 + t) * N_ + h * 64 + d];
    float vv = vb[(tok0 + t) * N_ + h * 64 + d];
    Ks[d * 129 + t] = kv;
    Vs[t * 65 + d] = vv;
  }
  __syncthreads();
  int wave = tid >> 6, lane = tid & 63;
  int rounds = (S + 3) >> 2;
  for (int r = 0; r < rounds; ++r) {
    int s = r * 4 + wave;
    bool act = (s < S);
    if (act) qrow[wave][lane] = qb[(tok0 + s) * N_ + h * 64 + lane];
    __syncthreads();
    float sc[2];
    float ssum = 0.f;
    if (act) {
      float mx = -3.0e38f;
#pragma unroll
      for (int c2 = 0; c2 < 2; ++c2) {
        int t = lane + c2 * 64;
        float sv = -3.0e38f;
        if (t < S) {
          float ad = 0.f;
#pragma unroll 16
          for (int j = 0; j < 64; ++j) ad += qrow[wave][j] * Ks[j * 129 + t];
          sv = ad * 0.125f;
        }
        sc[c2] = sv;
        mx = fmaxf(mx, sv);
      }
      for (int off = 32; off > 0; off >>= 1) mx = fmaxf(mx, __shfl_xor(mx, off));
#pragma unroll
      for (int c2 = 0; c2 < 2; ++c2) {
        int t = lane + c2 * 64;
        float e = 0.f;
        if (t < S) { e = expf(sc[c2] - mx); Pr[wave][t] = e; }
        ssum += e;
      }
      for (int off = 32; off > 0; off >>= 1) ssum += __shfl_xor(ssum, off);
    }
    __syncthreads();
    if (act) {
      float inv = 1.0f / ssum;
      float ov = 0.f;
      for (int t = 0; t < S; ++t) ov += Pr[wave][t] * Vs[t * 65 + lane];
      ob[(tok0 + s) * N_ + h * 64 + lane] = ov * inv;
    }
    __syncthreads();
  }
}

// ---------------- fused attention, 128<S<=512, bf16 K/V (rare path) ----------------
__global__ __launch_bounds__(256) void k_attn_big(const float* __restrict__ qb,
                                                  const float* __restrict__ kb,
                                                  const float* __restrict__ vb,
                                                  float* __restrict__ ob,
                                                  const int* __restrict__ meta, int iter) {
  int p = meta[3 + iter];
  if (p <= 128) return;
  int L = meta[6 + iter], nseq = meta[9 + iter];
  int M = B_ * nseq;
  int mh = blockIdx.x;
  int m = mh >> 3, h = mh & 7;
  if (m >= M) return;
  int S = p;
  int b = m / nseq, g2 = m % nseq;
  size_t tok0 = (size_t)b * L + (size_t)g2 * S;
  __shared__ unsigned short Ks[512 * 66];
  __shared__ unsigned short Vs[512 * 66];
  __shared__ float qrow[4][64];
  __shared__ float Pr[4][512];
  int tid = threadIdx.x;
  for (int i = tid; i < S * 64; i += 256) {
    int t = i >> 6, d = i & 63;
    Ks[t * 66 + d] = f2bf(kb[(tok0 + t) * N_ + h * 64 + d]);
    Vs[t * 66 + d] = f2bf(vb[(tok0 + t) * N_ + h * 64 + d]);
  }
  __syncthreads();
  int wave = tid >> 6, lane = tid & 63;
  int rounds = (S + 3) >> 2;
  for (int r = 0; r < rounds; ++r) {
    int s = r * 4 + wave;
    bool act = (s < S);
    if (act) qrow[wave][lane] = qb[(tok0 + s) * N_ + h * 64 + lane];
    __syncthreads();
    float sc[8];
    float ssum = 0.f;
    if (act) {
      const float2* qp = (const float2*)&qrow[wave][0];
      float mx = -3.0e38f;
#pragma unroll
      for (int c2 = 0; c2 < 8; ++c2) {
        int t = lane + c2 * 64;
        float sv = -3.0e38f;
        if (t < S) {
          const unsigned int* kp = (const unsigned int*)&Ks[t * 66];
          float ad = 0.f;
#pragma unroll
          for (int j2 = 0; j2 < 32; ++j2) {
            float2 qq = qp[j2];
            unsigned int kw = kp[j2];
            ad += qq.x * bf2f((unsigned short)(kw & 0xffffu));
            ad += qq.y * bf2f((unsigned short)(kw >> 16));
          }
          sv = ad * 0.125f;
        }
        sc[c2] = sv;
        mx = fmaxf(mx, sv);
      }
      for (int off = 32; off > 0; off >>= 1) mx = fmaxf(mx, __shfl_xor(mx, off));
#pragma unroll
      for (int c2 = 0; c2 < 8; ++c2) {
        int t = lane + c2 * 64;
        float e = 0.f;
        if (t < S) { e = expf(sc[c2] - mx); Pr[wave][t] = e; }
        ssum += e;
      }
      for (int off = 32; off > 0; off >>= 1) ssum += __shfl_xor(ssum, off);
    }
    __syncthreads();
    if (act) {
      float inv = 1.0f / ssum;
      float ov = 0.f;
      for (int t = 0; t < S; ++t) ov += Pr[wave][t] * bf2f(Vs[t * 66 + lane]);
      ob[(tok0 + s) * N_ + h * 64 + lane] = ov * inv;
    }
    __syncthreads();
  }
}

// ---------------- final LN + gelu + weighted accumulate ----------------
__global__ __launch_bounds__(256) void k_fin(const float* __restrict__ y,
                                             const float* __restrict__ g,
                                             const float* __restrict__ bt,
                                             const float* __restrict__ swb,
                                             float* __restrict__ acc,
                                             const int* __restrict__ meta, int iter) {
  int L = meta[6 + iter];
  int tokens = B_ * L;
  int tok = blockIdx.x;
  if (tok >= tokens) return;
  int b = tok / L, l = tok % L;
  if (l >= T_) return;   // truncated away
  __shared__ float red[256];
  int tid = threadIdx.x;
  float val[2];
#pragma unroll
  for (int q = 0; q < 2; ++q) val[q] = y[(size_t)tok * N_ + tid + q * 256];
  red[tid] = val[0] + val[1];
  __syncthreads();
  for (int off = 128; off > 0; off >>= 1) { if (tid < off) red[tid] += red[tid + off]; __syncthreads(); }
  float mean = red[0] * (1.0f / N_);
  __syncthreads();
  float d0 = val[0] - mean, d1 = val[1] - mean;
  red[tid] = d0 * d0 + d1 * d1;
  __syncthreads();
  for (int off = 128; off > 0; off >>= 1) { if (tid < off) red[tid] += red[tid + off]; __syncthreads(); }
  float inv = rsqrtf(red[0] * (1.0f / N_) + EPS_);
  float s = swb[b * 4 + iter];
  float u0 = gelu_exact(d0 * inv * g[tid] + bt[tid]);
  float u1 = gelu_exact(d1 * inv * g[tid + 256] + bt[tid + 256]);
  size_t o = ((size_t)b * T_ + l) * N_;
  acc[o + tid] += s * u0;
  acc[o + tid + 256] += s * u1;
}

// ---------------- final output ----------------
__global__ void k_final(const float* __restrict__ acc, const float* __restrict__ cur,
                        float* __restrict__ out) {
  size_t idx = (size_t)blockIdx.x * 256 + threadIdx.x;
  out[idx] = acc[idx] + cur[idx];
}

extern "C" void kernel_launch(void* const* d_in, const int* in_sizes, int n_in,
                              void* d_out, int out_size, void* d_ws, size_t ws_size,
                              hipStream_t stream) {
  (void)in_sizes; (void)n_in; (void)out_size; (void)ws_size;
  const float* x       = (const float*)d_in[0];
  const float* nv1     = (const float*)d_in[1];
  const float* nv2     = (const float*)d_in[2];
  const float* start_w = (const float*)d_in[3];
  const float* start_b = (const float*)d_in[4];
  const float* mix_w   = (const float*)d_in[5];
  const float* mix_b   = (const float*)d_in[6];
  const float* end_w   = (const float*)d_in[7];
  const float* end_b   = (const float*)d_in[8];
  const float* glin_w  = (const float*)d_in[9];
  const float* glin_b  = (const float*)d_in[10];
  const float* gnorm_g = (const float*)d_in[11];
  const float* gnorm_b = (const float*)d_in[12];
  const float* wq = (const float*)d_in[13];
  const float* bq = (const float*)d_in[14];
  const float* wk = (const float*)d_in[15];
  const float* bk = (const float*)d_in[16];
  const float* wv = (const float*)d_in[17];
  const float* bv = (const float*)d_in[18];
  const float* wo = (const float*)d_in[19];
  const float* bo = (const float*)d_in[20];
  const float* ff1w = (const float*)d_in[21];
  const float* ff1b = (const float*)d_in[22];
  const float* ff2w = (const float*)d_in[23];
  const float* ff2b = (const float*)d_in[24];
  const float* an1g = (const float*)d_in[25];
  const float* an1b = (const float*)d_in[26];
  const float* an2g = (const float*)d_in[27];
  const float* an2b = (const float*)d_in[28];
  const float* nrmg = (const float*)d_in[29];
  const float* nrmb = (const float*)d_in[30];

  char* ws = (char*)d_ws;
  int*   meta = (int*)(ws + OFF_META);
  float* freq = (float*)(ws + OFF_FREQ);
  float* swb  = (float*)(ws + OFF_SW);
  float* a32  = (float*)(ws + OFF_A32);
  float* b1k  = (float*)(ws + OFF_B1K);
  float* osm  = (float*)(ws + OFF_OSM);
  unsigned short* WB  = (unsigned short*)(ws + OFF_WB);
  unsigned short* WdH = (unsigned short*)(ws + OFF_WDH);
  unsigned short* WdL = (unsigned short*)(ws + OFF_WDL);
  unsigned short* EWH = (unsigned short*)(ws + OFF_EWH);
  unsigned short* EWL = (unsigned short*)(ws + OFF_EWL);
  float* cur  = (float*)(ws + OFF_CUR);
  float* accb = (float*)(ws + OFF_ACC);
  float* R0g  = (float*)(ws + OFF_R0G);
  float* G    = (float*)(ws + OFF_G);
  float* G2   = (float*)(ws + OFF_G2);
  float* PART = (float*)(ws + OFF_PART);
  float* A0 = (float*)(ws + OFF_A0);
  float* A2 = (float*)(ws + OFF_A2);
  float* A3 = (float*)(ws + OFF_A3);
  float* A4 = (float*)(ws + OFF_A4);
  float* A5 = (float*)(ws + OFF_A5);

  hipMemsetAsync(freq, 0, NBIN_ * sizeof(float), stream);
  hipMemsetAsync(accb, 0, (size_t)B_ * T_ * N_ * 4, stream);

  k_stft_freq<<<B_ * NFR_, 256, 0, stream>>>(x, freq);
  k_topk<<<1, 64, 0, stream>>>(freq, meta);
  k_sw<<<B_, 256, 0, stream>>>(x, meta, swb);

  // split attention/FF weights into bf16 hi/lo planes (once)
  const float* wlist[6] = {wq, wk, wv, wo, ff1w, ff2w};
  for (int w = 0; w < 6; ++w)
    k_split<<<256, 256, 0, stream>>>(wlist[w], WB + (size_t)w * 2 * 262144,
                                     WB + (size_t)(w * 2 + 1) * 262144, 262144);
  unsigned short* WqH = WB;               unsigned short* WqL = WB + 262144;
  unsigned short* WkH = WB + 2 * 262144;  unsigned short* WkL = WB + 3 * 262144;
  unsigned short* WvH = WB + 4 * 262144;  unsigned short* WvL = WB + 5 * 262144;
  unsigned short* WoH = WB + 6 * 262144;  unsigned short* WoL = WB + 7 * 262144;
  unsigned short* F1H = WB + 8 * 262144;  unsigned short* F1L = WB + 9 * 262144;
  unsigned short* F2H = WB + 10 * 262144; unsigned short* F2L = WB + 11 * 262144;

  const float* curIn = x;
  for (int i = 0; i < 3; ++i) {
    // ---- graph block ----
    k_adj<<<1, 64, 0, stream>>>(nv1 + i * C_ * 10, nv2 + i * 10 * C_, a32);
    k_wd<<<2048, 256, 0, stream>>>(start_w + i * C_ * KH_, start_b + i * C_, WdH, WdL, b1k);
    k_split<<<8192, 256, 0, stream>>>(end_w + (size_t)i * 8388608, EWH, EWL, 8388608);
    k_mm<<<dim3(8, 128, 1), 256, 0, stream>>>(curIn, WdH, WdL, b1k, R0g, nullptr,
                                              16384, 1024, 512, 512, nullptr, 0);
    k_gcnmix<<<B_ * T_, 256, 0, stream>>>(R0g, a32, mix_w + i * C_ * 96, mix_b + i * C_, G);
    k_repack<<<B_ * C_ * 16, 256, 0, stream>>>(G, G2);
    k_mm<<<dim3(4, 8, 8), 256, 0, stream>>>(G2, EWH, EWL, nullptr, nullptr, PART,
                                            1024, 512, 16384, 16384, nullptr, 0);
    k_red<<<2048, 256, 0, stream>>>(PART, end_b + i * T_, osm);
    k_lwln<<<B_ * T_, 256, 0, stream>>>(osm, glin_w + i * C_ * N_, glin_b + i * N_, curIn,
                                        gnorm_g + i * N_, gnorm_b + i * N_, cur);
    // ---- attention branch ----
    const int* Mdyn = meta + 15 + i;
    k_pad<<<4096, 256, 0, stream>>>(cur, A0, meta, i);
    dim3 gT(4, TOKMAX / 128, 1);
    k_mm<<<gT, 256, 0, stream>>>(A0, WqH, WqL, bq, A2, nullptr, TOKMAX, 512, 512, 512, Mdyn, 0);
    k_mm<<<gT, 256, 0, stream>>>(A0, WkH, WkL, bk, A3, nullptr, TOKMAX, 512, 512, 512, Mdyn, 0);
    k_mm<<<gT, 256, 0, stream>>>(A0, WvH, WvL, bv, A4, nullptr, TOKMAX, 512, 512, 512, Mdyn, 0);
    k_attn_small<<<65536, 256, 0, stream>>>(A2, A3, A4, A5, meta, i);
    k_attn_big<<<1024, 256, 0, stream>>>(A2, A3, A4, A5, meta, i);
    k_mm<<<gT, 256, 0, stream>>>(A5, WoH, WoL, bo, A2, nullptr, TOKMAX, 512, 512, 512, Mdyn, 0);
    k_lnadd<<<TOKMAX, 256, 0, stream>>>(A0, A2, an1g, an1b, A3, meta, i);
    k_mm<<<gT, 256, 0, stream>>>(A3, F1H, F1L, ff1b, A4, nullptr, TOKMAX, 512, 512, 512, Mdyn, 1);
    k_mm<<<gT, 256, 0, stream>>>(A4, F2H, F2L, ff2b, A5, nullptr, TOKMAX, 512, 512, 512, Mdyn, 0);
    k_lnadd<<<TOKMAX, 256, 0, stream>>>(A3, A5, an2g, an2b, A0, meta, i);
    k_fin<<<TOKMAX, 256, 0, stream>>>(A0, nrmg, nrmb, swb, accb, meta, i);
    curIn = cur;
  }
  k_final<<<(B_ * T_ * N_) / 256, 256, 0, stream>>>(accb, curIn, (float*)d_out);
}

// Round 3
// 3704.815 us; speedup vs baseline: 2.5742x; 1.1425x over previous
//
#include <hip/hip_runtime.h>
#include <math.h>

#define DI __device__ __forceinline__

namespace {
constexpr int B_ = 32;
constexpr int T_ = 512;
constexpr int N_ = 512;   // d_model
constexpr int C_ = 32;    // c_out / conv_ch / skip_ch
constexpr int KH_ = 481;
constexpr int HOP_ = 48;
constexpr int WIN_ = 48;
constexpr int NFR_ = 11;
constexpr int NBIN_ = 257;
constexpr int NSB_ = 4 * NFR_ * B_;   // 1408 stft blocks
constexpr int TOKMAX = 22528;   // 176*128 >= max possible tokens (21760)
constexpr float EPS_ = 1e-5f;
constexpr float ALPHA_ = 0.05f;

constexpr size_t MBY = 1ull << 20;
constexpr size_t OFF_META = 0;
constexpr size_t OFF_FREQ = 4096;
constexpr size_t OFF_SW   = 8192;
constexpr size_t OFF_A32  = 12288;
constexpr size_t OFF_B1K  = 16384;
constexpr size_t OFF_OSM  = 1 * MBY;     // 2MB
constexpr size_t OFF_WB   = 4 * MBY;     // 12 planes x 512KB = 6MB
constexpr size_t OFF_WDH  = 10 * MBY;    // 1MB
constexpr size_t OFF_WDL  = 11 * MBY;    // 1MB
constexpr size_t OFF_EWH  = 12 * MBY;    // 16MB
constexpr size_t OFF_EWL  = 28 * MBY;    // 16MB
constexpr size_t OFF_CUR  = 44 * MBY;    // 32MB
constexpr size_t OFF_ACC  = 76 * MBY;    // 32MB
constexpr size_t TR       = 108 * MBY;   // transient union region
// graph phase
constexpr size_t OFF_R0G  = TR;            // 64MB [16384][1024]
constexpr size_t OFF_G    = TR + 64 * MBY; // 64MB
constexpr size_t OFF_G2   = TR + 128 * MBY;// 64MB [1024][16384]
constexpr size_t OFF_PART = TR + 192 * MBY;// 16MB [8][1024][512]
// attention phase (aliases graph region)
constexpr size_t OFF_A0 = TR;              // 44MB each
constexpr size_t OFF_A2 = TR + 44 * MBY;
constexpr size_t OFF_A3 = TR + 88 * MBY;
constexpr size_t OFF_A4 = TR + 132 * MBY;
constexpr size_t OFF_A5 = TR + 176 * MBY;  // ends 328MB
// stft partials alias TR (stft completes before graph phase starts)
constexpr size_t OFF_FP = TR;              // NBIN_*NSB_ floats ~1.45MB
} // namespace

typedef __attribute__((ext_vector_type(4))) float f32x4;
typedef __attribute__((ext_vector_type(8))) short bf8;
typedef __attribute__((ext_vector_type(8))) unsigned short u16x8;

DI float gelu_exact(float x) { return 0.5f * x * (1.0f + erff(x * 0.7071067811865475f)); }
DI unsigned short f2bf(float f) {   // round-to-nearest-even
  unsigned u = __float_as_uint(f);
  u += 0x7FFFu + ((u >> 16) & 1u);
  return (unsigned short)(u >> 16);
}
DI float bf2f(unsigned short s) { return __uint_as_float(((unsigned)s) << 16); }

// ---------------- STFT via phasor recurrence ----------------
// block = (b, frame, 128-ch chunk). LDS holds windowed frame chunk only (24KB).
// Each (k, 8-ch) task: exact-reduced start angle + per-tap rotation.
// Partial per-(block,k) magnitude sums -> fpart[k][blk]  (deterministic).
__global__ __launch_bounds__(256) void k_stft2(const float* __restrict__ x,
                                               float* __restrict__ fpart) {
  int bid = blockIdx.x;
  int cc = bid & 3;
  int f = (bid >> 2) % NFR_;
  int b = bid / (4 * NFR_);
  __shared__ float xw[WIN_][128];
  int tid = threadIdx.x;
  for (int i = tid; i < WIN_ * 128; i += 256) {
    int j = i >> 7, n = i & 127;
    int gi = f * HOP_ + 232 + j - 256;
    if (gi < 0) gi = -gi;   // reflect pad (left only)
    float w = 0.5f - 0.5f * cosf((float)j * 0.13089969389957472f);   // 2pi/48
    xw[j][n] = w * x[((size_t)b * T_ + gi) * N_ + cc * 128 + n];
  }
  __syncthreads();
  // tasks: (k in [0,257)) x (16 chunks of 8 channels) = 4112
  for (int pair = tid; pair < NBIN_ * 16; pair += 256) {
    int k = pair >> 4;
    int n8 = (pair & 15) * 8;
    int r0 = (k * 232) & 511;                       // exact angle reduction
    float a0 = (float)r0 * 0.012271846303085130f;   // 2pi/512
    float c = cosf(a0), s = sinf(a0);
    float dA = (float)k * 0.012271846303085130f;
    float cd = cosf(dA), sd = sinf(dA);
    float re[8] = {0,0,0,0,0,0,0,0}, im[8] = {0,0,0,0,0,0,0,0};
    const float* xp = &xw[0][n8];
#pragma unroll 4
    for (int j = 0; j < WIN_; ++j) {
      float4 v0 = *(const float4*)xp;
      float4 v1 = *(const float4*)(xp + 4);
      re[0] += v0.x * c; im[0] += v0.x * s;
      re[1] += v0.y * c; im[1] += v0.y * s;
      re[2] += v0.z * c; im[2] += v0.z * s;
      re[3] += v0.w * c; im[3] += v0.w * s;
      re[4] += v1.x * c; im[4] += v1.x * s;
      re[5] += v1.y * c; im[5] += v1.y * s;
      re[6] += v1.z * c; im[6] += v1.z * s;
      re[7] += v1.w * c; im[7] += v1.w * s;
      float cn = c * cd - s * sd;
      s = s * cd + c * sd;
      c = cn;
      xp += 128;
    }
    float m = 0.f;
#pragma unroll
    for (int q = 0; q < 8; ++q) m += sqrtf(re[q] * re[q] + im[q] * im[q]);
    // reduce the 16 lanes sharing k (lane groups are 16-aligned)
    for (int off = 8; off > 0; off >>= 1) m += __shfl_xor(m, off);
    if ((tid & 15) == 0) fpart[(size_t)k * NSB_ + bid] = m;
  }
}

// ---------------- deterministic partial reduce -> freq ----------------
__global__ __launch_bounds__(256) void k_fred(const float* __restrict__ fpart,
                                              float* __restrict__ freq) {
  int k = blockIdx.x;
  __shared__ float red[256];
  int tid = threadIdx.x;
  float s = 0.f;
  for (int bb = tid; bb < NSB_; bb += 256) s += fpart[(size_t)k * NSB_ + bb];
  red[tid] = s;
  __syncthreads();
  for (int off = 128; off > 0; off >>= 1) {
    if (tid < off) red[tid] += red[tid + off];
    __syncthreads();
  }
  if (tid == 0) freq[k] = red[0];
}

// ---------------- top-k + meta ----------------
__global__ void k_topk(const float* __restrict__ freq, int* __restrict__ meta) {
  if (threadIdx.x == 0 && blockIdx.x == 0) {
    float bv[3] = {-1e30f, -1e30f, -1e30f};
    int bi[3] = {1, 1, 1};
    for (int k = 1; k < NBIN_; ++k) {
      float v = freq[k];
      if (v > bv[0]) { bv[2]=bv[1]; bi[2]=bi[1]; bv[1]=bv[0]; bi[1]=bi[0]; bv[0]=v; bi[0]=k; }
      else if (v > bv[1]) { bv[2]=bv[1]; bi[2]=bi[1]; bv[1]=v; bi[1]=k; }
      else if (v > bv[2]) { bv[2]=v; bi[2]=k; }
    }
    for (int i = 0; i < 3; ++i) {
      int top = bi[i];
      int p = T_ / top;
      int L = ((T_ + p - 1) / p) * p;
      meta[i] = top;
      meta[3 + i] = p;
      meta[6 + i] = L;
      meta[9 + i] = L / p;
      meta[15 + i] = B_ * L;   // tokens
    }
  }
}

// ---------------- per-batch branch weights sw ----------------
__global__ __launch_bounds__(256) void k_sw(const float* __restrict__ x,
                                            const int* __restrict__ meta,
                                            float* __restrict__ swb) {
  int b = blockIdx.x;
  __shared__ float ct[3][WIN_], st[3][WIN_];
  __shared__ float red[256];
  int tid = threadIdx.x;
  for (int i = tid; i < 3 * WIN_; i += 256) {
    int kk = i / WIN_, j = i % WIN_;
    int k = meta[kk];
    int r = (k * (232 + j)) & 511;
    float ang = (float)r * 0.012271846303085130f;
    float w = 0.5f - 0.5f * cosf((float)j * 0.13089969389957472f);
    ct[kk][j] = w * cosf(ang);
    st[kk][j] = w * sinf(ang);
  }
  __syncthreads();
  float acc[3] = {0.f, 0.f, 0.f};
  for (int it = tid; it < NFR_ * N_; it += 256) {
    int f = it / N_, n = it % N_;
    float xs[WIN_];
    for (int j = 0; j < WIN_; ++j) {
      int gi = f * HOP_ + 232 + j - 256;
      if (gi < 0) gi = -gi;
      xs[j] = x[((size_t)b * T_ + gi) * N_ + n];
    }
    for (int kk = 0; kk < 3; ++kk) {
      float re = 0.f, im = 0.f;
      for (int j = 0; j < WIN_; ++j) { re += xs[j] * ct[kk][j]; im += xs[j] * st[kk][j]; }
      acc[kk] += sqrtf(re * re + im * im);
    }
  }
  for (int kk = 0; kk < 3; ++kk) {
    red[tid] = acc[kk];
    __syncthreads();
    for (int off = 128; off > 0; off >>= 1) {
      if (tid < off) red[tid] += red[tid + off];
      __syncthreads();
    }
    if (tid == 0) swb[b * 4 + kk] = red[0];
    __syncthreads();
  }
  if (tid == 0) {
    float inv = 1.0f / (float)(NFR_ * N_);
    float m0 = swb[b*4+0]*inv, m1 = swb[b*4+1]*inv, m2 = swb[b*4+2]*inv;
    float mx = fmaxf(m0, fmaxf(m1, m2));
    float e0 = expf(m0-mx), e1 = expf(m1-mx), e2 = expf(m2-mx);
    float s = e0 + e1 + e2;
    swb[b*4+0] = e0/s; swb[b*4+1] = e1/s; swb[b*4+2] = e2/s;
  }
}

// ---------------- graph adjacency ----------------
__global__ void k_adj(const float* __restrict__ nv1, const float* __restrict__ nv2,
                      float* __restrict__ a32) {
  int v = threadIdx.x;
  if (v < C_) {
    float row[C_];
    for (int w = 0; w < C_; ++w) {
      float s = 0.f;
      for (int d = 0; d < 10; ++d) s += nv1[v * 10 + d] * nv2[d * C_ + w];
      row[w] = fmaxf(s, 0.f);
    }
    float mx = -1e30f;
    for (int w = 0; w < C_; ++w) mx = fmaxf(mx, row[w]);
    float sm = 0.f;
    for (int w = 0; w < C_; ++w) { row[w] = expf(row[w] - mx); sm += row[w]; }
    for (int w = 0; w < C_; ++w) row[w] /= sm;
    row[v] += 1.0f;
    float rs = 0.f;
    for (int w = 0; w < C_; ++w) rs += row[w];
    for (int w = 0; w < C_; ++w) a32[v * C_ + w] = row[w] / rs;
  }
}

// ---------------- weight hi/lo split ----------------
__global__ void k_split(const float* __restrict__ src, unsigned short* __restrict__ Hi,
                        unsigned short* __restrict__ Lo, int n) {
  int i = blockIdx.x * 256 + threadIdx.x;
  if (i * 4 >= n) return;
  float4 v = *(const float4*)&src[i * 4];
  float vv[4] = {v.x, v.y, v.z, v.w};
  ushort4 h, l;
  unsigned short hs[4], ls[4];
#pragma unroll
  for (int j = 0; j < 4; ++j) {
    unsigned short hh = f2bf(vv[j]);
    hs[j] = hh;
    ls[j] = f2bf(vv[j] - bf2f(hh));
  }
  h.x = hs[0]; h.y = hs[1]; h.z = hs[2]; h.w = hs[3];
  l.x = ls[0]; l.y = ls[1]; l.z = ls[2]; l.w = ls[3];
  *(ushort4*)&Hi[i * 4] = h;
  *(ushort4*)&Lo[i * 4] = l;
}

// ---------------- dense conv weight build (split planes) ----------------
__global__ void k_wd(const float* __restrict__ swi, const float* __restrict__ sbi,
                     unsigned short* __restrict__ WdH, unsigned short* __restrict__ WdL,
                     float* __restrict__ b1k) {
  int idx = blockIdx.x * 256 + threadIdx.x;
  if (idx < 1024 * N_) {
    int row = idx >> 9, j = idx & 511;
    int o = row >> 5, n = row & 31;
    int k = j - n;
    float v = (k >= 0 && k < KH_) ? swi[o * KH_ + k] : 0.f;
    unsigned short h = f2bf(v);
    WdH[idx] = h;
    WdL[idx] = f2bf(v - bf2f(h));
    if (j == 0) b1k[row] = sbi[o];
  }
}

// ---------------- split-bf16 MFMA GEMM ----------------
// C[M][N] = A[M][lda](fp32) @ W[N][K]^T, W pre-split into Bh+Bl bf16 planes.
// a*b ~= ah*bh + al*bh + ah*bl (3 MFMAs). 128x128 tile, 4 waves (2x2 of 64x64),
// 16x16x32 MFMA. Split-K via gridDim.z.
__global__ __launch_bounds__(256, 2) void k_mm(
    const float* __restrict__ A, const unsigned short* __restrict__ Bh,
    const unsigned short* __restrict__ Bl, const float* __restrict__ bias,
    float* __restrict__ C, float* __restrict__ Cpart,
    int M, int N, int K, int lda, const int* __restrict__ Mdyn, int dogelu) {
  if (Mdyn) M = *Mdyn;
  const int bm = blockIdx.y * 128;
  if (bm >= M) return;
  const int bn = blockIdx.x * 128;
  const int nz = gridDim.z, z = blockIdx.z;
  const int kpb = K / nz;
  const int kbeg = z * kpb, kend = kbeg + kpb;

  __shared__ unsigned short AhS[4096], AlS[4096], BhS[4096], BlS[4096];

  const int tid = threadIdx.x;
  const int wave = tid >> 6, lane = tid & 63;
  const int wr = wave >> 1, wc = wave & 1;
  const int fr = lane & 15, fs = lane >> 4;

  const int sr = tid >> 1, ss = (tid & 1) * 2;
  const int sx = (sr >> 1) & 3;
  const int so0 = sr * 32 + 8 * (ss ^ sx);
  const int so1 = sr * 32 + 8 * ((ss + 1) ^ sx);

  int aoff[4], boff[4];
#pragma unroll
  for (int m = 0; m < 4; ++m) {
    int ra = wr * 64 + m * 16 + fr;
    aoff[m] = ra * 32 + 8 * (fs ^ ((ra >> 1) & 3));
    int rb = wc * 64 + m * 16 + fr;
    boff[m] = rb * 32 + 8 * (fs ^ ((rb >> 1) & 3));
  }

  const bool aok = (bm + sr) < M;
  const float* Arow = A + (size_t)(bm + sr) * lda + ss * 8;
  const unsigned short* BhRow = Bh + (size_t)(bn + sr) * K + ss * 8;
  const unsigned short* BlRow = Bl + (size_t)(bn + sr) * K + ss * 8;

  f32x4 acc[4][4];
#pragma unroll
  for (int m = 0; m < 4; ++m)
#pragma unroll
    for (int n = 0; n < 4; ++n) acc[m][n] = (f32x4){0.f, 0.f, 0.f, 0.f};

  for (int k0 = kbeg; k0 < kend; k0 += 32) {
    float4 a0, a1, a2, a3;
    if (aok) {
      const float4* p = (const float4*)(Arow + k0);
      a0 = p[0]; a1 = p[1]; a2 = p[2]; a3 = p[3];
    } else {
      a0 = a1 = a2 = a3 = make_float4(0.f, 0.f, 0.f, 0.f);
    }
    u16x8 gb0 = *(const u16x8*)(BhRow + k0);
    u16x8 gb1 = *(const u16x8*)(BhRow + k0 + 8);
    u16x8 gl0 = *(const u16x8*)(BlRow + k0);
    u16x8 gl1 = *(const u16x8*)(BlRow + k0 + 8);
    float av[16];
    av[0]=a0.x; av[1]=a0.y; av[2]=a0.z; av[3]=a0.w;
    av[4]=a1.x; av[5]=a1.y; av[6]=a1.z; av[7]=a1.w;
    av[8]=a2.x; av[9]=a2.y; av[10]=a2.z; av[11]=a2.w;
    av[12]=a3.x; av[13]=a3.y; av[14]=a3.z; av[15]=a3.w;
    u16x8 h0, h1, l0, l1;
#pragma unroll
    for (int j = 0; j < 8; ++j) {   // truncation split: err <= 2^-16 rel
      unsigned u = __float_as_uint(av[j]);
      h0[j] = (unsigned short)(u >> 16);
      float r2 = av[j] - __uint_as_float(u & 0xffff0000u);
      l0[j] = (unsigned short)(__float_as_uint(r2) >> 16);
      unsigned u2 = __float_as_uint(av[j + 8]);
      h1[j] = (unsigned short)(u2 >> 16);
      float r3 = av[j + 8] - __uint_as_float(u2 & 0xffff0000u);
      l1[j] = (unsigned short)(__float_as_uint(r3) >> 16);
    }
    __syncthreads();
    *(u16x8*)&AhS[so0] = h0; *(u16x8*)&AhS[so1] = h1;
    *(u16x8*)&AlS[so0] = l0; *(u16x8*)&AlS[so1] = l1;
    *(u16x8*)&BhS[so0] = gb0; *(u16x8*)&BhS[so1] = gb1;
    *(u16x8*)&BlS[so0] = gl0; *(u16x8*)&BlS[so1] = gl1;
    __syncthreads();
    bf8 ah[4], al4[4], bh4[4], bl4[4];
#pragma unroll
    for (int m = 0; m < 4; ++m) {
      ah[m]  = *(const bf8*)&AhS[aoff[m]];
      al4[m] = *(const bf8*)&AlS[aoff[m]];
    }
#pragma unroll
    for (int n = 0; n < 4; ++n) {
      bh4[n] = *(const bf8*)&BhS[boff[n]];
      bl4[n] = *(const bf8*)&BlS[boff[n]];
    }
#pragma unroll
    for (int m = 0; m < 4; ++m)
#pragma unroll
      for (int n = 0; n < 4; ++n) {
        acc[m][n] = __builtin_amdgcn_mfma_f32_16x16x32_bf16(ah[m],  bh4[n], acc[m][n], 0, 0, 0);
        acc[m][n] = __builtin_amdgcn_mfma_f32_16x16x32_bf16(al4[m], bh4[n], acc[m][n], 0, 0, 0);
        acc[m][n] = __builtin_amdgcn_mfma_f32_16x16x32_bf16(ah[m],  bl4[n], acc[m][n], 0, 0, 0);
      }
  }

  if (nz > 1) {
    float* P = Cpart + (size_t)z * M * N;
#pragma unroll
    for (int m = 0; m < 4; ++m)
#pragma unroll
      for (int r = 0; r < 4; ++r) {
        int row = bm + wr * 64 + m * 16 + fs * 4 + r;
        if (row < M) {
#pragma unroll
          for (int n = 0; n < 4; ++n) {
            int col = bn + wc * 64 + n * 16 + fr;
            P[(size_t)row * N + col] = acc[m][n][r];
          }
        }
      }
  } else {
    float bcol[4];
#pragma unroll
    for (int n = 0; n < 4; ++n) bcol[n] = bias ? bias[bn + wc * 64 + n * 16 + fr] : 0.f;
#pragma unroll
    for (int m = 0; m < 4; ++m)
#pragma unroll
      for (int r = 0; r < 4; ++r) {
        int row = bm + wr * 64 + m * 16 + fs * 4 + r;
        if (row < M) {
#pragma unroll
          for (int n = 0; n < 4; ++n) {
            int col = bn + wc * 64 + n * 16 + fr;
            float v = acc[m][n][r] + bcol[n];
            if (dogelu) v = gelu_exact(v);
            C[(size_t)row * N + col] = v;
          }
        }
      }
  }
}

// ---------------- split-K reduce (+bias) for end GEMM ----------------
__global__ void k_red(const float* __restrict__ part, const float* __restrict__ eb,
                      float* __restrict__ osm) {
  int idx = blockIdx.x * 256 + threadIdx.x;   // 1024*512
  float s = eb[idx & 511];
#pragma unroll
  for (int zz = 0; zz < 8; ++zz) s += part[(size_t)zz * 524288 + idx];
  osm[idx] = s;
}

// ---------------- GCN propagate + mix + gelu (per token) ----------------
__global__ __launch_bounds__(256) void k_gcnmix(const float* __restrict__ Hb,
                                                const float* __restrict__ a32,
                                                const float* __restrict__ mw,
                                                const float* __restrict__ mb,
                                                float* __restrict__ G) {
  __shared__ float X[3][C_][C_];
  __shared__ float am[C_ * 33];
  __shared__ float mwl[C_ * 96];
  __shared__ float mbl[C_];
  size_t tok = blockIdx.x;
  int tid = threadIdx.x;
  for (int i = tid; i < C_ * C_; i += 256) am[(i >> 5) * 33 + (i & 31)] = a32[i];
  for (int i = tid; i < C_ * 96; i += 256) mwl[i] = mw[i];
  if (tid < C_) mbl[tid] = mb[tid];
  for (int i = tid; i < 1024; i += 256) X[0][i >> 5][i & 31] = Hb[tok * 1024 + i];
  __syncthreads();
#pragma unroll
  for (int dep = 1; dep <= 2; ++dep) {
    for (int i = tid; i < 1024; i += 256) {
      int c = i >> 5, v = i & 31;
      float s = 0.f;
      for (int w = 0; w < C_; ++w) s += X[dep - 1][c][w] * am[v * 33 + w];
      X[dep][c][v] = ALPHA_ * X[0][c][v] + (1.0f - ALPHA_) * s;
    }
    __syncthreads();
  }
  for (int i = tid; i < 1024; i += 256) {
    int o = i >> 5, v = i & 31;
    float s = mbl[o];
    for (int cc = 0; cc < 96; ++cc) s += mwl[o * 96 + cc] * X[cc >> 5][cc & 31][v];
    G[tok * 1024 + i] = gelu_exact(s);
  }
}

// ---------------- repack G[(b,s),(c,n)] -> G2[(b,n),(c,s)] ----------------
__global__ __launch_bounds__(256) void k_repack(const float* __restrict__ G,
                                                float* __restrict__ G2) {
  int bid = blockIdx.x;
  int st = bid & 15, c = (bid >> 4) & 31, b = bid >> 9;
  __shared__ float tile[32][33];
  int tid = threadIdx.x;
  int n = tid & 31, s = tid >> 5;
  for (int q = 0; q < 4; ++q) {
    int ss = s + q * 8;
    tile[ss][n] = G[((size_t)b * T_ + st * 32 + ss) * 1024 + c * 32 + n];
  }
  __syncthreads();
  int s2 = tid & 31, n2 = tid >> 5;
  for (int q = 0; q < 4; ++q) {
    int nn = n2 + q * 8;
    G2[((size_t)b * 32 + nn) * 16384 + c * 512 + st * 32 + s2] = tile[s2][nn];
  }
}

// ---------------- lw projection + residual + LN (graph epilogue) ----------------
__global__ __launch_bounds__(256) void k_lwln(const float* __restrict__ osm,
                                              const float* __restrict__ lw,
                                              const float* __restrict__ lb,
                                              const float* __restrict__ curIn,
                                              const float* __restrict__ g,
                                              const float* __restrict__ bt,
                                              float* __restrict__ curOut) {
  int tok = blockIdx.x;
  int b = tok >> 9, t = tok & 511;
  __shared__ float os[C_];
  __shared__ float red[256];
  int tid = threadIdx.x;
  if (tid < C_) os[tid] = osm[((size_t)b * C_ + tid) * T_ + t];
  __syncthreads();
  float val[2];
#pragma unroll
  for (int q = 0; q < 2; ++q) {
    int m = tid + q * 256;
    float s = lb[m] + curIn[(size_t)tok * N_ + m];
    for (int n2 = 0; n2 < C_; ++n2) s += os[n2] * lw[n2 * N_ + m];
    val[q] = s;
  }
  red[tid] = val[0] + val[1];
  __syncthreads();
  for (int off = 128; off > 0; off >>= 1) { if (tid < off) red[tid] += red[tid + off]; __syncthreads(); }
  float mean = red[0] * (1.0f / N_);
  __syncthreads();
  float d0 = val[0] - mean, d1 = val[1] - mean;
  red[tid] = d0 * d0 + d1 * d1;
  __syncthreads();
  for (int off = 128; off > 0; off >>= 1) { if (tid < off) red[tid] += red[tid + off]; __syncthreads(); }
  float inv = rsqrtf(red[0] * (1.0f / N_) + EPS_);
  curOut[(size_t)tok * N_ + tid] = d0 * inv * g[tid] + bt[tid];
  curOut[(size_t)tok * N_ + tid + 256] = d1 * inv * g[tid + 256] + bt[tid + 256];
}

// ---------------- zero-pad tokens ----------------
__global__ void k_pad(const float* __restrict__ cur, float* __restrict__ xa,
                      const int* __restrict__ meta, int iter) {
  int L = meta[6 + iter];
  size_t total = (size_t)(B_ * L) * N_;
  for (size_t idx = (size_t)blockIdx.x * 256 + threadIdx.x; idx < total;
       idx += (size_t)gridDim.x * 256) {
    size_t tokd = idx >> 9;
    int d = (int)(idx & 511);
    int b = (int)(tokd / L), l = (int)(tokd % L);
    xa[idx] = (l < T_) ? cur[((size_t)b * T_ + l) * N_ + d] : 0.f;
  }
}

// ---------------- residual add + LN (attention) ----------------
__global__ __launch_bounds__(256) void k_lnadd(const float* __restrict__ r1,
                                               const float* __restrict__ r2,
                                               const float* __restrict__ g,
                                               const float* __restrict__ bt,
                                               float* __restrict__ dst,
                                               const int* __restrict__ meta, int iter) {
  int tokens = meta[15 + iter];
  int tok = blockIdx.x;
  if (tok >= tokens) return;
  __shared__ float red[256];
  int tid = threadIdx.x;
  float val[2];
#pragma unroll
  for (int q = 0; q < 2; ++q) {
    int m = tid + q * 256;
    val[q] = r1[(size_t)tok * N_ + m] + r2[(size_t)tok * N_ + m];
  }
  red[tid] = val[0] + val[1];
  __syncthreads();
  for (int off = 128; off > 0; off >>= 1) { if (tid < off) red[tid] += red[tid + off]; __syncthreads(); }
  float mean = red[0] * (1.0f / N_);
  __syncthreads();
  float d0 = val[0] - mean, d1 = val[1] - mean;
  red[tid] = d0 * d0 + d1 * d1;
  __syncthreads();
  for (int off = 128; off > 0; off >>= 1) { if (tid < off) red[tid] += red[tid + off]; __syncthreads(); }
  float inv = rsqrtf(red[0] * (1.0f / N_) + EPS_);
  dst[(size_t)tok * N_ + tid] = d0 * inv * g[tid] + bt[tid];
  dst[(size_t)tok * N_ + tid + 256] = d1 * inv * g[tid + 256] + bt[tid + 256];
}

// ---------------- fused attention, S<=128, fp32 K/V in LDS ----------------
__global__ __launch_bounds__(256) void k_attn_small(const float* __restrict__ qb,
                                                    const float* __restrict__ kb,
                                                    const float* __restrict__ vb,
                                                    float* __restrict__ ob,
                                                    const int* __restrict__ meta, int iter) {
  int p = meta[3 + iter];
  if (p > 128) return;
  int L = meta[6 + iter], nseq = meta[9 + iter];
  int M = B_ * nseq;
  int mh = blockIdx.x;
  int m = mh >> 3, h = mh & 7;
  if (m >= M) return;
  int S = p;
  int b = m / nseq, g2 = m % nseq;
  size_t tok0 = (size_t)b * L + (size_t)g2 * S;
  __shared__ float Ks[64 * 129];
  __shared__ float Vs[128 * 65];
  __shared__ float qrow[4][64];
  __shared__ float Pr[4][128];
  int tid = threadIdx.x;
  for (int i = tid; i < S * 64; i += 256) {
    int t = i >> 6, d = i & 63;
    float kv = kb[(tok0 + t) * N_ + h * 64 + d];
    float vv = vb[(tok0 + t) * N_ + h * 64 + d];
    Ks[d * 129 + t] = kv;
    Vs[t * 65 + d] = vv;
  }
  __syncthreads();
  int wave = tid >> 6, lane = tid & 63;
  int rounds = (S + 3) >> 2;
  for (int r = 0; r < rounds; ++r) {
    int s = r * 4 + wave;
    bool act = (s < S);
    if (act) qrow[wave][lane] = qb[(tok0 + s) * N_ + h * 64 + lane];
    __syncthreads();
    float sc[2];
    float ssum = 0.f;
    if (act) {
      float mx = -3.0e38f;
#pragma unroll
      for (int c2 = 0; c2 < 2; ++c2) {
        int t = lane + c2 * 64;
        float sv = -3.0e38f;
        if (t < S) {
          float ad = 0.f;
#pragma unroll 16
          for (int j = 0; j < 64; ++j) ad += qrow[wave][j] * Ks[j * 129 + t];
          sv = ad * 0.125f;
        }
        sc[c2] = sv;
        mx = fmaxf(mx, sv);
      }
      for (int off = 32; off > 0; off >>= 1) mx = fmaxf(mx, __shfl_xor(mx, off));
#pragma unroll
      for (int c2 = 0; c2 < 2; ++c2) {
        int t = lane + c2 * 64;
        float e = 0.f;
        if (t < S) { e = expf(sc[c2] - mx); Pr[wave][t] = e; }
        ssum += e;
      }
      for (int off = 32; off > 0; off >>= 1) ssum += __shfl_xor(ssum, off);
    }
    __syncthreads();
    if (act) {
      float inv = 1.0f / ssum;
      float ov = 0.f;
      for (int t = 0; t < S; ++t) ov += Pr[wave][t] * Vs[t * 65 + lane];
      ob[(tok0 + s) * N_ + h * 64 + lane] = ov * inv;
    }
    __syncthreads();
  }
}

// ---------------- fused attention, 128<S<=512, bf16 K/V (rare path) ----------------
__global__ __launch_bounds__(256) void k_attn_big(const float* __restrict__ qb,
                                                  const float* __restrict__ kb,
                                                  const float* __restrict__ vb,
                                                  float* __restrict__ ob,
                                                  const int* __restrict__ meta, int iter) {
  int p = meta[3 + iter];
  if (p <= 128) return;
  int L = meta[6 + iter], nseq = meta[9 + iter];
  int M = B_ * nseq;
  int mh = blockIdx.x;
  int m = mh >> 3, h = mh & 7;
  if (m >= M) return;
  int S = p;
  int b = m / nseq, g2 = m % nseq;
  size_t tok0 = (size_t)b * L + (size_t)g2 * S;
  __shared__ unsigned short Ks[512 * 66];
  __shared__ unsigned short Vs[512 * 66];
  __shared__ float qrow[4][64];
  __shared__ float Pr[4][512];
  int tid = threadIdx.x;
  for (int i = tid; i < S * 64; i += 256) {
    int t = i >> 6, d = i & 63;
    Ks[t * 66 + d] = f2bf(kb[(tok0 + t) * N_ + h * 64 + d]);
    Vs[t * 66 + d] = f2bf(vb[(tok0 + t) * N_ + h * 64 + d]);
  }
  __syncthreads();
  int wave = tid >> 6, lane = tid & 63;
  int rounds = (S + 3) >> 2;
  for (int r = 0; r < rounds; ++r) {
    int s = r * 4 + wave;
    bool act = (s < S);
    if (act) qrow[wave][lane] = qb[(tok0 + s) * N_ + h * 64 + lane];
    __syncthreads();
    float sc[8];
    float ssum = 0.f;
    if (act) {
      const float2* qp = (const float2*)&qrow[wave][0];
      float mx = -3.0e38f;
#pragma unroll
      for (int c2 = 0; c2 < 8; ++c2) {
        int t = lane + c2 * 64;
        float sv = -3.0e38f;
        if (t < S) {
          const unsigned int* kp = (const unsigned int*)&Ks[t * 66];
          float ad = 0.f;
#pragma unroll
          for (int j2 = 0; j2 < 32; ++j2) {
            float2 qq = qp[j2];
            unsigned int kw = kp[j2];
            ad += qq.x * bf2f((unsigned short)(kw & 0xffffu));
            ad += qq.y * bf2f((unsigned short)(kw >> 16));
          }
          sv = ad * 0.125f;
        }
        sc[c2] = sv;
        mx = fmaxf(mx, sv);
      }
      for (int off = 32; off > 0; off >>= 1) mx = fmaxf(mx, __shfl_xor(mx, off));
#pragma unroll
      for (int c2 = 0; c2 < 8; ++c2) {
        int t = lane + c2 * 64;
        float e = 0.f;
        if (t < S) { e = expf(sc[c2] - mx); Pr[wave][t] = e; }
        ssum += e;
      }
      for (int off = 32; off > 0; off >>= 1) ssum += __shfl_xor(ssum, off);
    }
    __syncthreads();
    if (act) {
      float inv = 1.0f / ssum;
      float ov = 0.f;
      for (int t = 0; t < S; ++t) ov += Pr[wave][t] * bf2f(Vs[t * 66 + lane]);
      ob[(tok0 + s) * N_ + h * 64 + lane] = ov * inv;
    }
    __syncthreads();
  }
}

// ---------------- final LN + gelu + weighted accumulate ----------------
__global__ __launch_bounds__(256) void k_fin(const float* __restrict__ y,
                                             const float* __restrict__ g,
                                             const float* __restrict__ bt,
                                             const float* __restrict__ swb,
                                             float* __restrict__ acc,
                                             const int* __restrict__ meta, int iter) {
  int L = meta[6 + iter];
  int tokens = B_ * L;
  int tok = blockIdx.x;
  if (tok >= tokens) return;
  int b = tok / L, l = tok % L;
  if (l >= T_) return;   // truncated away
  __shared__ float red[256];
  int tid = threadIdx.x;
  float val[2];
#pragma unroll
  for (int q = 0; q < 2; ++q) val[q] = y[(size_t)tok * N_ + tid + q * 256];
  red[tid] = val[0] + val[1];
  __syncthreads();
  for (int off = 128; off > 0; off >>= 1) { if (tid < off) red[tid] += red[tid + off]; __syncthreads(); }
  float mean = red[0] * (1.0f / N_);
  __syncthreads();
  float d0 = val[0] - mean, d1 = val[1] - mean;
  red[tid] = d0 * d0 + d1 * d1;
  __syncthreads();
  for (int off = 128; off > 0; off >>= 1) { if (tid < off) red[tid] += red[tid + off]; __syncthreads(); }
  float inv = rsqrtf(red[0] * (1.0f / N_) + EPS_);
  float s = swb[b * 4 + iter];
  float u0 = gelu_exact(d0 * inv * g[tid] + bt[tid]);
  float u1 = gelu_exact(d1 * inv * g[tid + 256] + bt[tid + 256]);
  size_t o = ((size_t)b * T_ + l) * N_;
  acc[o + tid] += s * u0;
  acc[o + tid + 256] += s * u1;
}

// ---------------- final output ----------------
__global__ void k_final(const float* __restrict__ acc, const float* __restrict__ cur,
                        float* __restrict__ out) {
  size_t idx = (size_t)blockIdx.x * 256 + threadIdx.x;
  out[idx] = acc[idx] + cur[idx];
}

extern "C" void kernel_launch(void* const* d_in, const int* in_sizes, int n_in,
                              void* d_out, int out_size, void* d_ws, size_t ws_size,
                              hipStream_t stream) {
  (void)in_sizes; (void)n_in; (void)out_size; (void)ws_size;
  const float* x       = (const float*)d_in[0];
  const float* nv1     = (const float*)d_in[1];
  const float* nv2     = (const float*)d_in[2];
  const float* start_w = (const float*)d_in[3];
  const float* start_b = (const float*)d_in[4];
  const float* mix_w   = (const float*)d_in[5];
  const float* mix_b   = (const float*)d_in[6];
  const float* end_w   = (const float*)d_in[7];
  const float* end_b   = (const float*)d_in[8];
  const float* glin_w  = (const float*)d_in[9];
  const float* glin_b  = (const float*)d_in[10];
  const float* gnorm_g = (const float*)d_in[11];
  const float* gnorm_b = (const float*)d_in[12];
  const float* wq = (const float*)d_in[13];
  const float* bq = (const float*)d_in[14];
  const float* wk = (const float*)d_in[15];
  const float* bk = (const float*)d_in[16];
  const float* wv = (const float*)d_in[17];
  const float* bv = (const float*)d_in[18];
  const float* wo = (const float*)d_in[19];
  const float* bo = (const float*)d_in[20];
  const float* ff1w = (const float*)d_in[21];
  const float* ff1b = (const float*)d_in[22];
  const float* ff2w = (const float*)d_in[23];
  const float* ff2b = (const float*)d_in[24];
  const float* an1g = (const float*)d_in[25];
  const float* an1b = (const float*)d_in[26];
  const float* an2g = (const float*)d_in[27];
  const float* an2b = (const float*)d_in[28];
  const float* nrmg = (const float*)d_in[29];
  const float* nrmb = (const float*)d_in[30];

  char* ws = (char*)d_ws;
  int*   meta = (int*)(ws + OFF_META);
  float* freq = (float*)(ws + OFF_FREQ);
  float* swb  = (float*)(ws + OFF_SW);
  float* a32  = (float*)(ws + OFF_A32);
  float* b1k  = (float*)(ws + OFF_B1K);
  float* osm  = (float*)(ws + OFF_OSM);
  unsigned short* WB  = (unsigned short*)(ws + OFF_WB);
  unsigned short* WdH = (unsigned short*)(ws + OFF_WDH);
  unsigned short* WdL = (unsigned short*)(ws + OFF_WDL);
  unsigned short* EWH = (unsigned short*)(ws + OFF_EWH);
  unsigned short* EWL = (unsigned short*)(ws + OFF_EWL);
  float* cur  = (float*)(ws + OFF_CUR);
  float* accb = (float*)(ws + OFF_ACC);
  float* fpart = (float*)(ws + OFF_FP);
  float* R0g  = (float*)(ws + OFF_R0G);
  float* G    = (float*)(ws + OFF_G);
  float* G2   = (float*)(ws + OFF_G2);
  float* PART = (float*)(ws + OFF_PART);
  float* A0 = (float*)(ws + OFF_A0);
  float* A2 = (float*)(ws + OFF_A2);
  float* A3 = (float*)(ws + OFF_A3);
  float* A4 = (float*)(ws + OFF_A4);
  float* A5 = (float*)(ws + OFF_A5);

  hipMemsetAsync(accb, 0, (size_t)B_ * T_ * N_ * 4, stream);

  k_stft2<<<NSB_, 256, 0, stream>>>(x, fpart);
  k_fred<<<NBIN_, 256, 0, stream>>>(fpart, freq);
  k_topk<<<1, 64, 0, stream>>>(freq, meta);
  k_sw<<<B_, 256, 0, stream>>>(x, meta, swb);

  // split attention/FF weights into bf16 hi/lo planes (once)
  const float* wlist[6] = {wq, wk, wv, wo, ff1w, ff2w};
  for (int w = 0; w < 6; ++w)
    k_split<<<256, 256, 0, stream>>>(wlist[w], WB + (size_t)w * 2 * 262144,
                                     WB + (size_t)(w * 2 + 1) * 262144, 262144);
  unsigned short* WqH = WB;               unsigned short* WqL = WB + 262144;
  unsigned short* WkH = WB + 2 * 262144;  unsigned short* WkL = WB + 3 * 262144;
  unsigned short* WvH = WB + 4 * 262144;  unsigned short* WvL = WB + 5 * 262144;
  unsigned short* WoH = WB + 6 * 262144;  unsigned short* WoL = WB + 7 * 262144;
  unsigned short* F1H = WB + 8 * 262144;  unsigned short* F1L = WB + 9 * 262144;
  unsigned short* F2H = WB + 10 * 262144; unsigned short* F2L = WB + 11 * 262144;

  const float* curIn = x;
  for (int i = 0; i < 3; ++i) {
    // ---- graph block ----
    k_adj<<<1, 64, 0, stream>>>(nv1 + i * C_ * 10, nv2 + i * 10 * C_, a32);
    k_wd<<<2048, 256, 0, stream>>>(start_w + i * C_ * KH_, start_b + i * C_, WdH, WdL, b1k);
    k_split<<<8192, 256, 0, stream>>>(end_w + (size_t)i * 8388608, EWH, EWL, 8388608);
    k_mm<<<dim3(8, 128, 1), 256, 0, stream>>>(curIn, WdH, WdL, b1k, R0g, nullptr,
                                              16384, 1024, 512, 512, nullptr, 0);
    k_gcnmix<<<B_ * T_, 256, 0, stream>>>(R0g, a32, mix_w + i * C_ * 96, mix_b + i * C_, G);
    k_repack<<<B_ * C_ * 16, 256, 0, stream>>>(G, G2);
    k_mm<<<dim3(4, 8, 8), 256, 0, stream>>>(G2, EWH, EWL, nullptr, nullptr, PART,
                                            1024, 512, 16384, 16384, nullptr, 0);
    k_red<<<2048, 256, 0, stream>>>(PART, end_b + i * T_, osm);
    k_lwln<<<B_ * T_, 256, 0, stream>>>(osm, glin_w + i * C_ * N_, glin_b + i * N_, curIn,
                                        gnorm_g + i * N_, gnorm_b + i * N_, cur);
    // ---- attention branch ----
    const int* Mdyn = meta + 15 + i;
    k_pad<<<4096, 256, 0, stream>>>(cur, A0, meta, i);
    dim3 gT(4, TOKMAX / 128, 1);
    k_mm<<<gT, 256, 0, stream>>>(A0, WqH, WqL, bq, A2, nullptr, TOKMAX, 512, 512, 512, Mdyn, 0);
    k_mm<<<gT, 256, 0, stream>>>(A0, WkH, WkL, bk, A3, nullptr, TOKMAX, 512, 512, 512, Mdyn, 0);
    k_mm<<<gT, 256, 0, stream>>>(A0, WvH, WvL, bv, A4, nullptr, TOKMAX, 512, 512, 512, Mdyn, 0);
    k_attn_small<<<65536, 256, 0, stream>>>(A2, A3, A4, A5, meta, i);
    k_attn_big<<<1024, 256, 0, stream>>>(A2, A3, A4, A5, meta, i);
    k_mm<<<gT, 256, 0, stream>>>(A5, WoH, WoL, bo, A2, nullptr, TOKMAX, 512, 512, 512, Mdyn, 0);
    k_lnadd<<<TOKMAX, 256, 0, stream>>>(A0, A2, an1g, an1b, A3, meta, i);
    k_mm<<<gT, 256, 0, stream>>>(A3, F1H, F1L, ff1b, A4, nullptr, TOKMAX, 512, 512, 512, Mdyn, 1);
    k_mm<<<gT, 256, 0, stream>>>(A4, F2H, F2L, ff2b, A5, nullptr, TOKMAX, 512, 512, 512, Mdyn, 0);
    k_lnadd<<<TOKMAX, 256, 0, stream>>>(A3, A5, an2g, an2b, A0, meta, i);
    k_fin<<<TOKMAX, 256, 0, stream>>>(A0, nrmg, nrmb, swb, accb, meta, i);
    curIn = cur;
  }
  k_final<<<(B_ * T_ * N_) / 256, 256, 0, stream>>>(accb, curIn, (float*)d_out);
}

// Round 4
// 2941.092 us; speedup vs baseline: 3.2427x; 1.2597x over previous
//
#include <hip/hip_runtime.h>
#include <math.h>

#define DI __device__ __forceinline__

namespace {
constexpr int B_ = 32;
constexpr int T_ = 512;
constexpr int N_ = 512;   // d_model
constexpr int C_ = 32;    // c_out / conv_ch / skip_ch
constexpr int KH_ = 481;
constexpr int HOP_ = 48;
constexpr int WIN_ = 48;
constexpr int NFR_ = 11;
constexpr int NBIN_ = 257;
constexpr int NSB_ = 4 * NFR_ * B_;   // 1408 stft blocks
constexpr int TOKMAX = 22528;   // 176*128 >= max possible tokens (21760)
constexpr float EPS_ = 1e-5f;

constexpr size_t MBY = 1ull << 20;
constexpr size_t OFF_META = 0;
constexpr size_t OFF_FREQ = 4096;
constexpr size_t OFF_SW   = 8192;
constexpr size_t OFF_A32  = 12288;
constexpr size_t OFF_BEFF = 16384;       // 1024 floats
constexpr size_t OFF_P12  = 32768;       // 2048 floats
constexpr size_t OFF_OSM  = 1 * MBY;     // 2MB
constexpr size_t OFF_WB   = 4 * MBY;     // 12 planes x 512KB = 6MB
constexpr size_t OFF_WDH  = 10 * MBY;    // 1MB  (WdT hi plane [512][1024])
constexpr size_t OFF_WDL  = 11 * MBY;    // 1MB
constexpr size_t OFF_EWH  = 12 * MBY;    // 16MB
constexpr size_t OFF_EWL  = 28 * MBY;    // 16MB
constexpr size_t OFF_CUR  = 44 * MBY;    // 32MB
constexpr size_t OFF_ACC  = 76 * MBY;    // 32MB
constexpr size_t TR       = 108 * MBY;   // transient union region
// graph phase (TR+0..64MB is scratch for the weight-fold pipeline)
constexpr size_t OFF_T    = TR;            // 4MB  T [1024][1024]
constexpr size_t OFF_WP   = TR + 4 * MBY;  // 2MB  W' fp32 [1024][512]
constexpr size_t OFF_WPH  = TR + 6 * MBY;  // 1MB  W' hi plane
constexpr size_t OFF_WPL  = TR + 7 * MBY;  // 1MB
constexpr size_t OFF_G    = TR + 64 * MBY; // 64MB
constexpr size_t OFF_G2   = TR + 128 * MBY;// 64MB [1024][16384]
constexpr size_t OFF_PART = TR + 192 * MBY;// 16MB [8][1024][512]
// attention phase (aliases graph region)
constexpr size_t OFF_A0 = TR;              // 44MB each
constexpr size_t OFF_A2 = TR + 44 * MBY;
constexpr size_t OFF_A3 = TR + 88 * MBY;
constexpr size_t OFF_A4 = TR + 132 * MBY;
constexpr size_t OFF_A5 = TR + 176 * MBY;  // ends 328MB
// stft partials alias TR (stft completes before graph phase starts)
constexpr size_t OFF_FP = TR;              // NBIN_*NSB_ floats ~1.45MB
} // namespace

typedef __attribute__((ext_vector_type(4))) float f32x4;
typedef __attribute__((ext_vector_type(8))) short bf8;
typedef __attribute__((ext_vector_type(8))) unsigned short u16x8;

DI float gelu_exact(float x) { return 0.5f * x * (1.0f + erff(x * 0.7071067811865475f)); }
DI unsigned short f2bf(float f) {   // round-to-nearest-even
  unsigned u = __float_as_uint(f);
  u += 0x7FFFu + ((u >> 16) & 1u);
  return (unsigned short)(u >> 16);
}
DI float bf2f(unsigned short s) { return __uint_as_float(((unsigned)s) << 16); }

// ---------------- STFT via phasor recurrence ----------------
__global__ __launch_bounds__(256) void k_stft2(const float* __restrict__ x,
                                               float* __restrict__ fpart) {
  int bid = blockIdx.x;
  int cc = bid & 3;
  int f = (bid >> 2) % NFR_;
  int b = bid / (4 * NFR_);
  __shared__ float xw[WIN_][128];
  int tid = threadIdx.x;
  for (int i = tid; i < WIN_ * 128; i += 256) {
    int j = i >> 7, n = i & 127;
    int gi = f * HOP_ + 232 + j - 256;
    if (gi < 0) gi = -gi;   // reflect pad (left only)
    float w = 0.5f - 0.5f * cosf((float)j * 0.13089969389957472f);   // 2pi/48
    xw[j][n] = w * x[((size_t)b * T_ + gi) * N_ + cc * 128 + n];
  }
  __syncthreads();
  for (int pair = tid; pair < NBIN_ * 16; pair += 256) {
    int k = pair >> 4;
    int n8 = (pair & 15) * 8;
    int r0 = (k * 232) & 511;                       // exact angle reduction
    float a0 = (float)r0 * 0.012271846303085130f;   // 2pi/512
    float c = cosf(a0), s = sinf(a0);
    float dA = (float)k * 0.012271846303085130f;
    float cd = cosf(dA), sd = sinf(dA);
    float re[8] = {0,0,0,0,0,0,0,0}, im[8] = {0,0,0,0,0,0,0,0};
    const float* xp = &xw[0][n8];
#pragma unroll 4
    for (int j = 0; j < WIN_; ++j) {
      float4 v0 = *(const float4*)xp;
      float4 v1 = *(const float4*)(xp + 4);
      re[0] += v0.x * c; im[0] += v0.x * s;
      re[1] += v0.y * c; im[1] += v0.y * s;
      re[2] += v0.z * c; im[2] += v0.z * s;
      re[3] += v0.w * c; im[3] += v0.w * s;
      re[4] += v1.x * c; im[4] += v1.x * s;
      re[5] += v1.y * c; im[5] += v1.y * s;
      re[6] += v1.z * c; im[6] += v1.z * s;
      re[7] += v1.w * c; im[7] += v1.w * s;
      float cn = c * cd - s * sd;
      s = s * cd + c * sd;
      c = cn;
      xp += 128;
    }
    float m = 0.f;
#pragma unroll
    for (int q = 0; q < 8; ++q) m += sqrtf(re[q] * re[q] + im[q] * im[q]);
    for (int off = 8; off > 0; off >>= 1) m += __shfl_xor(m, off);
    if ((tid & 15) == 0) fpart[(size_t)k * NSB_ + bid] = m;
  }
}

// ---------------- deterministic partial reduce -> freq ----------------
__global__ __launch_bounds__(256) void k_fred(const float* __restrict__ fpart,
                                              float* __restrict__ freq) {
  int k = blockIdx.x;
  __shared__ float red[256];
  int tid = threadIdx.x;
  float s = 0.f;
  for (int bb = tid; bb < NSB_; bb += 256) s += fpart[(size_t)k * NSB_ + bb];
  red[tid] = s;
  __syncthreads();
  for (int off = 128; off > 0; off >>= 1) {
    if (tid < off) red[tid] += red[tid + off];
    __syncthreads();
  }
  if (tid == 0) freq[k] = red[0];
}

// ---------------- top-k + meta ----------------
__global__ void k_topk(const float* __restrict__ freq, int* __restrict__ meta) {
  if (threadIdx.x == 0 && blockIdx.x == 0) {
    float bv[3] = {-1e30f, -1e30f, -1e30f};
    int bi[3] = {1, 1, 1};
    for (int k = 1; k < NBIN_; ++k) {
      float v = freq[k];
      if (v > bv[0]) { bv[2]=bv[1]; bi[2]=bi[1]; bv[1]=bv[0]; bi[1]=bi[0]; bv[0]=v; bi[0]=k; }
      else if (v > bv[1]) { bv[2]=bv[1]; bi[2]=bi[1]; bv[1]=v; bi[1]=k; }
      else if (v > bv[2]) { bv[2]=v; bi[2]=k; }
    }
    for (int i = 0; i < 3; ++i) {
      int top = bi[i];
      int p = T_ / top;
      int L = ((T_ + p - 1) / p) * p;
      meta[i] = top;
      meta[3 + i] = p;
      meta[6 + i] = L;
      meta[9 + i] = L / p;
      meta[15 + i] = B_ * L;   // tokens
    }
  }
}

// ---------------- per-batch branch weights sw ----------------
__global__ __launch_bounds__(256) void k_sw(const float* __restrict__ x,
                                            const int* __restrict__ meta,
                                            float* __restrict__ swb) {
  int b = blockIdx.x;
  __shared__ float ct[3][WIN_], st[3][WIN_];
  __shared__ float red[256];
  int tid = threadIdx.x;
  for (int i = tid; i < 3 * WIN_; i += 256) {
    int kk = i / WIN_, j = i % WIN_;
    int k = meta[kk];
    int r = (k * (232 + j)) & 511;
    float ang = (float)r * 0.012271846303085130f;
    float w = 0.5f - 0.5f * cosf((float)j * 0.13089969389957472f);
    ct[kk][j] = w * cosf(ang);
    st[kk][j] = w * sinf(ang);
  }
  __syncthreads();
  float acc[3] = {0.f, 0.f, 0.f};
  for (int it = tid; it < NFR_ * N_; it += 256) {
    int f = it / N_, n = it % N_;
    float xs[WIN_];
    for (int j = 0; j < WIN_; ++j) {
      int gi = f * HOP_ + 232 + j - 256;
      if (gi < 0) gi = -gi;
      xs[j] = x[((size_t)b * T_ + gi) * N_ + n];
    }
    for (int kk = 0; kk < 3; ++kk) {
      float re = 0.f, im = 0.f;
      for (int j = 0; j < WIN_; ++j) { re += xs[j] * ct[kk][j]; im += xs[j] * st[kk][j]; }
      acc[kk] += sqrtf(re * re + im * im);
    }
  }
  for (int kk = 0; kk < 3; ++kk) {
    red[tid] = acc[kk];
    __syncthreads();
    for (int off = 128; off > 0; off >>= 1) {
      if (tid < off) red[tid] += red[tid + off];
      __syncthreads();
    }
    if (tid == 0) swb[b * 4 + kk] = red[0];
    __syncthreads();
  }
  if (tid == 0) {
    float inv = 1.0f / (float)(NFR_ * N_);
    float m0 = swb[b*4+0]*inv, m1 = swb[b*4+1]*inv, m2 = swb[b*4+2]*inv;
    float mx = fmaxf(m0, fmaxf(m1, m2));
    float e0 = expf(m0-mx), e1 = expf(m1-mx), e2 = expf(m2-mx);
    float s = e0 + e1 + e2;
    swb[b*4+0] = e0/s; swb[b*4+1] = e1/s; swb[b*4+2] = e2/s;
  }
}

// ---------------- graph adjacency ----------------
__global__ void k_adj(const float* __restrict__ nv1, const float* __restrict__ nv2,
                      float* __restrict__ a32) {
  int v = threadIdx.x;
  if (v < C_) {
    float row[C_];
    for (int w = 0; w < C_; ++w) {
      float s = 0.f;
      for (int d = 0; d < 10; ++d) s += nv1[v * 10 + d] * nv2[d * C_ + w];
      row[w] = fmaxf(s, 0.f);
    }
    float mx = -1e30f;
    for (int w = 0; w < C_; ++w) mx = fmaxf(mx, row[w]);
    float sm = 0.f;
    for (int w = 0; w < C_; ++w) { row[w] = expf(row[w] - mx); sm += row[w]; }
    for (int w = 0; w < C_; ++w) row[w] /= sm;
    row[v] += 1.0f;
    float rs = 0.f;
    for (int w = 0; w < C_; ++w) rs += row[w];
    for (int w = 0; w < C_; ++w) a32[v * C_ + w] = row[w] / rs;
  }
}

// ---------------- GCN operator prep: P1, P2, b_eff ----------------
// P_d = alpha*I + (1-alpha)*P_{d-1}*M  with M[w][v] = a[v][w].
// b_eff[(o,v)] = mb[o] + sum_d sum_c mw[o][d*32+c]*sb[c]*colsum(P_d)[v]
__global__ __launch_bounds__(1024) void k_prep(const float* __restrict__ a32,
                                               const float* __restrict__ mw,
                                               const float* __restrict__ mb,
                                               const float* __restrict__ sb,
                                               float* __restrict__ P12,
                                               float* __restrict__ beff) {
  __shared__ float Ms[32][32], P1s[32][32], P2s[32][32], S1[32], S2[32], sbl[32];
  int tid = threadIdx.x;
  int w = tid >> 5, v = tid & 31;
  Ms[w][v] = a32[v * 32 + w];
  if (tid < 32) sbl[tid] = sb[tid];
  __syncthreads();
  float p1 = 0.95f * Ms[w][v] + (w == v ? 0.05f : 0.f);
  P1s[w][v] = p1;
  __syncthreads();
  float p2 = 0.f;
  for (int u = 0; u < 32; ++u) p2 += P1s[w][u] * Ms[u][v];
  p2 = 0.95f * p2 + (w == v ? 0.05f : 0.f);
  P2s[w][v] = p2;
  P12[tid] = p1;
  P12[1024 + tid] = p2;
  __syncthreads();
  if (tid < 32) {
    float s1 = 0.f, s2 = 0.f;
    for (int u = 0; u < 32; ++u) { s1 += P1s[u][tid]; s2 += P2s[u][tid]; }
    S1[tid] = s1; S2[tid] = s2;
  }
  __syncthreads();
  int o = w;
  float be = mb[o];
  for (int c = 0; c < 32; ++c) {
    float sc = sbl[c];
    be += mw[o * 96 + c] * sc;
    be += mw[o * 96 + 32 + c] * sc * S1[v];
    be += mw[o * 96 + 64 + c] * sc * S2[v];
  }
  beff[tid] = be;
}

// ---------------- build T [1024][1024]: T[(o,v)][(c,w)] ----------------
__global__ __launch_bounds__(256) void k_T(const float* __restrict__ P12,
                                           const float* __restrict__ mw,
                                           float* __restrict__ Tm) {
  int idx = blockIdx.x * 256 + threadIdx.x;
  int r = idx >> 10, k2 = idx & 1023;
  int o = r >> 5, v = r & 31;
  int c = k2 >> 5, w = k2 & 31;
  float t = mw[o * 96 + 32 + c] * P12[w * 32 + v]
          + mw[o * 96 + 64 + c] * P12[1024 + w * 32 + v];
  if (w == v) t += mw[o * 96 + c];
  Tm[idx] = t;
}

// ---------------- build WdT hi/lo: WdT[j][(c,w)] = sw[c][j-w] ----------------
__global__ void k_wd2(const float* __restrict__ swi,
                      unsigned short* __restrict__ WH, unsigned short* __restrict__ WL) {
  int idx = blockIdx.x * 256 + threadIdx.x;   // 512*1024
  int j = idx >> 10, k2 = idx & 1023;
  int c = k2 >> 5, w = k2 & 31;
  int kk = j - w;
  float vv = (kk >= 0 && kk < KH_) ? swi[c * KH_ + kk] : 0.f;
  unsigned short h = f2bf(vv);
  WH[idx] = h;
  WL[idx] = f2bf(vv - bf2f(h));
}

// ---------------- weight hi/lo split ----------------
__global__ void k_split(const float* __restrict__ src, unsigned short* __restrict__ Hi,
                        unsigned short* __restrict__ Lo, int n) {
  int i = blockIdx.x * 256 + threadIdx.x;
  if (i * 4 >= n) return;
  float4 v = *(const float4*)&src[i * 4];
  float vv[4] = {v.x, v.y, v.z, v.w};
  ushort4 h, l;
  unsigned short hs[4], ls[4];
#pragma unroll
  for (int j = 0; j < 4; ++j) {
    unsigned short hh = f2bf(vv[j]);
    hs[j] = hh;
    ls[j] = f2bf(vv[j] - bf2f(hh));
  }
  h.x = hs[0]; h.y = hs[1]; h.z = hs[2]; h.w = hs[3];
  l.x = ls[0]; l.y = ls[1]; l.z = ls[2]; l.w = ls[3];
  *(ushort4*)&Hi[i * 4] = h;
  *(ushort4*)&Lo[i * 4] = l;
}

// ---------------- split-bf16 MFMA GEMM ----------------
// C[M][N] = A[M][lda](fp32) @ W[N][K]^T, W pre-split into Bh+Bl bf16 planes.
// a*b ~= ah*bh + al*bh + ah*bl (3 MFMAs). 128x128 tile, 4 waves. Split-K via z.
__global__ __launch_bounds__(256, 2) void k_mm(
    const float* __restrict__ A, const unsigned short* __restrict__ Bh,
    const unsigned short* __restrict__ Bl, const float* __restrict__ bias,
    float* __restrict__ C, float* __restrict__ Cpart,
    int M, int N, int K, int lda, const int* __restrict__ Mdyn, int dogelu) {
  if (Mdyn) M = *Mdyn;
  const int bm = blockIdx.y * 128;
  if (bm >= M) return;
  const int bn = blockIdx.x * 128;
  const int nz = gridDim.z, z = blockIdx.z;
  const int kpb = K / nz;
  const int kbeg = z * kpb, kend = kbeg + kpb;

  __shared__ unsigned short AhS[4096], AlS[4096], BhS[4096], BlS[4096];

  const int tid = threadIdx.x;
  const int wave = tid >> 6, lane = tid & 63;
  const int wr = wave >> 1, wc = wave & 1;
  const int fr = lane & 15, fs = lane >> 4;

  const int sr = tid >> 1, ss = (tid & 1) * 2;
  const int sx = (sr >> 1) & 3;
  const int so0 = sr * 32 + 8 * (ss ^ sx);
  const int so1 = sr * 32 + 8 * ((ss + 1) ^ sx);

  int aoff[4], boff[4];
#pragma unroll
  for (int m = 0; m < 4; ++m) {
    int ra = wr * 64 + m * 16 + fr;
    aoff[m] = ra * 32 + 8 * (fs ^ ((ra >> 1) & 3));
    int rb = wc * 64 + m * 16 + fr;
    boff[m] = rb * 32 + 8 * (fs ^ ((rb >> 1) & 3));
  }

  const bool aok = (bm + sr) < M;
  const float* Arow = A + (size_t)(bm + sr) * lda + ss * 8;
  const unsigned short* BhRow = Bh + (size_t)(bn + sr) * K + ss * 8;
  const unsigned short* BlRow = Bl + (size_t)(bn + sr) * K + ss * 8;

  f32x4 acc[4][4];
#pragma unroll
  for (int m = 0; m < 4; ++m)
#pragma unroll
    for (int n = 0; n < 4; ++n) acc[m][n] = (f32x4){0.f, 0.f, 0.f, 0.f};

  for (int k0 = kbeg; k0 < kend; k0 += 32) {
    float4 a0, a1, a2, a3;
    if (aok) {
      const float4* p = (const float4*)(Arow + k0);
      a0 = p[0]; a1 = p[1]; a2 = p[2]; a3 = p[3];
    } else {
      a0 = a1 = a2 = a3 = make_float4(0.f, 0.f, 0.f, 0.f);
    }
    u16x8 gb0 = *(const u16x8*)(BhRow + k0);
    u16x8 gb1 = *(const u16x8*)(BhRow + k0 + 8);
    u16x8 gl0 = *(const u16x8*)(BlRow + k0);
    u16x8 gl1 = *(const u16x8*)(BlRow + k0 + 8);
    float av[16];
    av[0]=a0.x; av[1]=a0.y; av[2]=a0.z; av[3]=a0.w;
    av[4]=a1.x; av[5]=a1.y; av[6]=a1.z; av[7]=a1.w;
    av[8]=a2.x; av[9]=a2.y; av[10]=a2.z; av[11]=a2.w;
    av[12]=a3.x; av[13]=a3.y; av[14]=a3.z; av[15]=a3.w;
    u16x8 h0, h1, l0, l1;
#pragma unroll
    for (int j = 0; j < 8; ++j) {   // truncation split: err <= 2^-16 rel
      unsigned u = __float_as_uint(av[j]);
      h0[j] = (unsigned short)(u >> 16);
      float r2 = av[j] - __uint_as_float(u & 0xffff0000u);
      l0[j] = (unsigned short)(__float_as_uint(r2) >> 16);
      unsigned u2 = __float_as_uint(av[j + 8]);
      h1[j] = (unsigned short)(u2 >> 16);
      float r3 = av[j + 8] - __uint_as_float(u2 & 0xffff0000u);
      l1[j] = (unsigned short)(__float_as_uint(r3) >> 16);
    }
    __syncthreads();
    *(u16x8*)&AhS[so0] = h0; *(u16x8*)&AhS[so1] = h1;
    *(u16x8*)&AlS[so0] = l0; *(u16x8*)&AlS[so1] = l1;
    *(u16x8*)&BhS[so0] = gb0; *(u16x8*)&BhS[so1] = gb1;
    *(u16x8*)&BlS[so0] = gl0; *(u16x8*)&BlS[so1] = gl1;
    __syncthreads();
    bf8 ah[4], al4[4], bh4[4], bl4[4];
#pragma unroll
    for (int m = 0; m < 4; ++m) {
      ah[m]  = *(const bf8*)&AhS[aoff[m]];
      al4[m] = *(const bf8*)&AlS[aoff[m]];
    }
#pragma unroll
    for (int n = 0; n < 4; ++n) {
      bh4[n] = *(const bf8*)&BhS[boff[n]];
      bl4[n] = *(const bf8*)&BlS[boff[n]];
    }
#pragma unroll
    for (int m = 0; m < 4; ++m)
#pragma unroll
      for (int n = 0; n < 4; ++n) {
        acc[m][n] = __builtin_amdgcn_mfma_f32_16x16x32_bf16(ah[m],  bh4[n], acc[m][n], 0, 0, 0);
        acc[m][n] = __builtin_amdgcn_mfma_f32_16x16x32_bf16(al4[m], bh4[n], acc[m][n], 0, 0, 0);
        acc[m][n] = __builtin_amdgcn_mfma_f32_16x16x32_bf16(ah[m],  bl4[n], acc[m][n], 0, 0, 0);
      }
  }

  if (nz > 1) {
    float* P = Cpart + (size_t)z * M * N;
#pragma unroll
    for (int m = 0; m < 4; ++m)
#pragma unroll
      for (int r = 0; r < 4; ++r) {
        int row = bm + wr * 64 + m * 16 + fs * 4 + r;
        if (row < M) {
#pragma unroll
          for (int n = 0; n < 4; ++n) {
            int col = bn + wc * 64 + n * 16 + fr;
            P[(size_t)row * N + col] = acc[m][n][r];
          }
        }
      }
  } else {
    float bcol[4];
#pragma unroll
    for (int n = 0; n < 4; ++n) bcol[n] = bias ? bias[bn + wc * 64 + n * 16 + fr] : 0.f;
#pragma unroll
    for (int m = 0; m < 4; ++m)
#pragma unroll
      for (int r = 0; r < 4; ++r) {
        int row = bm + wr * 64 + m * 16 + fs * 4 + r;
        if (row < M) {
#pragma unroll
          for (int n = 0; n < 4; ++n) {
            int col = bn + wc * 64 + n * 16 + fr;
            float v = acc[m][n][r] + bcol[n];
            if (dogelu) v = gelu_exact(v);
            C[(size_t)row * N + col] = v;
          }
        }
      }
  }
}

// ---------------- split-K reduce (+optional bias) ----------------
__global__ void k_red(const float* __restrict__ part, const float* __restrict__ eb,
                      float* __restrict__ dst) {
  int idx = blockIdx.x * 256 + threadIdx.x;   // 1024*512
  float s = eb ? eb[idx & 511] : 0.f;
#pragma unroll
  for (int zz = 0; zz < 8; ++zz) s += part[(size_t)zz * 524288 + idx];
  dst[idx] = s;
}

// ---------------- repack G[(b,s),(c,n)] -> G2[(b,n),(c,s)] ----------------
__global__ __launch_bounds__(256) void k_repack(const float* __restrict__ G,
                                                float* __restrict__ G2) {
  int bid = blockIdx.x;
  int st = bid & 15, c = (bid >> 4) & 31, b = bid >> 9;
  __shared__ float tile[32][33];
  int tid = threadIdx.x;
  int n = tid & 31, s = tid >> 5;
  for (int q = 0; q < 4; ++q) {
    int ss = s + q * 8;
    tile[ss][n] = G[((size_t)b * T_ + st * 32 + ss) * 1024 + c * 32 + n];
  }
  __syncthreads();
  int s2 = tid & 31, n2 = tid >> 5;
  for (int q = 0; q < 4; ++q) {
    int nn = n2 + q * 8;
    G2[((size_t)b * 32 + nn) * 16384 + c * 512 + st * 32 + s2] = tile[s2][nn];
  }
}

// ---------------- lw projection + residual + LN (graph epilogue) ----------------
__global__ __launch_bounds__(256) void k_lwln(const float* __restrict__ osm,
                                              const float* __restrict__ lw,
                                              const float* __restrict__ lb,
                                              const float* __restrict__ curIn,
                                              const float* __restrict__ g,
                                              const float* __restrict__ bt,
                                              float* __restrict__ curOut) {
  int tok = blockIdx.x;
  int b = tok >> 9, t = tok & 511;
  __shared__ float os[C_];
  __shared__ float red[256];
  int tid = threadIdx.x;
  if (tid < C_) os[tid] = osm[((size_t)b * C_ + tid) * T_ + t];
  __syncthreads();
  float val[2];
#pragma unroll
  for (int q = 0; q < 2; ++q) {
    int m = tid + q * 256;
    float s = lb[m] + curIn[(size_t)tok * N_ + m];
    for (int n2 = 0; n2 < C_; ++n2) s += os[n2] * lw[n2 * N_ + m];
    val[q] = s;
  }
  red[tid] = val[0] + val[1];
  __syncthreads();
  for (int off = 128; off > 0; off >>= 1) { if (tid < off) red[tid] += red[tid + off]; __syncthreads(); }
  float mean = red[0] * (1.0f / N_);
  __syncthreads();
  float d0 = val[0] - mean, d1 = val[1] - mean;
  red[tid] = d0 * d0 + d1 * d1;
  __syncthreads();
  for (int off = 128; off > 0; off >>= 1) { if (tid < off) red[tid] += red[tid + off]; __syncthreads(); }
  float inv = rsqrtf(red[0] * (1.0f / N_) + EPS_);
  curOut[(size_t)tok * N_ + tid] = d0 * inv * g[tid] + bt[tid];
  curOut[(size_t)tok * N_ + tid + 256] = d1 * inv * g[tid + 256] + bt[tid + 256];
}

// ---------------- zero-pad tokens ----------------
__global__ void k_pad(const float* __restrict__ cur, float* __restrict__ xa,
                      const int* __restrict__ meta, int iter) {
  int L = meta[6 + iter];
  size_t total = (size_t)(B_ * L) * N_;
  for (size_t idx = (size_t)blockIdx.x * 256 + threadIdx.x; idx < total;
       idx += (size_t)gridDim.x * 256) {
    size_t tokd = idx >> 9;
    int d = (int)(idx & 511);
    int b = (int)(tokd / L), l = (int)(tokd % L);
    xa[idx] = (l < T_) ? cur[((size_t)b * T_ + l) * N_ + d] : 0.f;
  }
}

// ---------------- residual add + LN (attention) ----------------
__global__ __launch_bounds__(256) void k_lnadd(const float* __restrict__ r1,
                                               const float* __restrict__ r2,
                                               const float* __restrict__ g,
                                               const float* __restrict__ bt,
                                               float* __restrict__ dst,
                                               const int* __restrict__ meta, int iter) {
  int tokens = meta[15 + iter];
  int tok = blockIdx.x;
  if (tok >= tokens) return;
  __shared__ float red[256];
  int tid = threadIdx.x;
  float val[2];
#pragma unroll
  for (int q = 0; q < 2; ++q) {
    int m = tid + q * 256;
    val[q] = r1[(size_t)tok * N_ + m] + r2[(size_t)tok * N_ + m];
  }
  red[tid] = val[0] + val[1];
  __syncthreads();
  for (int off = 128; off > 0; off >>= 1) { if (tid < off) red[tid] += red[tid + off]; __syncthreads(); }
  float mean = red[0] * (1.0f / N_);
  __syncthreads();
  float d0 = val[0] - mean, d1 = val[1] - mean;
  red[tid] = d0 * d0 + d1 * d1;
  __syncthreads();
  for (int off = 128; off > 0; off >>= 1) { if (tid < off) red[tid] += red[tid + off]; __syncthreads(); }
  float inv = rsqrtf(red[0] * (1.0f / N_) + EPS_);
  dst[(size_t)tok * N_ + tid] = d0 * inv * g[tid] + bt[tid];
  dst[(size_t)tok * N_ + tid + 256] = d1 * inv * g[tid + 256] + bt[tid + 256];
}

// ---------------- fused attention, S<=128, fp32 K/V in LDS ----------------
__global__ __launch_bounds__(256) void k_attn_small(const float* __restrict__ qb,
                                                    const float* __restrict__ kb,
                                                    const float* __restrict__ vb,
                                                    float* __restrict__ ob,
                                                    const int* __restrict__ meta, int iter) {
  int p = meta[3 + iter];
  if (p > 128) return;
  int L = meta[6 + iter], nseq = meta[9 + iter];
  int M = B_ * nseq;
  int mh = blockIdx.x;
  int m = mh >> 3, h = mh & 7;
  if (m >= M) return;
  int S = p;
  int b = m / nseq, g2 = m % nseq;
  size_t tok0 = (size_t)b * L + (size_t)g2 * S;
  __shared__ float Ks[64 * 129];
  __shared__ float Vs[128 * 65];
  __shared__ float qrow[4][64];
  __shared__ float Pr[4][128];
  int tid = threadIdx.x;
  for (int i = tid; i < S * 64; i += 256) {
    int t = i >> 6, d = i & 63;
    float kv = kb[(tok0 + t) * N_ + h * 64 + d];
    float vv = vb[(tok0 + t) * N_ + h * 64 + d];
    Ks[d * 129 + t] = kv;
    Vs[t * 65 + d] = vv;
  }
  __syncthreads();
  int wave = tid >> 6, lane = tid & 63;
  int rounds = (S + 3) >> 2;
  for (int r = 0; r < rounds; ++r) {
    int s = r * 4 + wave;
    bool act = (s < S);
    if (act) qrow[wave][lane] = qb[(tok0 + s) * N_ + h * 64 + lane];
    __syncthreads();
    float sc[2];
    float ssum = 0.f;
    if (act) {
      float mx = -3.0e38f;
#pragma unroll
      for (int c2 = 0; c2 < 2; ++c2) {
        int t = lane + c2 * 64;
        float sv = -3.0e38f;
        if (t < S) {
          float ad = 0.f;
#pragma unroll 16
          for (int j = 0; j < 64; ++j) ad += qrow[wave][j] * Ks[j * 129 + t];
          sv = ad * 0.125f;
        }
        sc[c2] = sv;
        mx = fmaxf(mx, sv);
      }
      for (int off = 32; off > 0; off >>= 1) mx = fmaxf(mx, __shfl_xor(mx, off));
#pragma unroll
      for (int c2 = 0; c2 < 2; ++c2) {
        int t = lane + c2 * 64;
        float e = 0.f;
        if (t < S) { e = expf(sc[c2] - mx); Pr[wave][t] = e; }
        ssum += e;
      }
      for (int off = 32; off > 0; off >>= 1) ssum += __shfl_xor(ssum, off);
    }
    __syncthreads();
    if (act) {
      float inv = 1.0f / ssum;
      float ov = 0.f;
      for (int t = 0; t < S; ++t) ov += Pr[wave][t] * Vs[t * 65 + lane];
      ob[(tok0 + s) * N_ + h * 64 + lane] = ov * inv;
    }
    __syncthreads();
  }
}

// ---------------- fused attention, 128<S<=512, bf16 K/V (rare path) ----------------
__global__ __launch_bounds__(256) void k_attn_big(const float* __restrict__ qb,
                                                  const float* __restrict__ kb,
                                                  const float* __restrict__ vb,
                                                  float* __restrict__ ob,
                                                  const int* __restrict__ meta, int iter) {
  int p = meta[3 + iter];
  if (p <= 128) return;
  int L = meta[6 + iter], nseq = meta[9 + iter];
  int M = B_ * nseq;
  int mh = blockIdx.x;
  int m = mh >> 3, h = mh & 7;
  if (m >= M) return;
  int S = p;
  int b = m / nseq, g2 = m % nseq;
  size_t tok0 = (size_t)b * L + (size_t)g2 * S;
  __shared__ unsigned short Ks[512 * 66];
  __shared__ unsigned short Vs[512 * 66];
  __shared__ float qrow[4][64];
  __shared__ float Pr[4][512];
  int tid = threadIdx.x;
  for (int i = tid; i < S * 64; i += 256) {
    int t = i >> 6, d = i & 63;
    Ks[t * 66 + d] = f2bf(kb[(tok0 + t) * N_ + h * 64 + d]);
    Vs[t * 66 + d] = f2bf(vb[(tok0 + t) * N_ + h * 64 + d]);
  }
  __syncthreads();
  int wave = tid >> 6, lane = tid & 63;
  int rounds = (S + 3) >> 2;
  for (int r = 0; r < rounds; ++r) {
    int s = r * 4 + wave;
    bool act = (s < S);
    if (act) qrow[wave][lane] = qb[(tok0 + s) * N_ + h * 64 + lane];
    __syncthreads();
    float sc[8];
    float ssum = 0.f;
    if (act) {
      const float2* qp = (const float2*)&qrow[wave][0];
      float mx = -3.0e38f;
#pragma unroll
      for (int c2 = 0; c2 < 8; ++c2) {
        int t = lane + c2 * 64;
        float sv = -3.0e38f;
        if (t < S) {
          const unsigned int* kp = (const unsigned int*)&Ks[t * 66];
          float ad = 0.f;
#pragma unroll
          for (int j2 = 0; j2 < 32; ++j2) {
            float2 qq = qp[j2];
            unsigned int kw = kp[j2];
            ad += qq.x * bf2f((unsigned short)(kw & 0xffffu));
            ad += qq.y * bf2f((unsigned short)(kw >> 16));
          }
          sv = ad * 0.125f;
        }
        sc[c2] = sv;
        mx = fmaxf(mx, sv);
      }
      for (int off = 32; off > 0; off >>= 1) mx = fmaxf(mx, __shfl_xor(mx, off));
#pragma unroll
      for (int c2 = 0; c2 < 8; ++c2) {
        int t = lane + c2 * 64;
        float e = 0.f;
        if (t < S) { e = expf(sc[c2] - mx); Pr[wave][t] = e; }
        ssum += e;
      }
      for (int off = 32; off > 0; off >>= 1) ssum += __shfl_xor(ssum, off);
    }
    __syncthreads();
    if (act) {
      float inv = 1.0f / ssum;
      float ov = 0.f;
      for (int t = 0; t < S; ++t) ov += Pr[wave][t] * bf2f(Vs[t * 66 + lane]);
      ob[(tok0 + s) * N_ + h * 64 + lane] = ov * inv;
    }
    __syncthreads();
  }
}

// ---------------- final LN + gelu + weighted accumulate ----------------
__global__ __launch_bounds__(256) void k_fin(const float* __restrict__ y,
                                             const float* __restrict__ g,
                                             const float* __restrict__ bt,
                                             const float* __restrict__ swb,
                                             float* __restrict__ acc,
                                             const int* __restrict__ meta, int iter) {
  int L = meta[6 + iter];
  int tokens = B_ * L;
  int tok = blockIdx.x;
  if (tok >= tokens) return;
  int b = tok / L, l = tok % L;
  if (l >= T_) return;   // truncated away
  __shared__ float red[256];
  int tid = threadIdx.x;
  float val[2];
#pragma unroll
  for (int q = 0; q < 2; ++q) val[q] = y[(size_t)tok * N_ + tid + q * 256];
  red[tid] = val[0] + val[1];
  __syncthreads();
  for (int off = 128; off > 0; off >>= 1) { if (tid < off) red[tid] += red[tid + off]; __syncthreads(); }
  float mean = red[0] * (1.0f / N_);
  __syncthreads();
  float d0 = val[0] - mean, d1 = val[1] - mean;
  red[tid] = d0 * d0 + d1 * d1;
  __syncthreads();
  for (int off = 128; off > 0; off >>= 1) { if (tid < off) red[tid] += red[tid + off]; __syncthreads(); }
  float inv = rsqrtf(red[0] * (1.0f / N_) + EPS_);
  float s = swb[b * 4 + iter];
  float u0 = gelu_exact(d0 * inv * g[tid] + bt[tid]);
  float u1 = gelu_exact(d1 * inv * g[tid + 256] + bt[tid + 256]);
  size_t o = ((size_t)b * T_ + l) * N_;
  acc[o + tid] += s * u0;
  acc[o + tid + 256] += s * u1;
}

// ---------------- final output ----------------
__global__ void k_final(const float* __restrict__ acc, const float* __restrict__ cur,
                        float* __restrict__ out) {
  size_t idx = (size_t)blockIdx.x * 256 + threadIdx.x;
  out[idx] = acc[idx] + cur[idx];
}

extern "C" void kernel_launch(void* const* d_in, const int* in_sizes, int n_in,
                              void* d_out, int out_size, void* d_ws, size_t ws_size,
                              hipStream_t stream) {
  (void)in_sizes; (void)n_in; (void)out_size; (void)ws_size;
  const float* x       = (const float*)d_in[0];
  const float* nv1     = (const float*)d_in[1];
  const float* nv2     = (const float*)d_in[2];
  const float* start_w = (const float*)d_in[3];
  const float* start_b = (const float*)d_in[4];
  const float* mix_w   = (const float*)d_in[5];
  const float* mix_b   = (const float*)d_in[6];
  const float* end_w   = (const float*)d_in[7];
  const float* end_b   = (const float*)d_in[8];
  const float* glin_w  = (const float*)d_in[9];
  const float* glin_b  = (const float*)d_in[10];
  const float* gnorm_g = (const float*)d_in[11];
  const float* gnorm_b = (const float*)d_in[12];
  const float* wq = (const float*)d_in[13];
  const float* bq = (const float*)d_in[14];
  const float* wk = (const float*)d_in[15];
  const float* bk = (const float*)d_in[16];
  const float* wv = (const float*)d_in[17];
  const float* bv = (const float*)d_in[18];
  const float* wo = (const float*)d_in[19];
  const float* bo = (const float*)d_in[20];
  const float* ff1w = (const float*)d_in[21];
  const float* ff1b = (const float*)d_in[22];
  const float* ff2w = (const float*)d_in[23];
  const float* ff2b = (const float*)d_in[24];
  const float* an1g = (const float*)d_in[25];
  const float* an1b = (const float*)d_in[26];
  const float* an2g = (const float*)d_in[27];
  const float* an2b = (const float*)d_in[28];
  const float* nrmg = (const float*)d_in[29];
  const float* nrmb = (const float*)d_in[30];

  char* ws = (char*)d_ws;
  int*   meta = (int*)(ws + OFF_META);
  float* freq = (float*)(ws + OFF_FREQ);
  float* swb  = (float*)(ws + OFF_SW);
  float* a32  = (float*)(ws + OFF_A32);
  float* beff = (float*)(ws + OFF_BEFF);
  float* P12  = (float*)(ws + OFF_P12);
  float* osm  = (float*)(ws + OFF_OSM);
  unsigned short* WB  = (unsigned short*)(ws + OFF_WB);
  unsigned short* WdH = (unsigned short*)(ws + OFF_WDH);
  unsigned short* WdL = (unsigned short*)(ws + OFF_WDL);
  unsigned short* EWH = (unsigned short*)(ws + OFF_EWH);
  unsigned short* EWL = (unsigned short*)(ws + OFF_EWL);
  float* cur  = (float*)(ws + OFF_CUR);
  float* accb = (float*)(ws + OFF_ACC);
  float* fpart = (float*)(ws + OFF_FP);
  float* Tm   = (float*)(ws + OFF_T);
  float* Wp   = (float*)(ws + OFF_WP);
  unsigned short* WPH = (unsigned short*)(ws + OFF_WPH);
  unsigned short* WPL = (unsigned short*)(ws + OFF_WPL);
  float* G    = (float*)(ws + OFF_G);
  float* G2   = (float*)(ws + OFF_G2);
  float* PART = (float*)(ws + OFF_PART);
  float* A0 = (float*)(ws + OFF_A0);
  float* A2 = (float*)(ws + OFF_A2);
  float* A3 = (float*)(ws + OFF_A3);
  float* A4 = (float*)(ws + OFF_A4);
  float* A5 = (float*)(ws + OFF_A5);

  hipMemsetAsync(accb, 0, (size_t)B_ * T_ * N_ * 4, stream);

  k_stft2<<<NSB_, 256, 0, stream>>>(x, fpart);
  k_fred<<<NBIN_, 256, 0, stream>>>(fpart, freq);
  k_topk<<<1, 64, 0, stream>>>(freq, meta);
  k_sw<<<B_, 256, 0, stream>>>(x, meta, swb);

  // split attention/FF weights into bf16 hi/lo planes (once)
  const float* wlist[6] = {wq, wk, wv, wo, ff1w, ff2w};
  for (int w = 0; w < 6; ++w)
    k_split<<<256, 256, 0, stream>>>(wlist[w], WB + (size_t)w * 2 * 262144,
                                     WB + (size_t)(w * 2 + 1) * 262144, 262144);
  unsigned short* WqH = WB;               unsigned short* WqL = WB + 262144;
  unsigned short* WkH = WB + 2 * 262144;  unsigned short* WkL = WB + 3 * 262144;
  unsigned short* WvH = WB + 4 * 262144;  unsigned short* WvL = WB + 5 * 262144;
  unsigned short* WoH = WB + 6 * 262144;  unsigned short* WoL = WB + 7 * 262144;
  unsigned short* F1H = WB + 8 * 262144;  unsigned short* F1L = WB + 9 * 262144;
  unsigned short* F2H = WB + 10 * 262144; unsigned short* F2L = WB + 11 * 262144;

  const float* curIn = x;
  for (int i = 0; i < 3; ++i) {
    // ---- graph block: fold conv+GCN+mix into one weight matrix W' = T @ Wd ----
    k_adj<<<1, 64, 0, stream>>>(nv1 + i * C_ * 10, nv2 + i * 10 * C_, a32);
    k_prep<<<1, 1024, 0, stream>>>(a32, mix_w + i * C_ * 96, mix_b + i * C_,
                                   start_b + i * C_, P12, beff);
    k_T<<<4096, 256, 0, stream>>>(P12, mix_w + i * C_ * 96, Tm);
    k_wd2<<<2048, 256, 0, stream>>>(start_w + i * C_ * KH_, WdH, WdL);
    k_mm<<<dim3(4, 8, 8), 256, 0, stream>>>(Tm, WdH, WdL, nullptr, nullptr, PART,
                                            1024, 512, 1024, 1024, nullptr, 0);
    k_red<<<2048, 256, 0, stream>>>(PART, nullptr, Wp);
    k_split<<<512, 256, 0, stream>>>(Wp, WPH, WPL, 524288);
    // G = gelu(curIn @ W'^T + b_eff)   [16384 x 1024]
    k_mm<<<dim3(8, 128, 1), 256, 0, stream>>>(curIn, WPH, WPL, beff, G, nullptr,
                                              16384, 1024, 512, 512, nullptr, 1);
    k_repack<<<B_ * C_ * 16, 256, 0, stream>>>(G, G2);
    k_split<<<8192, 256, 0, stream>>>(end_w + (size_t)i * 8388608, EWH, EWL, 8388608);
    k_mm<<<dim3(4, 8, 8), 256, 0, stream>>>(G2, EWH, EWL, nullptr, nullptr, PART,
                                            1024, 512, 16384, 16384, nullptr, 0);
    k_red<<<2048, 256, 0, stream>>>(PART, end_b + i * T_, osm);
    k_lwln<<<B_ * T_, 256, 0, stream>>>(osm, glin_w + i * C_ * N_, glin_b + i * N_, curIn,
                                        gnorm_g + i * N_, gnorm_b + i * N_, cur);
    // ---- attention branch ----
    const int* Mdyn = meta + 15 + i;
    k_pad<<<4096, 256, 0, stream>>>(cur, A0, meta, i);
    dim3 gT(4, TOKMAX / 128, 1);
    k_mm<<<gT, 256, 0, stream>>>(A0, WqH, WqL, bq, A2, nullptr, TOKMAX, 512, 512, 512, Mdyn, 0);
    k_mm<<<gT, 256, 0, stream>>>(A0, WkH, WkL, bk, A3, nullptr, TOKMAX, 512, 512, 512, Mdyn, 0);
    k_mm<<<gT, 256, 0, stream>>>(A0, WvH, WvL, bv, A4, nullptr, TOKMAX, 512, 512, 512, Mdyn, 0);
    k_attn_small<<<65536, 256, 0, stream>>>(A2, A3, A4, A5, meta, i);
    k_attn_big<<<1024, 256, 0, stream>>>(A2, A3, A4, A5, meta, i);
    k_mm<<<gT, 256, 0, stream>>>(A5, WoH, WoL, bo, A2, nullptr, TOKMAX, 512, 512, 512, Mdyn, 0);
    k_lnadd<<<TOKMAX, 256, 0, stream>>>(A0, A2, an1g, an1b, A3, meta, i);
    k_mm<<<gT, 256, 0, stream>>>(A3, F1H, F1L, ff1b, A4, nullptr, TOKMAX, 512, 512, 512, Mdyn, 1);
    k_mm<<<gT, 256, 0, stream>>>(A4, F2H, F2L, ff2b, A5, nullptr, TOKMAX, 512, 512, 512, Mdyn, 0);
    k_lnadd<<<TOKMAX, 256, 0, stream>>>(A3, A5, an2g, an2b, A0, meta, i);
    k_fin<<<TOKMAX, 256, 0, stream>>>(A0, nrmg, nrmb, swb, accb, meta, i);
    curIn = cur;
  }
  k_final<<<(B_ * T_ * N_) / 256, 256, 0, stream>>>(accb, curIn, (float*)d_out);
}

// Round 5
// 2707.207 us; speedup vs baseline: 3.5228x; 1.0864x over previous
//
#include <hip/hip_runtime.h>
#include <math.h>

#define DI __device__ __forceinline__

namespace {
constexpr int B_ = 32;
constexpr int T_ = 512;
constexpr int N_ = 512;   // d_model
constexpr int C_ = 32;    // c_out / conv_ch / skip_ch
constexpr int KH_ = 481;
constexpr int HOP_ = 48;
constexpr int WIN_ = 48;
constexpr int NFR_ = 11;
constexpr int NBIN_ = 257;
constexpr int NSB_ = 4 * NFR_ * B_;   // 1408 stft blocks
constexpr int TOKMAX = 22528;   // 176*128 >= max possible tokens (21760)
constexpr float EPS_ = 1e-5f;

constexpr size_t MBY = 1ull << 20;
constexpr size_t OFF_META = 0;
constexpr size_t OFF_FREQ = 4096;
constexpr size_t OFF_SW   = 8192;
constexpr size_t OFF_A32  = 12288;
constexpr size_t OFF_BEFF = 16384;       // 1024 floats
constexpr size_t OFF_P12  = 32768;       // 2048 floats
constexpr size_t OFF_OSM  = 1 * MBY;     // 2MB
constexpr size_t OFF_WB   = 4 * MBY;     // 12 planes x 512KB = 6MB
constexpr size_t OFF_WDH  = 10 * MBY;    // 1MB  (WdT hi plane [512][1024])
constexpr size_t OFF_WDL  = 11 * MBY;    // 1MB
constexpr size_t OFF_EWH  = 12 * MBY;    // 16MB
constexpr size_t OFF_EWL  = 28 * MBY;    // 16MB
constexpr size_t OFF_CUR  = 44 * MBY;    // 32MB
constexpr size_t OFF_ACC  = 76 * MBY;    // 32MB
constexpr size_t TR       = 108 * MBY;   // transient union region
// graph phase (TR+0..64MB is scratch for the weight-fold pipeline)
constexpr size_t OFF_T    = TR;            // 4MB  T [1024][1024]
constexpr size_t OFF_WP   = TR + 4 * MBY;  // 2MB  W' fp32 [1024][512]
constexpr size_t OFF_WPH  = TR + 6 * MBY;  // 1MB  W' hi plane
constexpr size_t OFF_WPL  = TR + 7 * MBY;  // 1MB
constexpr size_t OFF_G    = TR + 64 * MBY; // 64MB
constexpr size_t OFF_G2   = TR + 128 * MBY;// 64MB [1024][16384]
constexpr size_t OFF_PART = TR + 192 * MBY;// 16MB [8][1024][512]
// attention phase (aliases graph region)
constexpr size_t OFF_A0 = TR;              // 44MB each
constexpr size_t OFF_A2 = TR + 44 * MBY;
constexpr size_t OFF_A3 = TR + 88 * MBY;
constexpr size_t OFF_A4 = TR + 132 * MBY;
constexpr size_t OFF_A5 = TR + 176 * MBY;  // ends 328MB
// stft partials alias TR (stft completes before graph phase starts)
constexpr size_t OFF_FP = TR;              // NBIN_*NSB_ floats ~1.45MB
} // namespace

typedef __attribute__((ext_vector_type(4))) float f32x4;
typedef __attribute__((ext_vector_type(8))) short bf8;
typedef __attribute__((ext_vector_type(8))) unsigned short u16x8;

DI float gelu_exact(float x) { return 0.5f * x * (1.0f + erff(x * 0.7071067811865475f)); }
DI unsigned short f2bf(float f) {   // round-to-nearest-even
  unsigned u = __float_as_uint(f);
  u += 0x7FFFu + ((u >> 16) & 1u);
  return (unsigned short)(u >> 16);
}
DI float bf2f(unsigned short s) { return __uint_as_float(((unsigned)s) << 16); }

// ---------------- STFT via phasor recurrence ----------------
__global__ __launch_bounds__(256) void k_stft2(const float* __restrict__ x,
                                               float* __restrict__ fpart) {
  int bid = blockIdx.x;
  int cc = bid & 3;
  int f = (bid >> 2) % NFR_;
  int b = bid / (4 * NFR_);
  __shared__ float xw[WIN_][128];
  int tid = threadIdx.x;
  for (int i = tid; i < WIN_ * 128; i += 256) {
    int j = i >> 7, n = i & 127;
    int gi = f * HOP_ + 232 + j - 256;
    if (gi < 0) gi = -gi;   // reflect pad (left only)
    float w = 0.5f - 0.5f * cosf((float)j * 0.13089969389957472f);   // 2pi/48
    xw[j][n] = w * x[((size_t)b * T_ + gi) * N_ + cc * 128 + n];
  }
  __syncthreads();
  for (int pair = tid; pair < NBIN_ * 16; pair += 256) {
    int k = pair >> 4;
    int n8 = (pair & 15) * 8;
    int r0 = (k * 232) & 511;                       // exact angle reduction
    float a0 = (float)r0 * 0.012271846303085130f;   // 2pi/512
    float c = cosf(a0), s = sinf(a0);
    float dA = (float)k * 0.012271846303085130f;
    float cd = cosf(dA), sd = sinf(dA);
    float re[8] = {0,0,0,0,0,0,0,0}, im[8] = {0,0,0,0,0,0,0,0};
    const float* xp = &xw[0][n8];
#pragma unroll 4
    for (int j = 0; j < WIN_; ++j) {
      float4 v0 = *(const float4*)xp;
      float4 v1 = *(const float4*)(xp + 4);
      re[0] += v0.x * c; im[0] += v0.x * s;
      re[1] += v0.y * c; im[1] += v0.y * s;
      re[2] += v0.z * c; im[2] += v0.z * s;
      re[3] += v0.w * c; im[3] += v0.w * s;
      re[4] += v1.x * c; im[4] += v1.x * s;
      re[5] += v1.y * c; im[5] += v1.y * s;
      re[6] += v1.z * c; im[6] += v1.z * s;
      re[7] += v1.w * c; im[7] += v1.w * s;
      float cn = c * cd - s * sd;
      s = s * cd + c * sd;
      c = cn;
      xp += 128;
    }
    float m = 0.f;
#pragma unroll
    for (int q = 0; q < 8; ++q) m += sqrtf(re[q] * re[q] + im[q] * im[q]);
    for (int off = 8; off > 0; off >>= 1) m += __shfl_xor(m, off);
    if ((tid & 15) == 0) fpart[(size_t)k * NSB_ + bid] = m;
  }
}

// ---------------- deterministic partial reduce -> freq ----------------
__global__ __launch_bounds__(256) void k_fred(const float* __restrict__ fpart,
                                              float* __restrict__ freq) {
  int k = blockIdx.x;
  __shared__ float red[256];
  int tid = threadIdx.x;
  float s = 0.f;
  for (int bb = tid; bb < NSB_; bb += 256) s += fpart[(size_t)k * NSB_ + bb];
  red[tid] = s;
  __syncthreads();
  for (int off = 128; off > 0; off >>= 1) {
    if (tid < off) red[tid] += red[tid + off];
    __syncthreads();
  }
  if (tid == 0) freq[k] = red[0];
}

// ---------------- top-k + meta ----------------
__global__ void k_topk(const float* __restrict__ freq, int* __restrict__ meta) {
  if (threadIdx.x == 0 && blockIdx.x == 0) {
    float bv[3] = {-1e30f, -1e30f, -1e30f};
    int bi[3] = {1, 1, 1};
    for (int k = 1; k < NBIN_; ++k) {
      float v = freq[k];
      if (v > bv[0]) { bv[2]=bv[1]; bi[2]=bi[1]; bv[1]=bv[0]; bi[1]=bi[0]; bv[0]=v; bi[0]=k; }
      else if (v > bv[1]) { bv[2]=bv[1]; bi[2]=bi[1]; bv[1]=v; bi[1]=k; }
      else if (v > bv[2]) { bv[2]=v; bi[2]=k; }
    }
    for (int i = 0; i < 3; ++i) {
      int top = bi[i];
      int p = T_ / top;
      int L = ((T_ + p - 1) / p) * p;
      meta[i] = top;
      meta[3 + i] = p;
      meta[6 + i] = L;
      meta[9 + i] = L / p;
      meta[15 + i] = B_ * L;   // tokens
    }
  }
}

// ---------------- per-batch branch weights sw ----------------
__global__ __launch_bounds__(256) void k_sw(const float* __restrict__ x,
                                            const int* __restrict__ meta,
                                            float* __restrict__ swb) {
  int b = blockIdx.x;
  __shared__ float ct[3][WIN_], st[3][WIN_];
  __shared__ float red[256];
  int tid = threadIdx.x;
  for (int i = tid; i < 3 * WIN_; i += 256) {
    int kk = i / WIN_, j = i % WIN_;
    int k = meta[kk];
    int r = (k * (232 + j)) & 511;
    float ang = (float)r * 0.012271846303085130f;
    float w = 0.5f - 0.5f * cosf((float)j * 0.13089969389957472f);
    ct[kk][j] = w * cosf(ang);
    st[kk][j] = w * sinf(ang);
  }
  __syncthreads();
  float acc[3] = {0.f, 0.f, 0.f};
  for (int it = tid; it < NFR_ * N_; it += 256) {
    int f = it / N_, n = it % N_;
    float xs[WIN_];
    for (int j = 0; j < WIN_; ++j) {
      int gi = f * HOP_ + 232 + j - 256;
      if (gi < 0) gi = -gi;
      xs[j] = x[((size_t)b * T_ + gi) * N_ + n];
    }
    for (int kk = 0; kk < 3; ++kk) {
      float re = 0.f, im = 0.f;
      for (int j = 0; j < WIN_; ++j) { re += xs[j] * ct[kk][j]; im += xs[j] * st[kk][j]; }
      acc[kk] += sqrtf(re * re + im * im);
    }
  }
  for (int kk = 0; kk < 3; ++kk) {
    red[tid] = acc[kk];
    __syncthreads();
    for (int off = 128; off > 0; off >>= 1) {
      if (tid < off) red[tid] += red[tid + off];
      __syncthreads();
    }
    if (tid == 0) swb[b * 4 + kk] = red[0];
    __syncthreads();
  }
  if (tid == 0) {
    float inv = 1.0f / (float)(NFR_ * N_);
    float m0 = swb[b*4+0]*inv, m1 = swb[b*4+1]*inv, m2 = swb[b*4+2]*inv;
    float mx = fmaxf(m0, fmaxf(m1, m2));
    float e0 = expf(m0-mx), e1 = expf(m1-mx), e2 = expf(m2-mx);
    float s = e0 + e1 + e2;
    swb[b*4+0] = e0/s; swb[b*4+1] = e1/s; swb[b*4+2] = e2/s;
  }
}

// ---------------- graph adjacency ----------------
__global__ void k_adj(const float* __restrict__ nv1, const float* __restrict__ nv2,
                      float* __restrict__ a32) {
  int v = threadIdx.x;
  if (v < C_) {
    float row[C_];
    for (int w = 0; w < C_; ++w) {
      float s = 0.f;
      for (int d = 0; d < 10; ++d) s += nv1[v * 10 + d] * nv2[d * C_ + w];
      row[w] = fmaxf(s, 0.f);
    }
    float mx = -1e30f;
    for (int w = 0; w < C_; ++w) mx = fmaxf(mx, row[w]);
    float sm = 0.f;
    for (int w = 0; w < C_; ++w) { row[w] = expf(row[w] - mx); sm += row[w]; }
    for (int w = 0; w < C_; ++w) row[w] /= sm;
    row[v] += 1.0f;
    float rs = 0.f;
    for (int w = 0; w < C_; ++w) rs += row[w];
    for (int w = 0; w < C_; ++w) a32[v * C_ + w] = row[w] / rs;
  }
}

// ---------------- GCN operator prep: P1, P2, b_eff ----------------
__global__ __launch_bounds__(1024) void k_prep(const float* __restrict__ a32,
                                               const float* __restrict__ mw,
                                               const float* __restrict__ mb,
                                               const float* __restrict__ sb,
                                               float* __restrict__ P12,
                                               float* __restrict__ beff) {
  __shared__ float Ms[32][32], P1s[32][32], P2s[32][32], S1[32], S2[32], sbl[32];
  int tid = threadIdx.x;
  int w = tid >> 5, v = tid & 31;
  Ms[w][v] = a32[v * 32 + w];
  if (tid < 32) sbl[tid] = sb[tid];
  __syncthreads();
  float p1 = 0.95f * Ms[w][v] + (w == v ? 0.05f : 0.f);
  P1s[w][v] = p1;
  __syncthreads();
  float p2 = 0.f;
  for (int u = 0; u < 32; ++u) p2 += P1s[w][u] * Ms[u][v];
  p2 = 0.95f * p2 + (w == v ? 0.05f : 0.f);
  P2s[w][v] = p2;
  P12[tid] = p1;
  P12[1024 + tid] = p2;
  __syncthreads();
  if (tid < 32) {
    float s1 = 0.f, s2 = 0.f;
    for (int u = 0; u < 32; ++u) { s1 += P1s[u][tid]; s2 += P2s[u][tid]; }
    S1[tid] = s1; S2[tid] = s2;
  }
  __syncthreads();
  int o = w;
  float be = mb[o];
  for (int c = 0; c < 32; ++c) {
    float sc = sbl[c];
    be += mw[o * 96 + c] * sc;
    be += mw[o * 96 + 32 + c] * sc * S1[v];
    be += mw[o * 96 + 64 + c] * sc * S2[v];
  }
  beff[tid] = be;
}

// ---------------- build T [1024][1024]: T[(o,v)][(c,w)] ----------------
__global__ __launch_bounds__(256) void k_T(const float* __restrict__ P12,
                                           const float* __restrict__ mw,
                                           float* __restrict__ Tm) {
  int idx = blockIdx.x * 256 + threadIdx.x;
  int r = idx >> 10, k2 = idx & 1023;
  int o = r >> 5, v = r & 31;
  int c = k2 >> 5, w = k2 & 31;
  float t = mw[o * 96 + 32 + c] * P12[w * 32 + v]
          + mw[o * 96 + 64 + c] * P12[1024 + w * 32 + v];
  if (w == v) t += mw[o * 96 + c];
  Tm[idx] = t;
}

// ---------------- build WdT hi/lo: WdT[j][(c,w)] = sw[c][j-w] ----------------
__global__ void k_wd2(const float* __restrict__ swi,
                      unsigned short* __restrict__ WH, unsigned short* __restrict__ WL) {
  int idx = blockIdx.x * 256 + threadIdx.x;   // 512*1024
  int j = idx >> 10, k2 = idx & 1023;
  int c = k2 >> 5, w = k2 & 31;
  int kk = j - w;
  float vv = (kk >= 0 && kk < KH_) ? swi[c * KH_ + kk] : 0.f;
  unsigned short h = f2bf(vv);
  WH[idx] = h;
  WL[idx] = f2bf(vv - bf2f(h));
}

// ---------------- weight hi/lo split ----------------
__global__ void k_split(const float* __restrict__ src, unsigned short* __restrict__ Hi,
                        unsigned short* __restrict__ Lo, int n) {
  int i = blockIdx.x * 256 + threadIdx.x;
  if (i * 4 >= n) return;
  float4 v = *(const float4*)&src[i * 4];
  float vv[4] = {v.x, v.y, v.z, v.w};
  ushort4 h, l;
  unsigned short hs[4], ls[4];
#pragma unroll
  for (int j = 0; j < 4; ++j) {
    unsigned short hh = f2bf(vv[j]);
    hs[j] = hh;
    ls[j] = f2bf(vv[j] - bf2f(hh));
  }
  h.x = hs[0]; h.y = hs[1]; h.z = hs[2]; h.w = hs[3];
  l.x = ls[0]; l.y = ls[1]; l.z = ls[2]; l.w = ls[3];
  *(ushort4*)&Hi[i * 4] = h;
  *(ushort4*)&Lo[i * 4] = l;
}

// ---------------- split-bf16 MFMA GEMM ----------------
__global__ __launch_bounds__(256, 2) void k_mm(
    const float* __restrict__ A, const unsigned short* __restrict__ Bh,
    const unsigned short* __restrict__ Bl, const float* __restrict__ bias,
    float* __restrict__ C, float* __restrict__ Cpart,
    int M, int N, int K, int lda, const int* __restrict__ Mdyn, int dogelu) {
  if (Mdyn) M = *Mdyn;
  const int bm = blockIdx.y * 128;
  if (bm >= M) return;
  const int bn = blockIdx.x * 128;
  const int nz = gridDim.z, z = blockIdx.z;
  const int kpb = K / nz;
  const int kbeg = z * kpb, kend = kbeg + kpb;

  __shared__ unsigned short AhS[4096], AlS[4096], BhS[4096], BlS[4096];

  const int tid = threadIdx.x;
  const int wave = tid >> 6, lane = tid & 63;
  const int wr = wave >> 1, wc = wave & 1;
  const int fr = lane & 15, fs = lane >> 4;

  const int sr = tid >> 1, ss = (tid & 1) * 2;
  const int sx = (sr >> 1) & 3;
  const int so0 = sr * 32 + 8 * (ss ^ sx);
  const int so1 = sr * 32 + 8 * ((ss + 1) ^ sx);

  int aoff[4], boff[4];
#pragma unroll
  for (int m = 0; m < 4; ++m) {
    int ra = wr * 64 + m * 16 + fr;
    aoff[m] = ra * 32 + 8 * (fs ^ ((ra >> 1) & 3));
    int rb = wc * 64 + m * 16 + fr;
    boff[m] = rb * 32 + 8 * (fs ^ ((rb >> 1) & 3));
  }

  const bool aok = (bm + sr) < M;
  const float* Arow = A + (size_t)(bm + sr) * lda + ss * 8;
  const unsigned short* BhRow = Bh + (size_t)(bn + sr) * K + ss * 8;
  const unsigned short* BlRow = Bl + (size_t)(bn + sr) * K + ss * 8;

  f32x4 acc[4][4];
#pragma unroll
  for (int m = 0; m < 4; ++m)
#pragma unroll
    for (int n = 0; n < 4; ++n) acc[m][n] = (f32x4){0.f, 0.f, 0.f, 0.f};

  for (int k0 = kbeg; k0 < kend; k0 += 32) {
    float4 a0, a1, a2, a3;
    if (aok) {
      const float4* p = (const float4*)(Arow + k0);
      a0 = p[0]; a1 = p[1]; a2 = p[2]; a3 = p[3];
    } else {
      a0 = a1 = a2 = a3 = make_float4(0.f, 0.f, 0.f, 0.f);
    }
    u16x8 gb0 = *(const u16x8*)(BhRow + k0);
    u16x8 gb1 = *(const u16x8*)(BhRow + k0 + 8);
    u16x8 gl0 = *(const u16x8*)(BlRow + k0);
    u16x8 gl1 = *(const u16x8*)(BlRow + k0 + 8);
    float av[16];
    av[0]=a0.x; av[1]=a0.y; av[2]=a0.z; av[3]=a0.w;
    av[4]=a1.x; av[5]=a1.y; av[6]=a1.z; av[7]=a1.w;
    av[8]=a2.x; av[9]=a2.y; av[10]=a2.z; av[11]=a2.w;
    av[12]=a3.x; av[13]=a3.y; av[14]=a3.z; av[15]=a3.w;
    u16x8 h0, h1, l0, l1;
#pragma unroll
    for (int j = 0; j < 8; ++j) {   // truncation split: err <= 2^-16 rel
      unsigned u = __float_as_uint(av[j]);
      h0[j] = (unsigned short)(u >> 16);
      float r2 = av[j] - __uint_as_float(u & 0xffff0000u);
      l0[j] = (unsigned short)(__float_as_uint(r2) >> 16);
      unsigned u2 = __float_as_uint(av[j + 8]);
      h1[j] = (unsigned short)(u2 >> 16);
      float r3 = av[j + 8] - __uint_as_float(u2 & 0xffff0000u);
      l1[j] = (unsigned short)(__float_as_uint(r3) >> 16);
    }
    __syncthreads();
    *(u16x8*)&AhS[so0] = h0; *(u16x8*)&AhS[so1] = h1;
    *(u16x8*)&AlS[so0] = l0; *(u16x8*)&AlS[so1] = l1;
    *(u16x8*)&BhS[so0] = gb0; *(u16x8*)&BhS[so1] = gb1;
    *(u16x8*)&BlS[so0] = gl0; *(u16x8*)&BlS[so1] = gl1;
    __syncthreads();
    bf8 ah[4], al4[4], bh4[4], bl4[4];
#pragma unroll
    for (int m = 0; m < 4; ++m) {
      ah[m]  = *(const bf8*)&AhS[aoff[m]];
      al4[m] = *(const bf8*)&AlS[aoff[m]];
    }
#pragma unroll
    for (int n = 0; n < 4; ++n) {
      bh4[n] = *(const bf8*)&BhS[boff[n]];
      bl4[n] = *(const bf8*)&BlS[boff[n]];
    }
#pragma unroll
    for (int m = 0; m < 4; ++m)
#pragma unroll
      for (int n = 0; n < 4; ++n) {
        acc[m][n] = __builtin_amdgcn_mfma_f32_16x16x32_bf16(ah[m],  bh4[n], acc[m][n], 0, 0, 0);
        acc[m][n] = __builtin_amdgcn_mfma_f32_16x16x32_bf16(al4[m], bh4[n], acc[m][n], 0, 0, 0);
        acc[m][n] = __builtin_amdgcn_mfma_f32_16x16x32_bf16(ah[m],  bl4[n], acc[m][n], 0, 0, 0);
      }
  }

  if (nz > 1) {
    float* P = Cpart + (size_t)z * M * N;
#pragma unroll
    for (int m = 0; m < 4; ++m)
#pragma unroll
      for (int r = 0; r < 4; ++r) {
        int row = bm + wr * 64 + m * 16 + fs * 4 + r;
        if (row < M) {
#pragma unroll
          for (int n = 0; n < 4; ++n) {
            int col = bn + wc * 64 + n * 16 + fr;
            P[(size_t)row * N + col] = acc[m][n][r];
          }
        }
      }
  } else {
    float bcol[4];
#pragma unroll
    for (int n = 0; n < 4; ++n) bcol[n] = bias ? bias[bn + wc * 64 + n * 16 + fr] : 0.f;
#pragma unroll
    for (int m = 0; m < 4; ++m)
#pragma unroll
      for (int r = 0; r < 4; ++r) {
        int row = bm + wr * 64 + m * 16 + fs * 4 + r;
        if (row < M) {
#pragma unroll
          for (int n = 0; n < 4; ++n) {
            int col = bn + wc * 64 + n * 16 + fr;
            float v = acc[m][n][r] + bcol[n];
            if (dogelu) v = gelu_exact(v);
            C[(size_t)row * N + col] = v;
          }
        }
      }
  }
}

// ---------------- split-K reduce (+optional bias) ----------------
__global__ void k_red(const float* __restrict__ part, const float* __restrict__ eb,
                      float* __restrict__ dst) {
  int idx = blockIdx.x * 256 + threadIdx.x;   // 1024*512
  float s = eb ? eb[idx & 511] : 0.f;
#pragma unroll
  for (int zz = 0; zz < 8; ++zz) s += part[(size_t)zz * 524288 + idx];
  dst[idx] = s;
}

// ---------------- repack G[(b,s),(c,n)] -> G2[(b,n),(c,s)] ----------------
__global__ __launch_bounds__(256) void k_repack(const float* __restrict__ G,
                                                float* __restrict__ G2) {
  int bid = blockIdx.x;
  int st = bid & 15, c = (bid >> 4) & 31, b = bid >> 9;
  __shared__ float tile[32][33];
  int tid = threadIdx.x;
  int n = tid & 31, s = tid >> 5;
  for (int q = 0; q < 4; ++q) {
    int ss = s + q * 8;
    tile[ss][n] = G[((size_t)b * T_ + st * 32 + ss) * 1024 + c * 32 + n];
  }
  __syncthreads();
  int s2 = tid & 31, n2 = tid >> 5;
  for (int q = 0; q < 4; ++q) {
    int nn = n2 + q * 8;
    G2[((size_t)b * 32 + nn) * 16384 + c * 512 + st * 32 + s2] = tile[s2][nn];
  }
}

// ---------------- lw projection + residual + LN (graph epilogue) ----------------
__global__ __launch_bounds__(256) void k_lwln(const float* __restrict__ osm,
                                              const float* __restrict__ lw,
                                              const float* __restrict__ lb,
                                              const float* __restrict__ curIn,
                                              const float* __restrict__ g,
                                              const float* __restrict__ bt,
                                              float* __restrict__ curOut) {
  int tok = blockIdx.x;
  int b = tok >> 9, t = tok & 511;
  __shared__ float os[C_];
  __shared__ float red[256];
  int tid = threadIdx.x;
  if (tid < C_) os[tid] = osm[((size_t)b * C_ + tid) * T_ + t];
  __syncthreads();
  float val[2];
#pragma unroll
  for (int q = 0; q < 2; ++q) {
    int m = tid + q * 256;
    float s = lb[m] + curIn[(size_t)tok * N_ + m];
    for (int n2 = 0; n2 < C_; ++n2) s += os[n2] * lw[n2 * N_ + m];
    val[q] = s;
  }
  red[tid] = val[0] + val[1];
  __syncthreads();
  for (int off = 128; off > 0; off >>= 1) { if (tid < off) red[tid] += red[tid + off]; __syncthreads(); }
  float mean = red[0] * (1.0f / N_);
  __syncthreads();
  float d0 = val[0] - mean, d1 = val[1] - mean;
  red[tid] = d0 * d0 + d1 * d1;
  __syncthreads();
  for (int off = 128; off > 0; off >>= 1) { if (tid < off) red[tid] += red[tid + off]; __syncthreads(); }
  float inv = rsqrtf(red[0] * (1.0f / N_) + EPS_);
  curOut[(size_t)tok * N_ + tid] = d0 * inv * g[tid] + bt[tid];
  curOut[(size_t)tok * N_ + tid + 256] = d1 * inv * g[tid + 256] + bt[tid + 256];
}

// ---------------- zero-pad tokens ----------------
__global__ void k_pad(const float* __restrict__ cur, float* __restrict__ xa,
                      const int* __restrict__ meta, int iter) {
  int L = meta[6 + iter];
  size_t total = (size_t)(B_ * L) * N_;
  for (size_t idx = (size_t)blockIdx.x * 256 + threadIdx.x; idx < total;
       idx += (size_t)gridDim.x * 256) {
    size_t tokd = idx >> 9;
    int d = (int)(idx & 511);
    int b = (int)(tokd / L), l = (int)(tokd % L);
    xa[idx] = (l < T_) ? cur[((size_t)b * T_ + l) * N_ + d] : 0.f;
  }
}

// ---------------- residual add + LN (attention) ----------------
__global__ __launch_bounds__(256) void k_lnadd(const float* __restrict__ r1,
                                               const float* __restrict__ r2,
                                               const float* __restrict__ g,
                                               const float* __restrict__ bt,
                                               float* __restrict__ dst,
                                               const int* __restrict__ meta, int iter) {
  int tokens = meta[15 + iter];
  int tok = blockIdx.x;
  if (tok >= tokens) return;
  __shared__ float red[256];
  int tid = threadIdx.x;
  float val[2];
#pragma unroll
  for (int q = 0; q < 2; ++q) {
    int m = tid + q * 256;
    val[q] = r1[(size_t)tok * N_ + m] + r2[(size_t)tok * N_ + m];
  }
  red[tid] = val[0] + val[1];
  __syncthreads();
  for (int off = 128; off > 0; off >>= 1) { if (tid < off) red[tid] += red[tid + off]; __syncthreads(); }
  float mean = red[0] * (1.0f / N_);
  __syncthreads();
  float d0 = val[0] - mean, d1 = val[1] - mean;
  red[tid] = d0 * d0 + d1 * d1;
  __syncthreads();
  for (int off = 128; off > 0; off >>= 1) { if (tid < off) red[tid] += red[tid + off]; __syncthreads(); }
  float inv = rsqrtf(red[0] * (1.0f / N_) + EPS_);
  dst[(size_t)tok * N_ + tid] = d0 * inv * g[tid] + bt[tid];
  dst[(size_t)tok * N_ + tid + 256] = d1 * inv * g[tid + 256] + bt[tid + 256];
}

// ---------------- register attention, S<=32: wave per (seq,head), no LDS ----------------
// SMAX=8 handles S in [2,8]; SMAX=32 handles (8,32]. lane = head dim.
// K/V rows in registers (compile-time indices only), dots via 6-step shfl_xor.
template <int SMAX>
__global__ __launch_bounds__(256) void k_attn_reg(const float* __restrict__ qb,
                                                  const float* __restrict__ kb,
                                                  const float* __restrict__ vb,
                                                  float* __restrict__ ob,
                                                  const int* __restrict__ meta, int iter) {
  int S = meta[3 + iter];
  if (SMAX == 8) { if (S > 8) return; }
  else           { if (S <= 8 || S > SMAX) return; }
  int L = meta[6 + iter], nseq = meta[9 + iter];
  int npair = B_ * nseq * 8;
  int lane = threadIdx.x & 63;
  int gw = (blockIdx.x * 256 + threadIdx.x) >> 6;
  int nw = (gridDim.x * 256) >> 6;
  for (int pair = gw; pair < npair; pair += nw) {
    int h = pair & 7;
    int m = pair >> 3;
    int b = m / nseq, g2 = m - b * nseq;
    size_t base = ((size_t)b * L + (size_t)g2 * S) * N_ + h * 64 + lane;
    float kreg[SMAX], vreg[SMAX];
#pragma unroll
    for (int t = 0; t < SMAX; ++t) {
      if (t < S) {
        kreg[t] = kb[base + (size_t)t * N_];
        vreg[t] = vb[base + (size_t)t * N_];
      } else { kreg[t] = 0.f; vreg[t] = 0.f; }
    }
    for (int s = 0; s < S; ++s) {
      float q = qb[base + (size_t)s * N_];
      float sc[SMAX];
      float mx = -3.0e38f;
#pragma unroll
      for (int t = 0; t < SMAX; ++t) {
        sc[t] = -3.0e38f;
        if (t < S) {                    // wave-uniform branch
          float d = q * kreg[t];
#pragma unroll
          for (int off = 32; off > 0; off >>= 1) d += __shfl_xor(d, off);
          sc[t] = d * 0.125f;
          mx = fmaxf(mx, sc[t]);
        }
      }
      float ssum = 0.f, o = 0.f;
#pragma unroll
      for (int t = 0; t < SMAX; ++t) {
        if (t < S) {
          float e = expf(sc[t] - mx);
          ssum += e;
          o += e * vreg[t];
        }
      }
      ob[base + (size_t)s * N_] = o / ssum;
    }
  }
}

// ---------------- fused attention, 32<S<=128, fp32 K/V in LDS ----------------
__global__ __launch_bounds__(256) void k_attn_small(const float* __restrict__ qb,
                                                    const float* __restrict__ kb,
                                                    const float* __restrict__ vb,
                                                    float* __restrict__ ob,
                                                    const int* __restrict__ meta, int iter) {
  int p = meta[3 + iter];
  if (p <= 32 || p > 128) return;
  int L = meta[6 + iter], nseq = meta[9 + iter];
  int M = B_ * nseq;
  int mh = blockIdx.x;
  int m = mh >> 3, h = mh & 7;
  if (m >= M) return;
  int S = p;
  int b = m / nseq, g2 = m % nseq;
  size_t tok0 = (size_t)b * L + (size_t)g2 * S;
  __shared__ float Ks[64 * 129];
  __shared__ float Vs[128 * 65];
  __shared__ float qrow[4][64];
  __shared__ float Pr[4][128];
  int tid = threadIdx.x;
  for (int i = tid; i < S * 64; i += 256) {
    int t = i >> 6, d = i & 63;
    float kv = kb[(tok0 + t) * N_ + h * 64 + d];
    float vv = vb[(tok0 + t) * N_ + h * 64 + d];
    Ks[d * 129 + t] = kv;
    Vs[t * 65 + d] = vv;
  }
  __syncthreads();
  int wave = tid >> 6, lane = tid & 63;
  int rounds = (S + 3) >> 2;
  for (int r = 0; r < rounds; ++r) {
    int s = r * 4 + wave;
    bool act = (s < S);
    if (act) qrow[wave][lane] = qb[(tok0 + s) * N_ + h * 64 + lane];
    __syncthreads();
    float sc[2];
    float ssum = 0.f;
    if (act) {
      float mx = -3.0e38f;
#pragma unroll
      for (int c2 = 0; c2 < 2; ++c2) {
        int t = lane + c2 * 64;
        float sv = -3.0e38f;
        if (t < S) {
          float ad = 0.f;
#pragma unroll 16
          for (int j = 0; j < 64; ++j) ad += qrow[wave][j] * Ks[j * 129 + t];
          sv = ad * 0.125f;
        }
        sc[c2] = sv;
        mx = fmaxf(mx, sv);
      }
      for (int off = 32; off > 0; off >>= 1) mx = fmaxf(mx, __shfl_xor(mx, off));
#pragma unroll
      for (int c2 = 0; c2 < 2; ++c2) {
        int t = lane + c2 * 64;
        float e = 0.f;
        if (t < S) { e = expf(sc[c2] - mx); Pr[wave][t] = e; }
        ssum += e;
      }
      for (int off = 32; off > 0; off >>= 1) ssum += __shfl_xor(ssum, off);
    }
    __syncthreads();
    if (act) {
      float inv = 1.0f / ssum;
      float ov = 0.f;
      for (int t = 0; t < S; ++t) ov += Pr[wave][t] * Vs[t * 65 + lane];
      ob[(tok0 + s) * N_ + h * 64 + lane] = ov * inv;
    }
    __syncthreads();
  }
}

// ---------------- fused attention, 128<S<=512, bf16 K/V (rare path) ----------------
__global__ __launch_bounds__(256) void k_attn_big(const float* __restrict__ qb,
                                                  const float* __restrict__ kb,
                                                  const float* __restrict__ vb,
                                                  float* __restrict__ ob,
                                                  const int* __restrict__ meta, int iter) {
  int p = meta[3 + iter];
  if (p <= 128) return;
  int L = meta[6 + iter], nseq = meta[9 + iter];
  int M = B_ * nseq;
  int mh = blockIdx.x;
  int m = mh >> 3, h = mh & 7;
  if (m >= M) return;
  int S = p;
  int b = m / nseq, g2 = m % nseq;
  size_t tok0 = (size_t)b * L + (size_t)g2 * S;
  __shared__ unsigned short Ks[512 * 66];
  __shared__ unsigned short Vs[512 * 66];
  __shared__ float qrow[4][64];
  __shared__ float Pr[4][512];
  int tid = threadIdx.x;
  for (int i = tid; i < S * 64; i += 256) {
    int t = i >> 6, d = i & 63;
    Ks[t * 66 + d] = f2bf(kb[(tok0 + t) * N_ + h * 64 + d]);
    Vs[t * 66 + d] = f2bf(vb[(tok0 + t) * N_ + h * 64 + d]);
  }
  __syncthreads();
  int wave = tid >> 6, lane = tid & 63;
  int rounds = (S + 3) >> 2;
  for (int r = 0; r < rounds; ++r) {
    int s = r * 4 + wave;
    bool act = (s < S);
    if (act) qrow[wave][lane] = qb[(tok0 + s) * N_ + h * 64 + lane];
    __syncthreads();
    float sc[8];
    float ssum = 0.f;
    if (act) {
      const float2* qp = (const float2*)&qrow[wave][0];
      float mx = -3.0e38f;
#pragma unroll
      for (int c2 = 0; c2 < 8; ++c2) {
        int t = lane + c2 * 64;
        float sv = -3.0e38f;
        if (t < S) {
          const unsigned int* kp = (const unsigned int*)&Ks[t * 66];
          float ad = 0.f;
#pragma unroll
          for (int j2 = 0; j2 < 32; ++j2) {
            float2 qq = qp[j2];
            unsigned int kw = kp[j2];
            ad += qq.x * bf2f((unsigned short)(kw & 0xffffu));
            ad += qq.y * bf2f((unsigned short)(kw >> 16));
          }
          sv = ad * 0.125f;
        }
        sc[c2] = sv;
        mx = fmaxf(mx, sv);
      }
      for (int off = 32; off > 0; off >>= 1) mx = fmaxf(mx, __shfl_xor(mx, off));
#pragma unroll
      for (int c2 = 0; c2 < 8; ++c2) {
        int t = lane + c2 * 64;
        float e = 0.f;
        if (t < S) { e = expf(sc[c2] - mx); Pr[wave][t] = e; }
        ssum += e;
      }
      for (int off = 32; off > 0; off >>= 1) ssum += __shfl_xor(ssum, off);
    }
    __syncthreads();
    if (act) {
      float inv = 1.0f / ssum;
      float ov = 0.f;
      for (int t = 0; t < S; ++t) ov += Pr[wave][t] * bf2f(Vs[t * 66 + lane]);
      ob[(tok0 + s) * N_ + h * 64 + lane] = ov * inv;
    }
    __syncthreads();
  }
}

// ---------------- final LN + gelu + weighted accumulate ----------------
__global__ __launch_bounds__(256) void k_fin(const float* __restrict__ y,
                                             const float* __restrict__ g,
                                             const float* __restrict__ bt,
                                             const float* __restrict__ swb,
                                             float* __restrict__ acc,
                                             const int* __restrict__ meta, int iter) {
  int L = meta[6 + iter];
  int tokens = B_ * L;
  int tok = blockIdx.x;
  if (tok >= tokens) return;
  int b = tok / L, l = tok % L;
  if (l >= T_) return;   // truncated away
  __shared__ float red[256];
  int tid = threadIdx.x;
  float val[2];
#pragma unroll
  for (int q = 0; q < 2; ++q) val[q] = y[(size_t)tok * N_ + tid + q * 256];
  red[tid] = val[0] + val[1];
  __syncthreads();
  for (int off = 128; off > 0; off >>= 1) { if (tid < off) red[tid] += red[tid + off]; __syncthreads(); }
  float mean = red[0] * (1.0f / N_);
  __syncthreads();
  float d0 = val[0] - mean, d1 = val[1] - mean;
  red[tid] = d0 * d0 + d1 * d1;
  __syncthreads();
  for (int off = 128; off > 0; off >>= 1) { if (tid < off) red[tid] += red[tid + off]; __syncthreads(); }
  float inv = rsqrtf(red[0] * (1.0f / N_) + EPS_);
  float s = swb[b * 4 + iter];
  float u0 = gelu_exact(d0 * inv * g[tid] + bt[tid]);
  float u1 = gelu_exact(d1 * inv * g[tid + 256] + bt[tid + 256]);
  size_t o = ((size_t)b * T_ + l) * N_;
  acc[o + tid] += s * u0;
  acc[o + tid + 256] += s * u1;
}

// ---------------- final output ----------------
__global__ void k_final(const float* __restrict__ acc, const float* __restrict__ cur,
                        float* __restrict__ out) {
  size_t idx = (size_t)blockIdx.x * 256 + threadIdx.x;
  out[idx] = acc[idx] + cur[idx];
}

extern "C" void kernel_launch(void* const* d_in, const int* in_sizes, int n_in,
                              void* d_out, int out_size, void* d_ws, size_t ws_size,
                              hipStream_t stream) {
  (void)in_sizes; (void)n_in; (void)out_size; (void)ws_size;
  const float* x       = (const float*)d_in[0];
  const float* nv1     = (const float*)d_in[1];
  const float* nv2     = (const float*)d_in[2];
  const float* start_w = (const float*)d_in[3];
  const float* start_b = (const float*)d_in[4];
  const float* mix_w   = (const float*)d_in[5];
  const float* mix_b   = (const float*)d_in[6];
  const float* end_w   = (const float*)d_in[7];
  const float* end_b   = (const float*)d_in[8];
  const float* glin_w  = (const float*)d_in[9];
  const float* glin_b  = (const float*)d_in[10];
  const float* gnorm_g = (const float*)d_in[11];
  const float* gnorm_b = (const float*)d_in[12];
  const float* wq = (const float*)d_in[13];
  const float* bq = (const float*)d_in[14];
  const float* wk = (const float*)d_in[15];
  const float* bk = (const float*)d_in[16];
  const float* wv = (const float*)d_in[17];
  const float* bv = (const float*)d_in[18];
  const float* wo = (const float*)d_in[19];
  const float* bo = (const float*)d_in[20];
  const float* ff1w = (const float*)d_in[21];
  const float* ff1b = (const float*)d_in[22];
  const float* ff2w = (const float*)d_in[23];
  const float* ff2b = (const float*)d_in[24];
  const float* an1g = (const float*)d_in[25];
  const float* an1b = (const float*)d_in[26];
  const float* an2g = (const float*)d_in[27];
  const float* an2b = (const float*)d_in[28];
  const float* nrmg = (const float*)d_in[29];
  const float* nrmb = (const float*)d_in[30];

  char* ws = (char*)d_ws;
  int*   meta = (int*)(ws + OFF_META);
  float* freq = (float*)(ws + OFF_FREQ);
  float* swb  = (float*)(ws + OFF_SW);
  float* a32  = (float*)(ws + OFF_A32);
  float* beff = (float*)(ws + OFF_BEFF);
  float* P12  = (float*)(ws + OFF_P12);
  float* osm  = (float*)(ws + OFF_OSM);
  unsigned short* WB  = (unsigned short*)(ws + OFF_WB);
  unsigned short* WdH = (unsigned short*)(ws + OFF_WDH);
  unsigned short* WdL = (unsigned short*)(ws + OFF_WDL);
  unsigned short* EWH = (unsigned short*)(ws + OFF_EWH);
  unsigned short* EWL = (unsigned short*)(ws + OFF_EWL);
  float* cur  = (float*)(ws + OFF_CUR);
  float* accb = (float*)(ws + OFF_ACC);
  float* fpart = (float*)(ws + OFF_FP);
  float* Tm   = (float*)(ws + OFF_T);
  float* Wp   = (float*)(ws + OFF_WP);
  unsigned short* WPH = (unsigned short*)(ws + OFF_WPH);
  unsigned short* WPL = (unsigned short*)(ws + OFF_WPL);
  float* G    = (float*)(ws + OFF_G);
  float* G2   = (float*)(ws + OFF_G2);
  float* PART = (float*)(ws + OFF_PART);
  float* A0 = (float*)(ws + OFF_A0);
  float* A2 = (float*)(ws + OFF_A2);
  float* A3 = (float*)(ws + OFF_A3);
  float* A4 = (float*)(ws + OFF_A4);
  float* A5 = (float*)(ws + OFF_A5);

  hipMemsetAsync(accb, 0, (size_t)B_ * T_ * N_ * 4, stream);

  k_stft2<<<NSB_, 256, 0, stream>>>(x, fpart);
  k_fred<<<NBIN_, 256, 0, stream>>>(fpart, freq);
  k_topk<<<1, 64, 0, stream>>>(freq, meta);
  k_sw<<<B_, 256, 0, stream>>>(x, meta, swb);

  // split attention/FF weights into bf16 hi/lo planes (once)
  const float* wlist[6] = {wq, wk, wv, wo, ff1w, ff2w};
  for (int w = 0; w < 6; ++w)
    k_split<<<256, 256, 0, stream>>>(wlist[w], WB + (size_t)w * 2 * 262144,
                                     WB + (size_t)(w * 2 + 1) * 262144, 262144);
  unsigned short* WqH = WB;               unsigned short* WqL = WB + 262144;
  unsigned short* WkH = WB + 2 * 262144;  unsigned short* WkL = WB + 3 * 262144;
  unsigned short* WvH = WB + 4 * 262144;  unsigned short* WvL = WB + 5 * 262144;
  unsigned short* WoH = WB + 6 * 262144;  unsigned short* WoL = WB + 7 * 262144;
  unsigned short* F1H = WB + 8 * 262144;  unsigned short* F1L = WB + 9 * 262144;
  unsigned short* F2H = WB + 10 * 262144; unsigned short* F2L = WB + 11 * 262144;

  const float* curIn = x;
  for (int i = 0; i < 3; ++i) {
    // ---- graph block: fold conv+GCN+mix into one weight matrix W' = T @ Wd ----
    k_adj<<<1, 64, 0, stream>>>(nv1 + i * C_ * 10, nv2 + i * 10 * C_, a32);
    k_prep<<<1, 1024, 0, stream>>>(a32, mix_w + i * C_ * 96, mix_b + i * C_,
                                   start_b + i * C_, P12, beff);
    k_T<<<4096, 256, 0, stream>>>(P12, mix_w + i * C_ * 96, Tm);
    k_wd2<<<2048, 256, 0, stream>>>(start_w + i * C_ * KH_, WdH, WdL);
    k_mm<<<dim3(4, 8, 8), 256, 0, stream>>>(Tm, WdH, WdL, nullptr, nullptr, PART,
                                            1024, 512, 1024, 1024, nullptr, 0);
    k_red<<<2048, 256, 0, stream>>>(PART, nullptr, Wp);
    k_split<<<512, 256, 0, stream>>>(Wp, WPH, WPL, 524288);
    // G = gelu(curIn @ W'^T + b_eff)   [16384 x 1024]
    k_mm<<<dim3(8, 128, 1), 256, 0, stream>>>(curIn, WPH, WPL, beff, G, nullptr,
                                              16384, 1024, 512, 512, nullptr, 1);
    k_repack<<<B_ * C_ * 16, 256, 0, stream>>>(G, G2);
    k_split<<<8192, 256, 0, stream>>>(end_w + (size_t)i * 8388608, EWH, EWL, 8388608);
    k_mm<<<dim3(4, 8, 8), 256, 0, stream>>>(G2, EWH, EWL, nullptr, nullptr, PART,
                                            1024, 512, 16384, 16384, nullptr, 0);
    k_red<<<2048, 256, 0, stream>>>(PART, end_b + i * T_, osm);
    k_lwln<<<B_ * T_, 256, 0, stream>>>(osm, glin_w + i * C_ * N_, glin_b + i * N_, curIn,
                                        gnorm_g + i * N_, gnorm_b + i * N_, cur);
    // ---- attention branch ----
    const int* Mdyn = meta + 15 + i;
    k_pad<<<4096, 256, 0, stream>>>(cur, A0, meta, i);
    dim3 gT(4, TOKMAX / 128, 1);
    k_mm<<<gT, 256, 0, stream>>>(A0, WqH, WqL, bq, A2, nullptr, TOKMAX, 512, 512, 512, Mdyn, 0);
    k_mm<<<gT, 256, 0, stream>>>(A0, WkH, WkL, bk, A3, nullptr, TOKMAX, 512, 512, 512, Mdyn, 0);
    k_mm<<<gT, 256, 0, stream>>>(A0, WvH, WvL, bv, A4, nullptr, TOKMAX, 512, 512, 512, Mdyn, 0);
    k_attn_reg<8><<<2048, 256, 0, stream>>>(A2, A3, A4, A5, meta, i);
    k_attn_reg<32><<<2048, 256, 0, stream>>>(A2, A3, A4, A5, meta, i);
    k_attn_small<<<65536, 256, 0, stream>>>(A2, A3, A4, A5, meta, i);
    k_attn_big<<<1024, 256, 0, stream>>>(A2, A3, A4, A5, meta, i);
    k_mm<<<gT, 256, 0, stream>>>(A5, WoH, WoL, bo, A2, nullptr, TOKMAX, 512, 512, 512, Mdyn, 0);
    k_lnadd<<<TOKMAX, 256, 0, stream>>>(A0, A2, an1g, an1b, A3, meta, i);
    k_mm<<<gT, 256, 0, stream>>>(A3, F1H, F1L, ff1b, A4, nullptr, TOKMAX, 512, 512, 512, Mdyn, 1);
    k_mm<<<gT, 256, 0, stream>>>(A4, F2H, F2L, ff2b, A5, nullptr, TOKMAX, 512, 512, 512, Mdyn, 0);
    k_lnadd<<<TOKMAX, 256, 0, stream>>>(A3, A5, an2g, an2b, A0, meta, i);
    k_fin<<<TOKMAX, 256, 0, stream>>>(A0, nrmg, nrmb, swb, accb, meta, i);
    curIn = cur;
  }
  k_final<<<(B_ * T_ * N_) / 256, 256, 0, stream>>>(accb, curIn, (float*)d_out);
}